// Round 2
// baseline (4936.163 us; speedup 1.0000x reference)
//
#include <hip/hip_runtime.h>
#include <hip/hip_bf16.h>
#include <math.h>

// ---------- bf16 helpers (bit ops, branchless RNE) ----------
__device__ __forceinline__ float bflo(unsigned u) { return __uint_as_float(u << 16); }
__device__ __forceinline__ float bfhi(unsigned u) { return __uint_as_float(u & 0xffff0000u); }
__device__ __forceinline__ unsigned packbf(float a, float b) {
    unsigned ua = __float_as_uint(a), ub = __float_as_uint(b);
    ua += 0x7fffu + ((ua >> 16) & 1u);
    ub += 0x7fffu + ((ub >> 16) & 1u);
    return (ua >> 16) | (ub & 0xffff0000u);
}

// ---------- setup ----------
__global__ void zero_int_kernel(int* __restrict__ p, int n) {
    int i = blockIdx.x * blockDim.x + threadIdx.x;
    int s = gridDim.x * blockDim.x;
    for (; i < n; i += s) p[i] = 0;
}

__global__ void count_kernel(const int* __restrict__ dst, int* __restrict__ cnt, int E) {
    int e = blockIdx.x * blockDim.x + threadIdx.x;
    if (e < E) atomicAdd(&cnt[dst[e]], 1);
}

// ---------- GEMM: C[64-row tile, 64 cols] = A @ B(64x64) ----------
// 128 threads, thread = (rg=tid>>3 in 0..15 -> 4 rows, cg=tid&7 -> 8 cols).
// LDS: A row-major stride 65 (conflict-free scalar writes & reads), B stride 64.
// NODE: out_bf[g][row][c] = acc + bias   (bf16), guarded rows.
// EDGE: h = acc + bias + x3[dst] + x4[src]; h_e (bf16); fp32 stats (8-replica
//       atomics); msg = sigmoid(A_row)*x2[src] atomically scattered to acc_buf.
template <bool EDGE>
__global__ __launch_bounds__(128)
void gemm_kernel(const float* __restrict__ A, const float* __restrict__ Bg,
                 const float* __restrict__ bias, __hip_bfloat16* __restrict__ out_bf,
                 const __hip_bfloat16* __restrict__ x2, const __hip_bfloat16* __restrict__ x3,
                 const __hip_bfloat16* __restrict__ x4,
                 const int* __restrict__ dst, const int* __restrict__ src,
                 float* __restrict__ acc_buf, float* __restrict__ estats,
                 int M, long long group_stride) {
    __shared__ float At[64 * 65];   // row-major, stride 65
    __shared__ float Bs[64 * 64];
    __shared__ int dstl[64], srcl[64];

    int tid = threadIdx.x;
    long long row0 = (long long)blockIdx.x * 64;
    int g = blockIdx.y;

    // stage B (4096 floats)
    for (int i = tid; i < 1024; i += 128) {
        float4 v = ((const float4*)(Bg + (long long)g * 4096))[i];
        *(float4*)&Bs[i * 4] = v;
    }
    // stage A row-major stride 65 (scalar writes: banks (r+4k4+j)%32 cover all, 2-way)
    for (int i = tid; i < 1024; i += 128) {
        int r = i >> 4, k4 = i & 15;
        long long row = row0 + r;
        float4 v = make_float4(0.f, 0.f, 0.f, 0.f);
        if (EDGE || row < M) v = *(const float4*)&A[row * 64 + k4 * 4];
        float* p = &At[r * 65 + k4 * 4];
        p[0] = v.x; p[1] = v.y; p[2] = v.z; p[3] = v.w;
    }
    if (EDGE && tid < 64) {
        dstl[tid] = dst[row0 + tid];
        srcl[tid] = src[row0 + tid];
    }
    __syncthreads();

    int rg = tid >> 3, cg = tid & 7;
    int r0 = rg * 4, c0 = cg * 8;

    float acc[4][8];
    #pragma unroll
    for (int i = 0; i < 4; i++)
        #pragma unroll
        for (int j = 0; j < 8; j++) acc[i][j] = 0.f;

    #pragma unroll 4
    for (int k = 0; k < 64; k++) {
        float a0 = At[(r0 + 0) * 65 + k];
        float a1 = At[(r0 + 1) * 65 + k];
        float a2 = At[(r0 + 2) * 65 + k];
        float a3 = At[(r0 + 3) * 65 + k];
        float4 b0 = *(float4*)&Bs[k * 64 + c0];
        float4 b1 = *(float4*)&Bs[k * 64 + c0 + 4];
        float bv[8] = {b0.x, b0.y, b0.z, b0.w, b1.x, b1.y, b1.z, b1.w};
        float av[4] = {a0, a1, a2, a3};
        #pragma unroll
        for (int i = 0; i < 4; i++)
            #pragma unroll
            for (int j = 0; j < 8; j++) acc[i][j] = fmaf(av[i], bv[j], acc[i][j]);
    }

    float bb[8];
    #pragma unroll
    for (int j = 0; j < 8; j++) bb[j] = bias[g * 64 + c0 + j];

    if (EDGE) {
        float ps[8], pq[8];
        #pragma unroll
        for (int j = 0; j < 8; j++) { ps[j] = 0.f; pq[j] = 0.f; }
        #pragma unroll
        for (int i = 0; i < 4; i++) {
            int rl = r0 + i;
            long long e = row0 + rl;
            int de = dstl[rl], se = srcl[rl];
            uint4 g3 = *(const uint4*)&x3[(long long)de * 64 + c0];
            uint4 g4 = *(const uint4*)&x4[(long long)se * 64 + c0];
            uint4 g2 = *(const uint4*)&x2[(long long)se * 64 + c0];
            float4 wa = *(const float4*)&A[e * 64 + c0];       // L1-hot re-read
            float4 wb = *(const float4*)&A[e * 64 + c0 + 4];
            float x3v[8] = {bflo(g3.x), bfhi(g3.x), bflo(g3.y), bfhi(g3.y),
                            bflo(g3.z), bfhi(g3.z), bflo(g3.w), bfhi(g3.w)};
            float x4v[8] = {bflo(g4.x), bfhi(g4.x), bflo(g4.y), bfhi(g4.y),
                            bflo(g4.z), bfhi(g4.z), bflo(g4.w), bfhi(g4.w)};
            float x2v[8] = {bflo(g2.x), bfhi(g2.x), bflo(g2.y), bfhi(g2.y),
                            bflo(g2.z), bfhi(g2.z), bflo(g2.w), bfhi(g2.w)};
            float wv[8] = {wa.x, wa.y, wa.z, wa.w, wb.x, wb.y, wb.z, wb.w};
            float h[8];
            #pragma unroll
            for (int j = 0; j < 8; j++) {
                float hv = acc[i][j] + bb[j] + x3v[j] + x4v[j];
                h[j] = hv;
                ps[j] += hv;
                pq[j] += hv * hv;
            }
            uint4 hp;
            hp.x = packbf(h[0], h[1]); hp.y = packbf(h[2], h[3]);
            hp.z = packbf(h[4], h[5]); hp.w = packbf(h[6], h[7]);
            *(uint4*)&out_bf[e * 64 + c0] = hp;
            // message scatter: sigmoid(w) * x2[src] -> acc_buf[dst]
            float* ab = acc_buf + (long long)de * 64 + c0;
            #pragma unroll
            for (int j = 0; j < 8; j++) {
                float m = x2v[j] / (1.f + __expf(-wv[j]));
                atomicAdd(&ab[j], m);
            }
        }
        // block stats reduce (reuse At; stride 65 keeps it 2-way max)
        __syncthreads();
        float* red = At;
        #pragma unroll
        for (int j = 0; j < 8; j++) red[rg * 65 + c0 + j] = ps[j];
        __syncthreads();
        float* est = estats + (blockIdx.x & 7) * 128;
        if (tid < 64) {
            float s = 0.f;
            #pragma unroll
            for (int r = 0; r < 16; r++) s += red[r * 65 + tid];
            atomicAdd(&est[tid], s);
        }
        __syncthreads();
        #pragma unroll
        for (int j = 0; j < 8; j++) red[rg * 65 + c0 + j] = pq[j];
        __syncthreads();
        if (tid < 64) {
            float s = 0.f;
            #pragma unroll
            for (int r = 0; r < 16; r++) s += red[r * 65 + tid];
            atomicAdd(&est[64 + tid], s);
        }
    } else {
        #pragma unroll
        for (int i = 0; i < 4; i++) {
            long long row = row0 + r0 + i;
            if (row < M) {
                float h[8];
                #pragma unroll
                for (int j = 0; j < 8; j++) h[j] = acc[i][j] + bb[j];
                uint4 hp;
                hp.x = packbf(h[0], h[1]); hp.y = packbf(h[2], h[3]);
                hp.z = packbf(h[4], h[5]); hp.w = packbf(h[6], h[7]);
                *(uint4*)&out_bf[(long long)g * group_stride + row * 64 + c0] = hp;
            }
        }
    }
}

// ---------- node finish: h = x1 + acc/cnt; write h_v; node BN stats ----------
__global__ __launch_bounds__(256)
void node_finish_kernel(const float4* __restrict__ acc4, const __hip_bfloat16* __restrict__ x1,
                        const int* __restrict__ cnt, float4* __restrict__ hv4,
                        float* __restrict__ nstats, int total) {
    __shared__ float red[16 * 65];
    int tid = threadIdx.x;
    int idx = blockIdx.x * 256 + tid;
    int c0 = (tid & 15) * 4;
    float h0 = 0.f, h1 = 0.f, h2 = 0.f, h3 = 0.f;
    if (idx < total) {
        int n = idx >> 4;
        float4 a = acc4[idx];
        float ic = 1.f / fmaxf((float)cnt[n], 1.f);
        uint2 xv = *(const uint2*)&x1[(long long)n * 64 + c0];
        h0 = bflo(xv.x) + a.x * ic;
        h1 = bfhi(xv.x) + a.y * ic;
        h2 = bflo(xv.y) + a.z * ic;
        h3 = bfhi(xv.y) + a.w * ic;
        hv4[idx] = make_float4(h0, h1, h2, h3);
    }
    int rw = tid >> 4;
    red[rw * 65 + c0 + 0] = h0; red[rw * 65 + c0 + 1] = h1;
    red[rw * 65 + c0 + 2] = h2; red[rw * 65 + c0 + 3] = h3;
    __syncthreads();
    float* nst = nstats + (blockIdx.x & 7) * 128;
    if (tid < 64) {
        float s = 0.f;
        #pragma unroll
        for (int r = 0; r < 16; r++) s += red[r * 65 + tid];
        atomicAdd(&nst[tid], s);
    }
    __syncthreads();
    red[rw * 65 + c0 + 0] = h0 * h0; red[rw * 65 + c0 + 1] = h1 * h1;
    red[rw * 65 + c0 + 2] = h2 * h2; red[rw * 65 + c0 + 3] = h3 * h3;
    __syncthreads();
    if (tid < 64) {
        float s = 0.f;
        #pragma unroll
        for (int r = 0; r < 16; r++) s += red[r * 65 + tid];
        atomicAdd(&nst[64 + tid], s);
    }
}

// ---------- finalize: stats -> (kmul, kadd) for node & edge BN ----------
__global__ void finalize_kernel(const float* __restrict__ nstats, const float* __restrict__ estats,
                                const float* __restrict__ vs, const float* __restrict__ vb,
                                const float* __restrict__ es, const float* __restrict__ eb,
                                float* __restrict__ fin, float invN, float invE) {
    int t = threadIdx.x;   // 128
    const float* st = (t < 64) ? nstats : estats;
    float inv = (t < 64) ? invN : invE;
    int c = t & 63;
    float s = 0.f, q = 0.f;
    #pragma unroll
    for (int r = 0; r < 8; r++) { s += st[r * 128 + c]; q += st[r * 128 + 64 + c]; }
    float mean = s * inv;
    float var = q * inv - mean * mean;
    float rinv = rsqrtf(var + 1e-5f);
    float sc = (t < 64) ? vs[c] : es[c];
    float bi = (t < 64) ? vb[c] : eb[c];
    float kmul = rinv * sc;
    float kadd = bi - mean * kmul;
    int base = (t < 64) ? 0 : 128;
    fin[base + c] = kmul;
    fin[base + 64 + c] = kadd;
}

// ---------- node BN apply: out = xold + silu(h*kmul + kadd) ----------
__global__ __launch_bounds__(256)
void node_apply_kernel(const float4* __restrict__ hv4, const float4* __restrict__ xold4,
                       float4* __restrict__ out4, const float* __restrict__ fin, int total) {
    __shared__ float km[64], ka[64];
    if (threadIdx.x < 64) { km[threadIdx.x] = fin[threadIdx.x]; ka[threadIdx.x] = fin[64 + threadIdx.x]; }
    __syncthreads();
    int idx = blockIdx.x * 256 + threadIdx.x;
    if (idx >= total) return;
    int c0 = (idx & 15) * 4;
    float4 h = hv4[idx], xo = xold4[idx];
    float4 m = *(float4*)&km[c0], a = *(float4*)&ka[c0];
    float g0 = h.x * m.x + a.x, g1 = h.y * m.y + a.y, g2 = h.z * m.z + a.z, g3 = h.w * m.w + a.w;
    out4[idx] = make_float4(xo.x + g0 / (1.f + __expf(-g0)),
                            xo.y + g1 / (1.f + __expf(-g1)),
                            xo.z + g2 / (1.f + __expf(-g2)),
                            xo.w + g3 / (1.f + __expf(-g3)));
}

// ---------- edge BN apply: out = wold + silu(h_e*kmul + kadd) ----------
__global__ __launch_bounds__(256)
void edge_bn_kernel(const uint4* __restrict__ he, const float4* __restrict__ w4,
                    float4* __restrict__ out4, const float* __restrict__ fin, long long total) {
    __shared__ float km[64], ka[64];
    if (threadIdx.x < 64) { km[threadIdx.x] = fin[128 + threadIdx.x]; ka[threadIdx.x] = fin[192 + threadIdx.x]; }
    __syncthreads();
    for (long long idx = blockIdx.x * 256LL + threadIdx.x; idx < total; idx += gridDim.x * 256LL) {
        int c0 = (int)(idx & 7) * 8;
        uint4 hp = he[idx];
        float4 wa = w4[idx * 2], wb = w4[idx * 2 + 1];
        float hf[8] = {bflo(hp.x), bfhi(hp.x), bflo(hp.y), bfhi(hp.y),
                       bflo(hp.z), bfhi(hp.z), bflo(hp.w), bfhi(hp.w)};
        float4 m0 = *(float4*)&km[c0], m1 = *(float4*)&km[c0 + 4];
        float4 a0 = *(float4*)&ka[c0], a1 = *(float4*)&ka[c0 + 4];
        float mv[8] = {m0.x, m0.y, m0.z, m0.w, m1.x, m1.y, m1.z, m1.w};
        float av[8] = {a0.x, a0.y, a0.z, a0.w, a1.x, a1.y, a1.z, a1.w};
        float wv[8] = {wa.x, wa.y, wa.z, wa.w, wb.x, wb.y, wb.z, wb.w};
        float o[8];
        #pragma unroll
        for (int j = 0; j < 8; j++) {
            float g = hf[j] * mv[j] + av[j];
            o[j] = wv[j] + g / (1.f + __expf(-g));
        }
        out4[idx * 2]     = make_float4(o[0], o[1], o[2], o[3]);
        out4[idx * 2 + 1] = make_float4(o[4], o[5], o[6], o[7]);
    }
}

// ---------- launch ----------
extern "C" void kernel_launch(void* const* d_in, const int* in_sizes, int n_in,
                              void* d_out, int out_size, void* d_ws, size_t ws_size,
                              hipStream_t stream) {
    const float* x_in  = (const float*)d_in[0];
    const float* ea_in = (const float*)d_in[1];
    const int*   ei    = (const int*)d_in[2];
    const float* v_w   = (const float*)d_in[3];
    const float* v_b   = (const float*)d_in[4];
    const float* e_w   = (const float*)d_in[5];
    const float* e_b   = (const float*)d_in[6];
    const float* vbn_s = (const float*)d_in[7];
    const float* vbn_b = (const float*)d_in[8];
    const float* ebn_s = (const float*)d_in[9];
    const float* ebn_b = (const float*)d_in[10];

    const int Nn = in_sizes[0] / 64;
    const int E  = in_sizes[1] / 64;
    const int L  = in_sizes[3] / (4 * 64 * 64);

    const int* dst = ei;
    const int* src = ei + E;

    // workspace layout
    float* acc_buf = (float*)d_ws;                    // [Nn][64] fp32
    float* nstats  = acc_buf + (long long)Nn * 64;    // [8][128]
    float* estats  = nstats + 1024;                   // [8][128]
    float* fin     = estats + 1024;                   // [4][64]
    float* h_v     = fin + 256;                       // [Nn][64] fp32
    __hip_bfloat16* xp  = (__hip_bfloat16*)(h_v + (long long)Nn * 64);  // [4][Nn][64] bf16
    __hip_bfloat16* h_e = xp + (long long)4 * Nn * 64;                  // [E][64] bf16
    int* cnt = (int*)(h_e + (long long)E * 64);       // [Nn]

    size_t needed = ((size_t)Nn * 64 * 2 + 2304) * 4 +
                    ((size_t)4 * Nn * 64 + (size_t)E * 64) * 2 + (size_t)Nn * 4;
    if (ws_size < needed) return;

    float* out_x = (float*)d_out;
    float* out_w = out_x + (long long)Nn * 64;

    zero_int_kernel<<<64, 256, 0, stream>>>(cnt, Nn);
    count_kernel<<<(E + 255) / 256, 256, 0, stream>>>(dst, cnt, E);

    const __hip_bfloat16* x1 = xp;
    const __hip_bfloat16* x2 = xp + (long long)Nn * 64;
    const __hip_bfloat16* x3 = xp + (long long)2 * Nn * 64;
    const __hip_bfloat16* x4 = xp + (long long)3 * Nn * 64;

    for (int l = 0; l < L; l++) {
        const float* xl = (l == 0) ? x_in : out_x;
        const float* wl = (l == 0) ? ea_in : out_w;

        // zero acc_buf + stats (contiguous)
        hipMemsetAsync(acc_buf, 0, ((size_t)Nn * 64 + 2048) * 4, stream);

        // node projections -> xp[4] (bf16)
        gemm_kernel<false><<<dim3((Nn + 63) / 64, 4), 128, 0, stream>>>(
            xl, v_w + (long long)l * 4 * 4096, v_b + l * 256, xp,
            nullptr, nullptr, nullptr, nullptr, nullptr, nullptr, nullptr,
            Nn, (long long)Nn * 64);

        // edge GEMM + gathers + h_e(bf16) + edge stats + msg scatter
        gemm_kernel<true><<<dim3(E / 64, 1), 128, 0, stream>>>(
            wl, e_w + (long long)l * 4096, e_b + l * 64, h_e,
            x2, x3, x4, dst, src, acc_buf, estats, E, 0);

        // h_v = x1 + acc/cnt; node stats
        node_finish_kernel<<<(Nn * 16 + 255) / 256, 256, 0, stream>>>(
            (const float4*)acc_buf, x1, cnt, (float4*)h_v, nstats, Nn * 16);

        // fold BN affine
        finalize_kernel<<<1, 128, 0, stream>>>(
            nstats, estats, vbn_s + l * 64, vbn_b + l * 64,
            ebn_s + l * 64, ebn_b + l * 64, fin, 1.f / (float)Nn, 1.f / (float)E);

        // node update -> out_x
        node_apply_kernel<<<(Nn * 16 + 255) / 256, 256, 0, stream>>>(
            (const float4*)h_v, (const float4*)xl, (float4*)out_x, fin, Nn * 16);

        // edge update -> out_w
        edge_bn_kernel<<<4096, 256, 0, stream>>>(
            (const uint4*)h_e, (const float4*)wl, (float4*)out_w, fin, (long long)E * 8);
    }
}

// Round 3
// 1408.176 us; speedup vs baseline: 3.5054x; 3.5054x over previous
//
#include <hip/hip_runtime.h>
#include <hip/hip_bf16.h>
#include <math.h>

// ---------- bf16 helpers (bit ops, branchless RNE) ----------
__device__ __forceinline__ float bflo(unsigned u) { return __uint_as_float(u << 16); }
__device__ __forceinline__ float bfhi(unsigned u) { return __uint_as_float(u & 0xffff0000u); }
__device__ __forceinline__ unsigned packbf(float a, float b) {
    unsigned ua = __float_as_uint(a), ub = __float_as_uint(b);
    ua += 0x7fffu + ((ua >> 16) & 1u);
    ub += 0x7fffu + ((ub >> 16) & 1u);
    return (ua >> 16) | (ub & 0xffff0000u);
}

// ---------- setup ----------
__global__ void zero_int_kernel(int* __restrict__ p, int n) {
    int i = blockIdx.x * blockDim.x + threadIdx.x;
    int s = gridDim.x * blockDim.x;
    for (; i < n; i += s) p[i] = 0;
}

__global__ void count_kernel(const int* __restrict__ dst, int* __restrict__ cnt, int E) {
    int e = blockIdx.x * blockDim.x + threadIdx.x;
    if (e < E) atomicAdd(&cnt[dst[e]], 1);
}

// single-block exclusive scan of cnt[0..n) -> off[0..n]
__global__ __launch_bounds__(1024)
void scan_kernel(const int* __restrict__ cnt, int* __restrict__ off, int n) {
    __shared__ int wsum[16];
    __shared__ int carry;
    int tid = threadIdx.x, lane = tid & 63, wid = tid >> 6;
    if (tid == 0) carry = 0;
    __syncthreads();
    for (int base = 0; base < n; base += 1024) {
        int i = base + tid;
        int v = (i < n) ? cnt[i] : 0;
        int sc = v;
        #pragma unroll
        for (int s = 1; s < 64; s <<= 1) {
            int t = __shfl_up(sc, (unsigned)s, 64);
            if (lane >= s) sc += t;
        }
        if (lane == 63) wsum[wid] = sc;
        __syncthreads();
        int woff = 0;
        for (int k = 0; k < wid; k++) woff += wsum[k];
        int inc = carry + woff + sc;
        if (i < n) off[i + 1] = inc;
        if (i == 0) off[0] = 0;
        __syncthreads();
        if (tid == 0) {
            int t = 0;
            for (int k = 0; k < 16; k++) t += wsum[k];
            carry += t;
        }
        __syncthreads();
    }
}

// perm[e] = CSR slot for edge e; consumes cnt (leaves zeros)
__global__ void fill_perm_kernel(const int* __restrict__ dst, const int* __restrict__ off,
                                 int* __restrict__ cnt, int* __restrict__ perm, int E) {
    int e = blockIdx.x * blockDim.x + threadIdx.x;
    if (e < E) {
        int d = dst[e];
        int pos = atomicSub(&cnt[d], 1) - 1;
        perm[e] = off[d] + pos;
    }
}

// ---------- GEMM: C[64-row tile, 64 cols] = A @ B(64x64) ----------
// 128 threads, thread = (rg=tid>>3 -> 4 rows, cg=tid&7 -> 8 cols).
// LDS: A row-major stride 65 (<=2-way conflicts), B stride 64.
// NODE: out_bf[g][row][c] = acc + bias (bf16).
// EDGE: h = acc + bias + x3[dst] + x4[src] -> h_e (bf16); fp32 stats
//       (8-replica atomics); msg = sigmoid(w)*x2[src] -> msg_csr[perm[e]]
//       (plain bf16 row scatter, NO atomics).
template <bool EDGE>
__global__ __launch_bounds__(128)
void gemm_kernel(const float* __restrict__ A, const float* __restrict__ Bg,
                 const float* __restrict__ bias, __hip_bfloat16* __restrict__ out_bf,
                 const __hip_bfloat16* __restrict__ x2, const __hip_bfloat16* __restrict__ x3,
                 const __hip_bfloat16* __restrict__ x4,
                 const int* __restrict__ dst, const int* __restrict__ src,
                 const int* __restrict__ perm, __hip_bfloat16* __restrict__ msg_csr,
                 float* __restrict__ estats, int M, long long group_stride) {
    __shared__ float At[64 * 65];
    __shared__ float Bs[64 * 64];
    __shared__ int dstl[64], srcl[64], perml[64];

    int tid = threadIdx.x;
    long long row0 = (long long)blockIdx.x * 64;
    int g = blockIdx.y;

    for (int i = tid; i < 1024; i += 128) {
        float4 v = ((const float4*)(Bg + (long long)g * 4096))[i];
        *(float4*)&Bs[i * 4] = v;
    }
    for (int i = tid; i < 1024; i += 128) {
        int r = i >> 4, k4 = i & 15;
        long long row = row0 + r;
        float4 v = make_float4(0.f, 0.f, 0.f, 0.f);
        if (EDGE || row < M) v = *(const float4*)&A[row * 64 + k4 * 4];
        float* p = &At[r * 65 + k4 * 4];
        p[0] = v.x; p[1] = v.y; p[2] = v.z; p[3] = v.w;
    }
    if (EDGE && tid < 64) {
        dstl[tid] = dst[row0 + tid];
        srcl[tid] = src[row0 + tid];
        perml[tid] = perm[row0 + tid];
    }
    __syncthreads();

    int rg = tid >> 3, cg = tid & 7;
    int r0 = rg * 4, c0 = cg * 8;

    float acc[4][8];
    #pragma unroll
    for (int i = 0; i < 4; i++)
        #pragma unroll
        for (int j = 0; j < 8; j++) acc[i][j] = 0.f;

    #pragma unroll 4
    for (int k = 0; k < 64; k++) {
        float a0 = At[(r0 + 0) * 65 + k];
        float a1 = At[(r0 + 1) * 65 + k];
        float a2 = At[(r0 + 2) * 65 + k];
        float a3 = At[(r0 + 3) * 65 + k];
        float4 b0 = *(float4*)&Bs[k * 64 + c0];
        float4 b1 = *(float4*)&Bs[k * 64 + c0 + 4];
        float bv[8] = {b0.x, b0.y, b0.z, b0.w, b1.x, b1.y, b1.z, b1.w};
        float av[4] = {a0, a1, a2, a3};
        #pragma unroll
        for (int i = 0; i < 4; i++)
            #pragma unroll
            for (int j = 0; j < 8; j++) acc[i][j] = fmaf(av[i], bv[j], acc[i][j]);
    }

    float bb[8];
    #pragma unroll
    for (int j = 0; j < 8; j++) bb[j] = bias[g * 64 + c0 + j];

    if (EDGE) {
        float ps[8], pq[8];
        #pragma unroll
        for (int j = 0; j < 8; j++) { ps[j] = 0.f; pq[j] = 0.f; }
        #pragma unroll
        for (int i = 0; i < 4; i++) {
            int rl = r0 + i;
            long long e = row0 + rl;
            int de = dstl[rl], se = srcl[rl];
            uint4 g3 = *(const uint4*)&x3[(long long)de * 64 + c0];
            uint4 g4 = *(const uint4*)&x4[(long long)se * 64 + c0];
            uint4 g2 = *(const uint4*)&x2[(long long)se * 64 + c0];
            float x3v[8] = {bflo(g3.x), bfhi(g3.x), bflo(g3.y), bfhi(g3.y),
                            bflo(g3.z), bfhi(g3.z), bflo(g3.w), bfhi(g3.w)};
            float x4v[8] = {bflo(g4.x), bfhi(g4.x), bflo(g4.y), bfhi(g4.y),
                            bflo(g4.z), bfhi(g4.z), bflo(g4.w), bfhi(g4.w)};
            float x2v[8] = {bflo(g2.x), bfhi(g2.x), bflo(g2.y), bfhi(g2.y),
                            bflo(g2.z), bfhi(g2.z), bflo(g2.w), bfhi(g2.w)};
            float h[8], m[8];
            #pragma unroll
            for (int j = 0; j < 8; j++) {
                float wv = At[rl * 65 + c0 + j];           // w from LDS (broadcast)
                float hv = acc[i][j] + bb[j] + x3v[j] + x4v[j];
                h[j] = hv;
                ps[j] += hv;
                pq[j] += hv * hv;
                m[j] = x2v[j] / (1.f + __expf(-wv));       // sigmoid(w)*x2[src]
            }
            uint4 hp;
            hp.x = packbf(h[0], h[1]); hp.y = packbf(h[2], h[3]);
            hp.z = packbf(h[4], h[5]); hp.w = packbf(h[6], h[7]);
            *(uint4*)&out_bf[e * 64 + c0] = hp;
            uint4 mp;
            mp.x = packbf(m[0], m[1]); mp.y = packbf(m[2], m[3]);
            mp.z = packbf(m[4], m[5]); mp.w = packbf(m[6], m[7]);
            *(uint4*)&msg_csr[(long long)perml[rl] * 64 + c0] = mp;  // scatter, no atomics
        }
        __syncthreads();
        float* red = At;
        #pragma unroll
        for (int j = 0; j < 8; j++) red[rg * 65 + c0 + j] = ps[j];
        __syncthreads();
        float* est = estats + (blockIdx.x & 7) * 128;
        if (tid < 64) {
            float s = 0.f;
            #pragma unroll
            for (int r = 0; r < 16; r++) s += red[r * 65 + tid];
            atomicAdd(&est[tid], s);
        }
        __syncthreads();
        #pragma unroll
        for (int j = 0; j < 8; j++) red[rg * 65 + c0 + j] = pq[j];
        __syncthreads();
        if (tid < 64) {
            float s = 0.f;
            #pragma unroll
            for (int r = 0; r < 16; r++) s += red[r * 65 + tid];
            atomicAdd(&est[64 + tid], s);
        }
    } else {
        #pragma unroll
        for (int i = 0; i < 4; i++) {
            long long row = row0 + r0 + i;
            if (row < M) {
                float h[8];
                #pragma unroll
                for (int j = 0; j < 8; j++) h[j] = acc[i][j] + bb[j];
                uint4 hp;
                hp.x = packbf(h[0], h[1]); hp.y = packbf(h[2], h[3]);
                hp.z = packbf(h[4], h[5]); hp.w = packbf(h[6], h[7]);
                *(uint4*)&out_bf[(long long)g * group_stride + row * 64 + c0] = hp;
            }
        }
    }
}

// ---------- node finish: h = x1 + mean(msg rows); h_v fp32; node BN stats ----------
// half-wave (32 lanes) per node, lane k handles features 2k, 2k+1.
__global__ __launch_bounds__(256)
void node_finish_kernel(const __hip_bfloat16* __restrict__ msg, const __hip_bfloat16* __restrict__ x1,
                        const int* __restrict__ off, float* __restrict__ h_v,
                        float* __restrict__ nstats, int Nn) {
    __shared__ float red[8 * 66];
    int tid = threadIdx.x;
    int hw = tid >> 5, k = tid & 31;
    int n = blockIdx.x * 8 + hw;
    float h0 = 0.f, h1 = 0.f;
    if (n < Nn) {
        int o0 = off[n], o1 = off[n + 1];
        float a0 = 0.f, a1 = 0.f;
        for (int j = o0; j < o1; j++) {
            unsigned u = *(const unsigned*)&msg[(long long)j * 64 + 2 * k];
            a0 += bflo(u);
            a1 += bfhi(u);
        }
        float ic = 1.f / fmaxf((float)(o1 - o0), 1.f);
        unsigned xu = *(const unsigned*)&x1[(long long)n * 64 + 2 * k];
        h0 = bflo(xu) + a0 * ic;
        h1 = bfhi(xu) + a1 * ic;
        *(float2*)&h_v[(long long)n * 64 + 2 * k] = make_float2(h0, h1);
    }
    red[hw * 66 + 2 * k] = h0;
    red[hw * 66 + 2 * k + 1] = h1;
    __syncthreads();
    float* nst = nstats + (blockIdx.x & 7) * 128;
    if (tid < 64) {
        float s = 0.f;
        #pragma unroll
        for (int r = 0; r < 8; r++) s += red[r * 66 + tid];
        atomicAdd(&nst[tid], s);
    }
    __syncthreads();
    red[hw * 66 + 2 * k] = h0 * h0;
    red[hw * 66 + 2 * k + 1] = h1 * h1;
    __syncthreads();
    if (tid < 64) {
        float s = 0.f;
        #pragma unroll
        for (int r = 0; r < 8; r++) s += red[r * 66 + tid];
        atomicAdd(&nst[64 + tid], s);
    }
}

// ---------- finalize: stats -> (kmul, kadd) for node & edge BN ----------
__global__ void finalize_kernel(const float* __restrict__ nstats, const float* __restrict__ estats,
                                const float* __restrict__ vs, const float* __restrict__ vb,
                                const float* __restrict__ es, const float* __restrict__ eb,
                                float* __restrict__ fin, float invN, float invE) {
    int t = threadIdx.x;   // 128
    const float* st = (t < 64) ? nstats : estats;
    float inv = (t < 64) ? invN : invE;
    int c = t & 63;
    float s = 0.f, q = 0.f;
    #pragma unroll
    for (int r = 0; r < 8; r++) { s += st[r * 128 + c]; q += st[r * 128 + 64 + c]; }
    float mean = s * inv;
    float var = q * inv - mean * mean;
    float rinv = rsqrtf(var + 1e-5f);
    float sc = (t < 64) ? vs[c] : es[c];
    float bi = (t < 64) ? vb[c] : eb[c];
    float kmul = rinv * sc;
    float kadd = bi - mean * kmul;
    int base = (t < 64) ? 0 : 128;
    fin[base + c] = kmul;
    fin[base + 64 + c] = kadd;
}

// ---------- node BN apply: out = xold + silu(h*kmul + kadd) ----------
__global__ __launch_bounds__(256)
void node_apply_kernel(const float4* __restrict__ hv4, const float4* __restrict__ xold4,
                       float4* __restrict__ out4, const float* __restrict__ fin, int total) {
    __shared__ float km[64], ka[64];
    if (threadIdx.x < 64) { km[threadIdx.x] = fin[threadIdx.x]; ka[threadIdx.x] = fin[64 + threadIdx.x]; }
    __syncthreads();
    int idx = blockIdx.x * 256 + threadIdx.x;
    if (idx >= total) return;
    int c0 = (idx & 15) * 4;
    float4 h = hv4[idx], xo = xold4[idx];
    float4 m = *(float4*)&km[c0], a = *(float4*)&ka[c0];
    float g0 = h.x * m.x + a.x, g1 = h.y * m.y + a.y, g2 = h.z * m.z + a.z, g3 = h.w * m.w + a.w;
    out4[idx] = make_float4(xo.x + g0 / (1.f + __expf(-g0)),
                            xo.y + g1 / (1.f + __expf(-g1)),
                            xo.z + g2 / (1.f + __expf(-g2)),
                            xo.w + g3 / (1.f + __expf(-g3)));
}

// ---------- edge BN apply: out = wold + silu(h_e*kmul + kadd) ----------
__global__ __launch_bounds__(256)
void edge_bn_kernel(const uint4* __restrict__ he, const float4* __restrict__ w4,
                    float4* __restrict__ out4, const float* __restrict__ fin, long long total) {
    __shared__ float km[64], ka[64];
    if (threadIdx.x < 64) { km[threadIdx.x] = fin[128 + threadIdx.x]; ka[threadIdx.x] = fin[192 + threadIdx.x]; }
    __syncthreads();
    for (long long idx = blockIdx.x * 256LL + threadIdx.x; idx < total; idx += gridDim.x * 256LL) {
        int c0 = (int)(idx & 7) * 8;
        uint4 hp = he[idx];
        float4 wa = w4[idx * 2], wb = w4[idx * 2 + 1];
        float hf[8] = {bflo(hp.x), bfhi(hp.x), bflo(hp.y), bfhi(hp.y),
                       bflo(hp.z), bfhi(hp.z), bflo(hp.w), bfhi(hp.w)};
        float4 m0 = *(float4*)&km[c0], m1 = *(float4*)&km[c0 + 4];
        float4 a0 = *(float4*)&ka[c0], a1 = *(float4*)&ka[c0 + 4];
        float mv[8] = {m0.x, m0.y, m0.z, m0.w, m1.x, m1.y, m1.z, m1.w};
        float av[8] = {a0.x, a0.y, a0.z, a0.w, a1.x, a1.y, a1.z, a1.w};
        float wv[8] = {wa.x, wa.y, wa.z, wa.w, wb.x, wb.y, wb.z, wb.w};
        float o[8];
        #pragma unroll
        for (int j = 0; j < 8; j++) {
            float g = hf[j] * mv[j] + av[j];
            o[j] = wv[j] + g / (1.f + __expf(-g));
        }
        out4[idx * 2]     = make_float4(o[0], o[1], o[2], o[3]);
        out4[idx * 2 + 1] = make_float4(o[4], o[5], o[6], o[7]);
    }
}

// ---------- launch ----------
extern "C" void kernel_launch(void* const* d_in, const int* in_sizes, int n_in,
                              void* d_out, int out_size, void* d_ws, size_t ws_size,
                              hipStream_t stream) {
    const float* x_in  = (const float*)d_in[0];
    const float* ea_in = (const float*)d_in[1];
    const int*   ei    = (const int*)d_in[2];
    const float* v_w   = (const float*)d_in[3];
    const float* v_b   = (const float*)d_in[4];
    const float* e_w   = (const float*)d_in[5];
    const float* e_b   = (const float*)d_in[6];
    const float* vbn_s = (const float*)d_in[7];
    const float* vbn_b = (const float*)d_in[8];
    const float* ebn_s = (const float*)d_in[9];
    const float* ebn_b = (const float*)d_in[10];

    const int Nn = in_sizes[0] / 64;
    const int E  = in_sizes[1] / 64;
    const int L  = in_sizes[3] / (4 * 64 * 64);

    const int* dst = ei;
    const int* src = ei + E;

    // workspace layout (fp32 first, then bf16, then ints)
    float* h_v    = (float*)d_ws;                       // [Nn][64] fp32
    float* nstats = h_v + (long long)Nn * 64;           // [L][8][128]
    float* estats = nstats + (long long)L * 1024;       // [L][8][128]
    float* fin    = estats + (long long)L * 1024;       // [4][64]
    __hip_bfloat16* xp      = (__hip_bfloat16*)(fin + 256);          // [4][Nn][64]
    __hip_bfloat16* h_e     = xp + (long long)4 * Nn * 64;           // [E][64]
    __hip_bfloat16* msg_csr = h_e + (long long)E * 64;               // [E][64]
    int* cnt  = (int*)(msg_csr + (long long)E * 64);    // [Nn]
    int* off  = cnt + Nn;                               // [Nn+1]
    int* perm = off + Nn + 1;                           // [E]

    size_t needed = ((size_t)Nn * 64 + (size_t)L * 2048 + 256) * 4 +
                    ((size_t)4 * Nn * 64 + (size_t)2 * E * 64) * 2 +
                    ((size_t)2 * Nn + 1 + (size_t)E) * 4;
    if (ws_size < needed) return;

    float* out_x = (float*)d_out;
    float* out_w = out_x + (long long)Nn * 64;

    // CSR build (once) + zero all per-layer stats (once)
    zero_int_kernel<<<64, 256, 0, stream>>>(cnt, Nn);
    zero_int_kernel<<<8, 256, 0, stream>>>((int*)nstats, L * 2048);
    count_kernel<<<(E + 255) / 256, 256, 0, stream>>>(dst, cnt, E);
    scan_kernel<<<1, 1024, 0, stream>>>(cnt, off, Nn);
    fill_perm_kernel<<<(E + 255) / 256, 256, 0, stream>>>(dst, off, cnt, perm, E);

    const __hip_bfloat16* x1 = xp;
    const __hip_bfloat16* x2 = xp + (long long)Nn * 64;
    const __hip_bfloat16* x3 = xp + (long long)2 * Nn * 64;
    const __hip_bfloat16* x4 = xp + (long long)3 * Nn * 64;

    for (int l = 0; l < L; l++) {
        const float* xl = (l == 0) ? x_in : out_x;
        const float* wl = (l == 0) ? ea_in : out_w;
        float* nst = nstats + (long long)l * 1024;
        float* est = estats + (long long)l * 1024;

        // node projections -> xp[4] (bf16)
        gemm_kernel<false><<<dim3((Nn + 63) / 64, 4), 128, 0, stream>>>(
            xl, v_w + (long long)l * 4 * 4096, v_b + l * 256, xp,
            nullptr, nullptr, nullptr, nullptr, nullptr, nullptr, nullptr, nullptr,
            Nn, (long long)Nn * 64);

        // edge GEMM + gathers + h_e(bf16) + edge stats + msg scatter (no atomics)
        gemm_kernel<true><<<dim3(E / 64, 1), 128, 0, stream>>>(
            wl, e_w + (long long)l * 4096, e_b + l * 64, h_e,
            x2, x3, x4, dst, src, perm, msg_csr, est, E, 0);

        // h_v = x1 + mean(msg); node stats (coalesced CSR gather)
        node_finish_kernel<<<(Nn + 7) / 8, 256, 0, stream>>>(
            msg_csr, x1, off, h_v, nst, Nn);

        // fold BN affine
        finalize_kernel<<<1, 128, 0, stream>>>(
            nst, est, vbn_s + l * 64, vbn_b + l * 64,
            ebn_s + l * 64, ebn_b + l * 64, fin, 1.f / (float)Nn, 1.f / (float)E);

        // node update -> out_x
        node_apply_kernel<<<(Nn * 16 + 255) / 256, 256, 0, stream>>>(
            (const float4*)h_v, (const float4*)xl, (float4*)out_x, fin, Nn * 16);

        // edge update -> out_w
        edge_bn_kernel<<<4096, 256, 0, stream>>>(
            (const uint4*)h_e, (const float4*)wl, (float4*)out_w, fin, (long long)E * 8);
    }
}

// Round 4
// 1334.449 us; speedup vs baseline: 3.6990x; 1.0552x over previous
//
#include <hip/hip_runtime.h>
#include <hip/hip_bf16.h>
#include <math.h>

typedef __attribute__((ext_vector_type(8))) short bf16x8;
typedef __attribute__((ext_vector_type(4))) float f32x4;

// ---------- bf16 helpers (bit ops, branchless RNE) ----------
__device__ __forceinline__ float bflo(unsigned u) { return __uint_as_float(u << 16); }
__device__ __forceinline__ float bfhi(unsigned u) { return __uint_as_float(u & 0xffff0000u); }
__device__ __forceinline__ unsigned packbf(float a, float b) {
    unsigned ua = __float_as_uint(a), ub = __float_as_uint(b);
    ua += 0x7fffu + ((ua >> 16) & 1u);
    ub += 0x7fffu + ((ub >> 16) & 1u);
    return (ua >> 16) | (ub & 0xffff0000u);
}

// ---------- setup ----------
__global__ void zero_int_kernel(int* __restrict__ p, int n) {
    int i = blockIdx.x * blockDim.x + threadIdx.x;
    int s = gridDim.x * blockDim.x;
    for (; i < n; i += s) p[i] = 0;
}

__global__ void count_kernel(const int* __restrict__ dst, int* __restrict__ cnt, int E) {
    int e = blockIdx.x * blockDim.x + threadIdx.x;
    if (e < E) atomicAdd(&cnt[dst[e]], 1);
}

__global__ __launch_bounds__(1024)
void scan_kernel(const int* __restrict__ cnt, int* __restrict__ off, int n) {
    __shared__ int wsum[16];
    __shared__ int carry;
    int tid = threadIdx.x, lane = tid & 63, wid = tid >> 6;
    if (tid == 0) carry = 0;
    __syncthreads();
    for (int base = 0; base < n; base += 1024) {
        int i = base + tid;
        int v = (i < n) ? cnt[i] : 0;
        int sc = v;
        #pragma unroll
        for (int s = 1; s < 64; s <<= 1) {
            int t = __shfl_up(sc, (unsigned)s, 64);
            if (lane >= s) sc += t;
        }
        if (lane == 63) wsum[wid] = sc;
        __syncthreads();
        int woff = 0;
        for (int k = 0; k < wid; k++) woff += wsum[k];
        int inc = carry + woff + sc;
        if (i < n) off[i + 1] = inc;
        if (i == 0) off[0] = 0;
        __syncthreads();
        if (tid == 0) {
            int t = 0;
            for (int k = 0; k < 16; k++) t += wsum[k];
            carry += t;
        }
        __syncthreads();
    }
}

__global__ void fill_perm_kernel(const int* __restrict__ dst, const int* __restrict__ off,
                                 int* __restrict__ cnt, int* __restrict__ perm, int E) {
    int e = blockIdx.x * blockDim.x + threadIdx.x;
    if (e < E) {
        int d = dst[e];
        int pos = atomicSub(&cnt[d], 1) - 1;
        perm[e] = off[d] + pos;
    }
}

// ---------- pack weights into MFMA A-operand fragments (W^T, bf16) ----------
// frag element j of lane l for tile(ft,ks): m = ft*16+(l&15), k = ks*32+(l>>4)*8+j.
// Same (lane,elem)->k convention used for the B operand -> any true HW k-permutation cancels.
__global__ void pack_kernel(const float* __restrict__ v_w, const float* __restrict__ e_w,
                            short* __restrict__ vwp, short* __restrict__ ewp, int L) {
    int t = blockIdx.x * blockDim.x + threadIdx.x;
    if (t >= L * 5 * 4 * 2 * 64) return;
    int lane = t & 63;
    int ks = (t >> 6) & 1;
    int ft = (t >> 7) & 3;
    int mat = t >> 9;            // 0..L*5-1
    int layer = mat / 5, mi = mat % 5;
    const float* W = (mi < 4) ? (v_w + (long long)(layer * 4 + mi) * 4096)
                              : (e_w + (long long)layer * 4096);
    int m = ft * 16 + (lane & 15);
    int k0 = ks * 32 + (lane >> 4) * 8;
    short* dstp = (mi < 4)
        ? vwp + ((((long long)(layer * 4 + mi) * 4 + ft) * 2 + ks) * 64 + lane) * 8
        : ewp + ((((long long)layer * 4 + ft) * 2 + ks) * 64 + lane) * 8;
    #pragma unroll
    for (int j = 0; j < 8; j++) {
        unsigned u = __float_as_uint(W[(k0 + j) * 64 + m]);
        u += 0x7fffu + ((u >> 16) & 1u);
        dstp[j] = (short)(u >> 16);
    }
}

// ---------- node GEMM (MFMA): xp[g][n][f] = bf16(x@v_w[g] + v_b[g]) ----------
__global__ __launch_bounds__(256)
void node_gemm_mfma(const float* __restrict__ X, const short* __restrict__ vwp,
                    const float* __restrict__ vb, __hip_bfloat16* __restrict__ xp,
                    int Nn) {
    __shared__ short Xs[64 * 64];   // bf16 tile, XOR-swizzled
    int tid = threadIdx.x;
    long long row0 = (long long)blockIdx.x * 64;

    {   // stage fp32 -> bf16 LDS, swizzle byte ^= (row&7)<<4
        int r = tid >> 2, cq = tid & 3;
        long long row = row0 + r;
        float4 v0 = {0,0,0,0}, v1 = {0,0,0,0}, v2 = {0,0,0,0}, v3 = {0,0,0,0};
        if (row < Nn) {
            const float* sp = X + row * 64 + cq * 16;
            v0 = *(const float4*)(sp);     v1 = *(const float4*)(sp + 4);
            v2 = *(const float4*)(sp + 8); v3 = *(const float4*)(sp + 12);
        }
        uint4 w0, w1;
        w0.x = packbf(v0.x, v0.y); w0.y = packbf(v0.z, v0.w);
        w0.z = packbf(v1.x, v1.y); w0.w = packbf(v1.z, v1.w);
        w1.x = packbf(v2.x, v2.y); w1.y = packbf(v2.z, v2.w);
        w1.z = packbf(v3.x, v3.y); w1.w = packbf(v3.z, v3.w);
        int base = r * 128 + cq * 32, swz = (r & 7) << 4;
        *(uint4*)((char*)Xs + (base ^ swz)) = w0;
        *(uint4*)((char*)Xs + ((base + 16) ^ swz)) = w1;
    }
    __syncthreads();

    int l = tid & 63, wv = tid >> 6;
    int rl = wv * 16 + (l & 15);
    long long node = row0 + rl;
    bf16x8 bfr[2];
    #pragma unroll
    for (int ks = 0; ks < 2; ks++) {
        int off = (rl * 128 + ks * 64 + (l >> 4) * 16) ^ ((rl & 7) << 4);
        bfr[ks] = *(bf16x8*)((char*)Xs + off);
    }
    int q4 = (l >> 4) * 4;
    bool valid = node < Nn;
    for (int g = 0; g < 4; g++) {
        f32x4 acc[4];
        #pragma unroll
        for (int ft = 0; ft < 4; ft++) {
            acc[ft] = f32x4{0.f, 0.f, 0.f, 0.f};
            #pragma unroll
            for (int ks = 0; ks < 2; ks++) {
                bf16x8 a = *(const bf16x8*)(vwp + (((long long)(g * 4 + ft) * 2 + ks) * 64 + l) * 8);
                acc[ft] = __builtin_amdgcn_mfma_f32_16x16x32_bf16(a, bfr[ks], acc[ft], 0, 0, 0);
            }
        }
        if (valid) {
            #pragma unroll
            for (int ft = 0; ft < 4; ft++) {
                int f0 = ft * 16 + q4;
                float4 bv = *(const float4*)&vb[g * 64 + f0];
                uint2 o;
                o.x = packbf(acc[ft][0] + bv.x, acc[ft][1] + bv.y);
                o.y = packbf(acc[ft][2] + bv.z, acc[ft][3] + bv.w);
                *(uint2*)&xp[((long long)g * Nn + node) * 64 + f0] = o;
            }
        }
    }
}

// ---------- edge GEMM (MFMA) + gathers + h_e + msg scatter + edge stats ----------
__global__ __launch_bounds__(256)
void edge_gemm_mfma(const float* __restrict__ Wl, const short* __restrict__ ewp,
                    const float* __restrict__ eb,
                    const __hip_bfloat16* __restrict__ x2, const __hip_bfloat16* __restrict__ x3,
                    const __hip_bfloat16* __restrict__ x4,
                    const int* __restrict__ dst, const int* __restrict__ src,
                    const int* __restrict__ perm,
                    __hip_bfloat16* __restrict__ h_e, __hip_bfloat16* __restrict__ msg_csr,
                    float* __restrict__ estats) {
    __shared__ short Ws[64 * 64];
    __shared__ int dstl[64], srcl[64], perml[64];
    __shared__ float sred[2][4][64];
    int tid = threadIdx.x;
    long long row0 = (long long)blockIdx.x * 64;

    {   // stage w tile fp32 -> bf16 LDS (swizzled); E is a multiple of 64, no guard
        int r = tid >> 2, cq = tid & 3;
        const float* sp = Wl + (row0 + r) * 64 + cq * 16;
        float4 v0 = *(const float4*)(sp),     v1 = *(const float4*)(sp + 4);
        float4 v2 = *(const float4*)(sp + 8), v3 = *(const float4*)(sp + 12);
        uint4 w0, w1;
        w0.x = packbf(v0.x, v0.y); w0.y = packbf(v0.z, v0.w);
        w0.z = packbf(v1.x, v1.y); w0.w = packbf(v1.z, v1.w);
        w1.x = packbf(v2.x, v2.y); w1.y = packbf(v2.z, v2.w);
        w1.z = packbf(v3.x, v3.y); w1.w = packbf(v3.z, v3.w);
        int base = r * 128 + cq * 32, swz = (r & 7) << 4;
        *(uint4*)((char*)Ws + (base ^ swz)) = w0;
        *(uint4*)((char*)Ws + ((base + 16) ^ swz)) = w1;
        if (tid < 64) {
            dstl[tid] = dst[row0 + tid];
            srcl[tid] = src[row0 + tid];
            perml[tid] = perm[row0 + tid];
        }
    }
    __syncthreads();

    int l = tid & 63, wv = tid >> 6;
    int rl = wv * 16 + (l & 15);
    long long e = row0 + rl;
    bf16x8 bfr[2];
    #pragma unroll
    for (int ks = 0; ks < 2; ks++) {
        int off = (rl * 128 + ks * 64 + (l >> 4) * 16) ^ ((rl & 7) << 4);
        bfr[ks] = *(bf16x8*)((char*)Ws + off);
    }
    int q4 = (l >> 4) * 4;
    int de = dstl[rl], se = srcl[rl], pe = perml[rl];

    f32x4 acc[4];
    #pragma unroll
    for (int ft = 0; ft < 4; ft++) {
        acc[ft] = f32x4{0.f, 0.f, 0.f, 0.f};
        #pragma unroll
        for (int ks = 0; ks < 2; ks++) {
            bf16x8 a = *(const bf16x8*)(ewp + (((long long)ft * 2 + ks) * 64 + l) * 8);
            acc[ft] = __builtin_amdgcn_mfma_f32_16x16x32_bf16(a, bfr[ks], acc[ft], 0, 0, 0);
        }
    }

    #pragma unroll
    for (int ft = 0; ft < 4; ft++) {
        int f0 = ft * 16 + q4;
        float4 bv = *(const float4*)&eb[f0];
        uint2 g3 = *(const uint2*)&x3[(long long)de * 64 + f0];
        uint2 g4 = *(const uint2*)&x4[(long long)se * 64 + f0];
        uint2 g2 = *(const uint2*)&x2[(long long)se * 64 + f0];
        int woff = (rl * 128 + f0 * 2) ^ ((rl & 7) << 4);
        uint2 wu = *(uint2*)((char*)Ws + woff);
        float h0 = acc[ft][0] + bv.x + bflo(g3.x) + bflo(g4.x);
        float h1 = acc[ft][1] + bv.y + bfhi(g3.x) + bfhi(g4.x);
        float h2 = acc[ft][2] + bv.z + bflo(g3.y) + bflo(g4.y);
        float h3 = acc[ft][3] + bv.w + bfhi(g3.y) + bfhi(g4.y);
        uint2 ho;
        ho.x = packbf(h0, h1); ho.y = packbf(h2, h3);
        *(uint2*)&h_e[e * 64 + f0] = ho;
        float m0 = bflo(g2.x) / (1.f + __expf(-bflo(wu.x)));
        float m1 = bfhi(g2.x) / (1.f + __expf(-bfhi(wu.x)));
        float m2 = bflo(g2.y) / (1.f + __expf(-bflo(wu.y)));
        float m3 = bfhi(g2.y) / (1.f + __expf(-bfhi(wu.y)));
        uint2 mo;
        mo.x = packbf(m0, m1); mo.y = packbf(m2, m3);
        *(uint2*)&msg_csr[(long long)pe * 64 + f0] = mo;
        // stats: reduce over the 16 edge-lanes (xor masks touch lane bits 0-3 only)
        float s0 = h0, s1 = h1, s2 = h2, s3 = h3;
        float p0 = h0 * h0, p1 = h1 * h1, p2 = h2 * h2, p3 = h3 * h3;
        #pragma unroll
        for (int d = 1; d < 16; d <<= 1) {
            s0 += __shfl_xor(s0, d); s1 += __shfl_xor(s1, d);
            s2 += __shfl_xor(s2, d); s3 += __shfl_xor(s3, d);
            p0 += __shfl_xor(p0, d); p1 += __shfl_xor(p1, d);
            p2 += __shfl_xor(p2, d); p3 += __shfl_xor(p3, d);
        }
        if ((l & 15) == 0) {
            sred[0][wv][f0 + 0] = s0; sred[0][wv][f0 + 1] = s1;
            sred[0][wv][f0 + 2] = s2; sred[0][wv][f0 + 3] = s3;
            sred[1][wv][f0 + 0] = p0; sred[1][wv][f0 + 1] = p1;
            sred[1][wv][f0 + 2] = p2; sred[1][wv][f0 + 3] = p3;
        }
    }
    __syncthreads();
    if (tid < 128) {
        int which = tid >> 6, f = tid & 63;
        float s = sred[which][0][f] + sred[which][1][f] + sred[which][2][f] + sred[which][3][f];
        atomicAdd(&estats[(blockIdx.x & 7) * 128 + which * 64 + f], s);
    }
}

// ---------- node finish: h = x1 + mean(msg rows); h_v fp32; node BN stats ----------
__global__ __launch_bounds__(256)
void node_finish_kernel(const __hip_bfloat16* __restrict__ msg, const __hip_bfloat16* __restrict__ x1,
                        const int* __restrict__ off, float* __restrict__ h_v,
                        float* __restrict__ nstats, int Nn) {
    __shared__ float red[8 * 66];
    int tid = threadIdx.x;
    int hw = tid >> 5, k = tid & 31;
    int n = blockIdx.x * 8 + hw;
    float h0 = 0.f, h1 = 0.f;
    if (n < Nn) {
        int o0 = off[n], o1 = off[n + 1];
        float a0 = 0.f, a1 = 0.f;
        for (int j = o0; j < o1; j++) {
            unsigned u = *(const unsigned*)&msg[(long long)j * 64 + 2 * k];
            a0 += bflo(u);
            a1 += bfhi(u);
        }
        float ic = 1.f / fmaxf((float)(o1 - o0), 1.f);
        unsigned xu = *(const unsigned*)&x1[(long long)n * 64 + 2 * k];
        h0 = bflo(xu) + a0 * ic;
        h1 = bfhi(xu) + a1 * ic;
        *(float2*)&h_v[(long long)n * 64 + 2 * k] = make_float2(h0, h1);
    }
    red[hw * 66 + 2 * k] = h0;
    red[hw * 66 + 2 * k + 1] = h1;
    __syncthreads();
    float* nst = nstats + (blockIdx.x & 7) * 128;
    if (tid < 64) {
        float s = 0.f;
        #pragma unroll
        for (int r = 0; r < 8; r++) s += red[r * 66 + tid];
        atomicAdd(&nst[tid], s);
    }
    __syncthreads();
    red[hw * 66 + 2 * k] = h0 * h0;
    red[hw * 66 + 2 * k + 1] = h1 * h1;
    __syncthreads();
    if (tid < 64) {
        float s = 0.f;
        #pragma unroll
        for (int r = 0; r < 8; r++) s += red[r * 66 + tid];
        atomicAdd(&nst[64 + tid], s);
    }
}

// ---------- finalize: stats -> (kmul, kadd) ----------
__global__ void finalize_kernel(const float* __restrict__ nstats, const float* __restrict__ estats,
                                const float* __restrict__ vs, const float* __restrict__ vb,
                                const float* __restrict__ es, const float* __restrict__ eb,
                                float* __restrict__ fin, float invN, float invE) {
    int t = threadIdx.x;   // 128
    const float* st = (t < 64) ? nstats : estats;
    float inv = (t < 64) ? invN : invE;
    int c = t & 63;
    float s = 0.f, q = 0.f;
    #pragma unroll
    for (int r = 0; r < 8; r++) { s += st[r * 128 + c]; q += st[r * 128 + 64 + c]; }
    float mean = s * inv;
    float var = q * inv - mean * mean;
    float rinv = rsqrtf(var + 1e-5f);
    float sc = (t < 64) ? vs[c] : es[c];
    float bi = (t < 64) ? vb[c] : eb[c];
    float kmul = rinv * sc;
    float kadd = bi - mean * kmul;
    int base = (t < 64) ? 0 : 128;
    fin[base + c] = kmul;
    fin[base + 64 + c] = kadd;
}

// ---------- node BN apply ----------
__global__ __launch_bounds__(256)
void node_apply_kernel(const float4* __restrict__ hv4, const float4* __restrict__ xold4,
                       float4* __restrict__ out4, const float* __restrict__ fin, int total) {
    __shared__ float km[64], ka[64];
    if (threadIdx.x < 64) { km[threadIdx.x] = fin[threadIdx.x]; ka[threadIdx.x] = fin[64 + threadIdx.x]; }
    __syncthreads();
    int idx = blockIdx.x * 256 + threadIdx.x;
    if (idx >= total) return;
    int c0 = (idx & 15) * 4;
    float4 h = hv4[idx], xo = xold4[idx];
    float4 m = *(float4*)&km[c0], a = *(float4*)&ka[c0];
    float g0 = h.x * m.x + a.x, g1 = h.y * m.y + a.y, g2 = h.z * m.z + a.z, g3 = h.w * m.w + a.w;
    out4[idx] = make_float4(xo.x + g0 / (1.f + __expf(-g0)),
                            xo.y + g1 / (1.f + __expf(-g1)),
                            xo.z + g2 / (1.f + __expf(-g2)),
                            xo.w + g3 / (1.f + __expf(-g3)));
}

// ---------- edge BN apply ----------
__global__ __launch_bounds__(256)
void edge_bn_kernel(const uint4* __restrict__ he, const float4* __restrict__ w4,
                    float4* __restrict__ out4, const float* __restrict__ fin, long long total) {
    __shared__ float km[64], ka[64];
    if (threadIdx.x < 64) { km[threadIdx.x] = fin[128 + threadIdx.x]; ka[threadIdx.x] = fin[192 + threadIdx.x]; }
    __syncthreads();
    for (long long idx = blockIdx.x * 256LL + threadIdx.x; idx < total; idx += gridDim.x * 256LL) {
        int c0 = (int)(idx & 7) * 8;
        uint4 hp = he[idx];
        float4 wa = w4[idx * 2], wb = w4[idx * 2 + 1];
        float hf[8] = {bflo(hp.x), bfhi(hp.x), bflo(hp.y), bfhi(hp.y),
                       bflo(hp.z), bfhi(hp.z), bflo(hp.w), bfhi(hp.w)};
        float4 m0 = *(float4*)&km[c0], m1 = *(float4*)&km[c0 + 4];
        float4 a0 = *(float4*)&ka[c0], a1 = *(float4*)&ka[c0 + 4];
        float mv[8] = {m0.x, m0.y, m0.z, m0.w, m1.x, m1.y, m1.z, m1.w};
        float av[8] = {a0.x, a0.y, a0.z, a0.w, a1.x, a1.y, a1.z, a1.w};
        float wv[8] = {wa.x, wa.y, wa.z, wa.w, wb.x, wb.y, wb.z, wb.w};
        float o[8];
        #pragma unroll
        for (int j = 0; j < 8; j++) {
            float g = hf[j] * mv[j] + av[j];
            o[j] = wv[j] + g / (1.f + __expf(-g));
        }
        out4[idx * 2]     = make_float4(o[0], o[1], o[2], o[3]);
        out4[idx * 2 + 1] = make_float4(o[4], o[5], o[6], o[7]);
    }
}

// ---------- launch ----------
extern "C" void kernel_launch(void* const* d_in, const int* in_sizes, int n_in,
                              void* d_out, int out_size, void* d_ws, size_t ws_size,
                              hipStream_t stream) {
    const float* x_in  = (const float*)d_in[0];
    const float* ea_in = (const float*)d_in[1];
    const int*   ei    = (const int*)d_in[2];
    const float* v_w   = (const float*)d_in[3];
    const float* v_b   = (const float*)d_in[4];
    const float* e_w   = (const float*)d_in[5];
    const float* e_b   = (const float*)d_in[6];
    const float* vbn_s = (const float*)d_in[7];
    const float* vbn_b = (const float*)d_in[8];
    const float* ebn_s = (const float*)d_in[9];
    const float* ebn_b = (const float*)d_in[10];

    const int Nn = in_sizes[0] / 64;
    const int E  = in_sizes[1] / 64;
    const int L  = in_sizes[3] / (4 * 64 * 64);

    const int* dst = ei;
    const int* src = ei + E;

    // workspace layout
    float* h_v    = (float*)d_ws;                       // [Nn][64] fp32
    float* nstats = h_v + (long long)Nn * 64;           // [L][8][128]
    float* estats = nstats + (long long)L * 1024;       // [L][8][128]
    float* fin    = estats + (long long)L * 1024;       // [4][64]
    __hip_bfloat16* xp      = (__hip_bfloat16*)(fin + 256);          // [4][Nn][64]
    __hip_bfloat16* h_e     = xp + (long long)4 * Nn * 64;           // [E][64]
    __hip_bfloat16* msg_csr = h_e + (long long)E * 64;               // [E][64]
    short* vwp = (short*)(msg_csr + (long long)E * 64); // [L][4][4][2][64][8]
    short* ewp = vwp + (long long)L * 16384;            // [L][4][2][64][8]
    int* cnt  = (int*)(ewp + (long long)L * 4096);      // [Nn]
    int* off  = cnt + Nn;                               // [Nn+1]
    int* perm = off + Nn + 1;                           // [E]

    size_t needed = ((size_t)Nn * 64 + (size_t)L * 2048 + 256) * 4 +
                    ((size_t)4 * Nn * 64 + (size_t)2 * E * 64 + (size_t)L * 20480) * 2 +
                    ((size_t)2 * Nn + 1 + (size_t)E) * 4;
    if (ws_size < needed) return;

    float* out_x = (float*)d_out;
    float* out_w = out_x + (long long)Nn * 64;

    // CSR build + zero stats + pack weights (once per call)
    zero_int_kernel<<<64, 256, 0, stream>>>(cnt, Nn);
    zero_int_kernel<<<8, 256, 0, stream>>>((int*)nstats, L * 2048);
    count_kernel<<<(E + 255) / 256, 256, 0, stream>>>(dst, cnt, E);
    scan_kernel<<<1, 1024, 0, stream>>>(cnt, off, Nn);
    fill_perm_kernel<<<(E + 255) / 256, 256, 0, stream>>>(dst, off, cnt, perm, E);
    pack_kernel<<<(L * 2560 + 255) / 256, 256, 0, stream>>>(v_w, e_w, vwp, ewp, L);

    const __hip_bfloat16* x1 = xp;
    const __hip_bfloat16* x2 = xp + (long long)Nn * 64;
    const __hip_bfloat16* x3 = xp + (long long)2 * Nn * 64;
    const __hip_bfloat16* x4 = xp + (long long)3 * Nn * 64;

    for (int l = 0; l < L; l++) {
        const float* xl = (l == 0) ? x_in : out_x;
        const float* wl = (l == 0) ? ea_in : out_w;
        float* nst = nstats + (long long)l * 1024;
        float* est = estats + (long long)l * 1024;

        // node projections -> xp[4] (bf16, MFMA)
        node_gemm_mfma<<<(Nn + 63) / 64, 256, 0, stream>>>(
            xl, vwp + (long long)l * 16384, v_b + l * 256, xp, Nn);

        // edge GEMM (MFMA) + gathers + h_e + msg scatter + edge stats
        edge_gemm_mfma<<<E / 64, 256, 0, stream>>>(
            wl, ewp + (long long)l * 4096, e_b + l * 64,
            x2, x3, x4, dst, src, perm, h_e, msg_csr, est);

        // h_v = x1 + mean(msg); node stats
        node_finish_kernel<<<(Nn + 7) / 8, 256, 0, stream>>>(
            msg_csr, x1, off, h_v, nst, Nn);

        finalize_kernel<<<1, 128, 0, stream>>>(
            nst, est, vbn_s + l * 64, vbn_b + l * 64,
            ebn_s + l * 64, ebn_b + l * 64, fin, 1.f / (float)Nn, 1.f / (float)E);

        node_apply_kernel<<<(Nn * 16 + 255) / 256, 256, 0, stream>>>(
            (const float4*)h_v, (const float4*)xl, (float4*)out_x, fin, Nn * 16);

        edge_bn_kernel<<<4096, 256, 0, stream>>>(
            (const uint4*)h_e, (const float4*)wl, (float4*)out_w, fin, (long long)E * 8);
    }
}

// Round 5
// 1255.000 us; speedup vs baseline: 3.9332x; 1.0633x over previous
//
#include <hip/hip_runtime.h>
#include <hip/hip_bf16.h>
#include <math.h>

typedef __attribute__((ext_vector_type(8))) short bf16x8;
typedef __attribute__((ext_vector_type(4))) float f32x4;

// ---------- bf16 helpers (bit ops, branchless RNE) ----------
__device__ __forceinline__ float bflo(unsigned u) { return __uint_as_float(u << 16); }
__device__ __forceinline__ float bfhi(unsigned u) { return __uint_as_float(u & 0xffff0000u); }
__device__ __forceinline__ unsigned packbf(float a, float b) {
    unsigned ua = __float_as_uint(a), ub = __float_as_uint(b);
    ua += 0x7fffu + ((ua >> 16) & 1u);
    ub += 0x7fffu + ((ub >> 16) & 1u);
    return (ua >> 16) | (ub & 0xffff0000u);
}

// ---------- setup ----------
__global__ void zero_int_kernel(int* __restrict__ p, int n) {
    int i = blockIdx.x * blockDim.x + threadIdx.x;
    int s = gridDim.x * blockDim.x;
    for (; i < n; i += s) p[i] = 0;
}

__global__ void count_kernel(const int* __restrict__ dst, int* __restrict__ cnt, int E) {
    int e = blockIdx.x * blockDim.x + threadIdx.x;
    if (e < E) atomicAdd(&cnt[dst[e]], 1);
}

__global__ __launch_bounds__(1024)
void scan_kernel(const int* __restrict__ cnt, int* __restrict__ off, int n) {
    __shared__ int wsum[16];
    __shared__ int carry;
    int tid = threadIdx.x, lane = tid & 63, wid = tid >> 6;
    if (tid == 0) carry = 0;
    __syncthreads();
    for (int base = 0; base < n; base += 1024) {
        int i = base + tid;
        int v = (i < n) ? cnt[i] : 0;
        int sc = v;
        #pragma unroll
        for (int s = 1; s < 64; s <<= 1) {
            int t = __shfl_up(sc, (unsigned)s, 64);
            if (lane >= s) sc += t;
        }
        if (lane == 63) wsum[wid] = sc;
        __syncthreads();
        int woff = 0;
        for (int k = 0; k < wid; k++) woff += wsum[k];
        int inc = carry + woff + sc;
        if (i < n) off[i + 1] = inc;
        if (i == 0) off[0] = 0;
        __syncthreads();
        if (tid == 0) {
            int t = 0;
            for (int k = 0; k < 16; k++) t += wsum[k];
            carry += t;
        }
        __syncthreads();
    }
}

// eidx[slot] = edge id (CSR order); consumes cnt (leaves zeros)
__global__ void fill_eidx_kernel(const int* __restrict__ dst, const int* __restrict__ off,
                                 int* __restrict__ cnt, int* __restrict__ eidx, int E) {
    int e = blockIdx.x * blockDim.x + threadIdx.x;
    if (e < E) {
        int d = dst[e];
        int pos = atomicSub(&cnt[d], 1) - 1;
        eidx[off[d] + pos] = e;
    }
}

// ---------- pack weights into MFMA A-operand fragments (W^T, bf16) ----------
__global__ void pack_kernel(const float* __restrict__ v_w, const float* __restrict__ e_w,
                            short* __restrict__ vwp, short* __restrict__ ewp, int L) {
    int t = blockIdx.x * blockDim.x + threadIdx.x;
    if (t >= L * 5 * 4 * 2 * 64) return;
    int lane = t & 63;
    int ks = (t >> 6) & 1;
    int ft = (t >> 7) & 3;
    int mat = t >> 9;
    int layer = mat / 5, mi = mat % 5;
    const float* W = (mi < 4) ? (v_w + (long long)(layer * 4 + mi) * 4096)
                              : (e_w + (long long)layer * 4096);
    int m = ft * 16 + (lane & 15);
    int k0 = ks * 32 + (lane >> 4) * 8;
    short* dstp = (mi < 4)
        ? vwp + ((((long long)(layer * 4 + mi) * 4 + ft) * 2 + ks) * 64 + lane) * 8
        : ewp + ((((long long)layer * 4 + ft) * 2 + ks) * 64 + lane) * 8;
    #pragma unroll
    for (int j = 0; j < 8; j++) {
        unsigned u = __float_as_uint(W[(k0 + j) * 64 + m]);
        u += 0x7fffu + ((u >> 16) & 1u);
        dstp[j] = (short)(u >> 16);
    }
}

// ---------- node GEMM (MFMA): xp[g][n][f] = bf16(x@v_w[g] + v_b[g]) ----------
__global__ __launch_bounds__(256)
void node_gemm_mfma(const float* __restrict__ X, const short* __restrict__ vwp,
                    const float* __restrict__ vb, __hip_bfloat16* __restrict__ xp,
                    int Nn) {
    __shared__ short Xs[64 * 64];
    int tid = threadIdx.x;
    long long row0 = (long long)blockIdx.x * 64;

    {
        int r = tid >> 2, cq = tid & 3;
        long long row = row0 + r;
        float4 v0 = {0,0,0,0}, v1 = {0,0,0,0}, v2 = {0,0,0,0}, v3 = {0,0,0,0};
        if (row < Nn) {
            const float* sp = X + row * 64 + cq * 16;
            v0 = *(const float4*)(sp);     v1 = *(const float4*)(sp + 4);
            v2 = *(const float4*)(sp + 8); v3 = *(const float4*)(sp + 12);
        }
        uint4 w0, w1;
        w0.x = packbf(v0.x, v0.y); w0.y = packbf(v0.z, v0.w);
        w0.z = packbf(v1.x, v1.y); w0.w = packbf(v1.z, v1.w);
        w1.x = packbf(v2.x, v2.y); w1.y = packbf(v2.z, v2.w);
        w1.z = packbf(v3.x, v3.y); w1.w = packbf(v3.z, v3.w);
        int base = r * 128 + cq * 32, swz = (r & 7) << 4;
        *(uint4*)((char*)Xs + (base ^ swz)) = w0;
        *(uint4*)((char*)Xs + ((base + 16) ^ swz)) = w1;
    }
    __syncthreads();

    int l = tid & 63, wv = tid >> 6;
    int rl = wv * 16 + (l & 15);
    long long node = row0 + rl;
    bf16x8 bfr[2];
    #pragma unroll
    for (int ks = 0; ks < 2; ks++) {
        int off = (rl * 128 + ks * 64 + (l >> 4) * 16) ^ ((rl & 7) << 4);
        bfr[ks] = *(bf16x8*)((char*)Xs + off);
    }
    int q4 = (l >> 4) * 4;
    bool valid = node < Nn;
    for (int g = 0; g < 4; g++) {
        f32x4 acc[4];
        #pragma unroll
        for (int ft = 0; ft < 4; ft++) {
            acc[ft] = f32x4{0.f, 0.f, 0.f, 0.f};
            #pragma unroll
            for (int ks = 0; ks < 2; ks++) {
                bf16x8 a = *(const bf16x8*)(vwp + (((long long)(g * 4 + ft) * 2 + ks) * 64 + l) * 8);
                acc[ft] = __builtin_amdgcn_mfma_f32_16x16x32_bf16(a, bfr[ks], acc[ft], 0, 0, 0);
            }
        }
        if (valid) {
            #pragma unroll
            for (int ft = 0; ft < 4; ft++) {
                int f0 = ft * 16 + q4;
                float4 bv = *(const float4*)&vb[g * 64 + f0];
                uint2 o;
                o.x = packbf(acc[ft][0] + bv.x, acc[ft][1] + bv.y);
                o.y = packbf(acc[ft][2] + bv.z, acc[ft][3] + bv.w);
                *(uint2*)&xp[((long long)g * Nn + node) * 64 + f0] = o;
            }
        }
    }
}

// ---------- edge GEMM (MFMA) + gathers + h_e + msg (edge-order) + edge stats ----------
// WF32: w-state input is fp32 (layer 0) else bf16.
template <bool WF32>
__global__ __launch_bounds__(256)
void edge_gemm_mfma(const void* __restrict__ Wl_, const short* __restrict__ ewp,
                    const float* __restrict__ eb,
                    const __hip_bfloat16* __restrict__ x2, const __hip_bfloat16* __restrict__ x3,
                    const __hip_bfloat16* __restrict__ x4,
                    const int* __restrict__ dst, const int* __restrict__ src,
                    __hip_bfloat16* __restrict__ h_e, __hip_bfloat16* __restrict__ msg,
                    float* __restrict__ estats) {
    __shared__ short Ws[64 * 64];
    __shared__ int dstl[64], srcl[64];
    __shared__ float sred[2][4][64];
    int tid = threadIdx.x;
    long long row0 = (long long)blockIdx.x * 64;

    {   // stage w tile -> bf16 LDS (swizzled); E multiple of 64
        int r = tid >> 2, cq = tid & 3;
        int base = r * 128 + cq * 32, swz = (r & 7) << 4;
        uint4 w0, w1;
        if (WF32) {
            const float* sp = (const float*)Wl_ + (row0 + r) * 64 + cq * 16;
            float4 v0 = *(const float4*)(sp),     v1 = *(const float4*)(sp + 4);
            float4 v2 = *(const float4*)(sp + 8), v3 = *(const float4*)(sp + 12);
            w0.x = packbf(v0.x, v0.y); w0.y = packbf(v0.z, v0.w);
            w0.z = packbf(v1.x, v1.y); w0.w = packbf(v1.z, v1.w);
            w1.x = packbf(v2.x, v2.y); w1.y = packbf(v2.z, v2.w);
            w1.z = packbf(v3.x, v3.y); w1.w = packbf(v3.z, v3.w);
        } else {
            const unsigned short* sp = (const unsigned short*)Wl_ + (row0 + r) * 64 + cq * 16;
            w0 = *(const uint4*)(sp);
            w1 = *(const uint4*)(sp + 8);
        }
        *(uint4*)((char*)Ws + (base ^ swz)) = w0;
        *(uint4*)((char*)Ws + ((base + 16) ^ swz)) = w1;
        if (tid < 64) {
            dstl[tid] = dst[row0 + tid];
            srcl[tid] = src[row0 + tid];
        }
    }
    __syncthreads();

    int l = tid & 63, wv = tid >> 6;
    int rl = wv * 16 + (l & 15);
    long long e = row0 + rl;
    bf16x8 bfr[2];
    #pragma unroll
    for (int ks = 0; ks < 2; ks++) {
        int off = (rl * 128 + ks * 64 + (l >> 4) * 16) ^ ((rl & 7) << 4);
        bfr[ks] = *(bf16x8*)((char*)Ws + off);
    }
    int q4 = (l >> 4) * 4;
    int de = dstl[rl], se = srcl[rl];

    f32x4 acc[4];
    #pragma unroll
    for (int ft = 0; ft < 4; ft++) {
        acc[ft] = f32x4{0.f, 0.f, 0.f, 0.f};
        #pragma unroll
        for (int ks = 0; ks < 2; ks++) {
            bf16x8 a = *(const bf16x8*)(ewp + (((long long)ft * 2 + ks) * 64 + l) * 8);
            acc[ft] = __builtin_amdgcn_mfma_f32_16x16x32_bf16(a, bfr[ks], acc[ft], 0, 0, 0);
        }
    }

    #pragma unroll
    for (int ft = 0; ft < 4; ft++) {
        int f0 = ft * 16 + q4;
        float4 bv = *(const float4*)&eb[f0];
        uint2 g3 = *(const uint2*)&x3[(long long)de * 64 + f0];
        uint2 g4 = *(const uint2*)&x4[(long long)se * 64 + f0];
        uint2 g2 = *(const uint2*)&x2[(long long)se * 64 + f0];
        int woff = (rl * 128 + f0 * 2) ^ ((rl & 7) << 4);
        uint2 wu = *(uint2*)((char*)Ws + woff);
        float h0 = acc[ft][0] + bv.x + bflo(g3.x) + bflo(g4.x);
        float h1 = acc[ft][1] + bv.y + bfhi(g3.x) + bfhi(g4.x);
        float h2 = acc[ft][2] + bv.z + bflo(g3.y) + bflo(g4.y);
        float h3 = acc[ft][3] + bv.w + bfhi(g3.y) + bfhi(g4.y);
        uint2 ho;
        ho.x = packbf(h0, h1); ho.y = packbf(h2, h3);
        *(uint2*)&h_e[e * 64 + f0] = ho;
        float m0 = bflo(g2.x) / (1.f + __expf(-bflo(wu.x)));
        float m1 = bfhi(g2.x) / (1.f + __expf(-bfhi(wu.x)));
        float m2 = bflo(g2.y) / (1.f + __expf(-bflo(wu.y)));
        float m3 = bfhi(g2.y) / (1.f + __expf(-bfhi(wu.y)));
        uint2 mo;
        mo.x = packbf(m0, m1); mo.y = packbf(m2, m3);
        *(uint2*)&msg[e * 64 + f0] = mo;   // edge-order, coalesced full lines
        float s0 = h0, s1 = h1, s2 = h2, s3 = h3;
        float p0 = h0 * h0, p1 = h1 * h1, p2 = h2 * h2, p3 = h3 * h3;
        #pragma unroll
        for (int d = 1; d < 16; d <<= 1) {
            s0 += __shfl_xor(s0, d); s1 += __shfl_xor(s1, d);
            s2 += __shfl_xor(s2, d); s3 += __shfl_xor(s3, d);
            p0 += __shfl_xor(p0, d); p1 += __shfl_xor(p1, d);
            p2 += __shfl_xor(p2, d); p3 += __shfl_xor(p3, d);
        }
        if ((l & 15) == 0) {
            sred[0][wv][f0 + 0] = s0; sred[0][wv][f0 + 1] = s1;
            sred[0][wv][f0 + 2] = s2; sred[0][wv][f0 + 3] = s3;
            sred[1][wv][f0 + 0] = p0; sred[1][wv][f0 + 1] = p1;
            sred[1][wv][f0 + 2] = p2; sred[1][wv][f0 + 3] = p3;
        }
    }
    __syncthreads();
    if (tid < 128) {
        int which = tid >> 6, f = tid & 63;
        float s = sred[which][0][f] + sred[which][1][f] + sred[which][2][f] + sred[which][3][f];
        atomicAdd(&estats[(blockIdx.x & 7) * 128 + which * 64 + f], s);
    }
}

// ---------- node finish: h = x1 + mean over CSR-gathered msg rows; node BN stats ----------
// half-wave (32 lanes) per node, lane k handles features 2k, 2k+1.
__global__ __launch_bounds__(256)
void node_finish_kernel(const __hip_bfloat16* __restrict__ msg, const __hip_bfloat16* __restrict__ x1,
                        const int* __restrict__ off, const int* __restrict__ eidx,
                        float* __restrict__ h_v, float* __restrict__ nstats, int Nn) {
    __shared__ float red[8 * 66];
    int tid = threadIdx.x;
    int hw = tid >> 5, k = tid & 31;
    int n = blockIdx.x * 8 + hw;
    float h0 = 0.f, h1 = 0.f;
    if (n < Nn) {
        int o0 = off[n], o1 = off[n + 1];
        float a0 = 0.f, a1 = 0.f;
        for (int j = o0; j < o1; j++) {
            int e = eidx[j];
            unsigned u = *(const unsigned*)&msg[(long long)e * 64 + 2 * k];
            a0 += bflo(u);
            a1 += bfhi(u);
        }
        float ic = 1.f / fmaxf((float)(o1 - o0), 1.f);
        unsigned xu = *(const unsigned*)&x1[(long long)n * 64 + 2 * k];
        h0 = bflo(xu) + a0 * ic;
        h1 = bfhi(xu) + a1 * ic;
        *(float2*)&h_v[(long long)n * 64 + 2 * k] = make_float2(h0, h1);
    }
    red[hw * 66 + 2 * k] = h0;
    red[hw * 66 + 2 * k + 1] = h1;
    __syncthreads();
    float* nst = nstats + (blockIdx.x & 7) * 128;
    if (tid < 64) {
        float s = 0.f;
        #pragma unroll
        for (int r = 0; r < 8; r++) s += red[r * 66 + tid];
        atomicAdd(&nst[tid], s);
    }
    __syncthreads();
    red[hw * 66 + 2 * k] = h0 * h0;
    red[hw * 66 + 2 * k + 1] = h1 * h1;
    __syncthreads();
    if (tid < 64) {
        float s = 0.f;
        #pragma unroll
        for (int r = 0; r < 8; r++) s += red[r * 66 + tid];
        atomicAdd(&nst[64 + tid], s);
    }
}

// ---------- finalize: stats -> (kmul, kadd) ----------
__global__ void finalize_kernel(const float* __restrict__ nstats, const float* __restrict__ estats,
                                const float* __restrict__ vs, const float* __restrict__ vb,
                                const float* __restrict__ es, const float* __restrict__ eb,
                                float* __restrict__ fin, float invN, float invE) {
    int t = threadIdx.x;   // 128
    const float* st = (t < 64) ? nstats : estats;
    float inv = (t < 64) ? invN : invE;
    int c = t & 63;
    float s = 0.f, q = 0.f;
    #pragma unroll
    for (int r = 0; r < 8; r++) { s += st[r * 128 + c]; q += st[r * 128 + 64 + c]; }
    float mean = s * inv;
    float var = q * inv - mean * mean;
    float rinv = rsqrtf(var + 1e-5f);
    float sc = (t < 64) ? vs[c] : es[c];
    float bi = (t < 64) ? vb[c] : eb[c];
    float kmul = rinv * sc;
    float kadd = bi - mean * kmul;
    int base = (t < 64) ? 0 : 128;
    fin[base + c] = kmul;
    fin[base + 64 + c] = kadd;
}

// ---------- node BN apply ----------
__global__ __launch_bounds__(256)
void node_apply_kernel(const float4* __restrict__ hv4, const float4* __restrict__ xold4,
                       float4* __restrict__ out4, const float* __restrict__ fin, int total) {
    __shared__ float km[64], ka[64];
    if (threadIdx.x < 64) { km[threadIdx.x] = fin[threadIdx.x]; ka[threadIdx.x] = fin[64 + threadIdx.x]; }
    __syncthreads();
    int idx = blockIdx.x * 256 + threadIdx.x;
    if (idx >= total) return;
    int c0 = (idx & 15) * 4;
    float4 h = hv4[idx], xo = xold4[idx];
    float4 m = *(float4*)&km[c0], a = *(float4*)&ka[c0];
    float g0 = h.x * m.x + a.x, g1 = h.y * m.y + a.y, g2 = h.z * m.z + a.z, g3 = h.w * m.w + a.w;
    out4[idx] = make_float4(xo.x + g0 / (1.f + __expf(-g0)),
                            xo.y + g1 / (1.f + __expf(-g1)),
                            xo.z + g2 / (1.f + __expf(-g2)),
                            xo.w + g3 / (1.f + __expf(-g3)));
}

// ---------- edge update: w_new = w_old + silu(h_e*kmul + kadd) ----------
// RF32: w_old fp32 (layer 0). OUT32: write fp32 to d_out (last layer) else bf16 state.
template <bool RF32, bool OUT32>
__global__ __launch_bounds__(256)
void edge_update_kernel(const uint4* __restrict__ he, const void* __restrict__ wold_,
                        void* __restrict__ wnew_, const float* __restrict__ fin, long long total) {
    __shared__ float km[64], ka[64];
    if (threadIdx.x < 64) { km[threadIdx.x] = fin[128 + threadIdx.x]; ka[threadIdx.x] = fin[192 + threadIdx.x]; }
    __syncthreads();
    for (long long idx = blockIdx.x * 256LL + threadIdx.x; idx < total; idx += gridDim.x * 256LL) {
        int c0 = (int)(idx & 7) * 8;
        uint4 hp = he[idx];
        float hf[8] = {bflo(hp.x), bfhi(hp.x), bflo(hp.y), bfhi(hp.y),
                       bflo(hp.z), bfhi(hp.z), bflo(hp.w), bfhi(hp.w)};
        float wv[8];
        if (RF32) {
            const float4* w4 = (const float4*)wold_;
            float4 wa = w4[idx * 2], wb = w4[idx * 2 + 1];
            wv[0] = wa.x; wv[1] = wa.y; wv[2] = wa.z; wv[3] = wa.w;
            wv[4] = wb.x; wv[5] = wb.y; wv[6] = wb.z; wv[7] = wb.w;
        } else {
            uint4 wu = ((const uint4*)wold_)[idx];
            wv[0] = bflo(wu.x); wv[1] = bfhi(wu.x); wv[2] = bflo(wu.y); wv[3] = bfhi(wu.y);
            wv[4] = bflo(wu.z); wv[5] = bfhi(wu.z); wv[6] = bflo(wu.w); wv[7] = bfhi(wu.w);
        }
        float4 m0 = *(float4*)&km[c0], m1 = *(float4*)&km[c0 + 4];
        float4 a0 = *(float4*)&ka[c0], a1 = *(float4*)&ka[c0 + 4];
        float mv[8] = {m0.x, m0.y, m0.z, m0.w, m1.x, m1.y, m1.z, m1.w};
        float av[8] = {a0.x, a0.y, a0.z, a0.w, a1.x, a1.y, a1.z, a1.w};
        float o[8];
        #pragma unroll
        for (int j = 0; j < 8; j++) {
            float g = hf[j] * mv[j] + av[j];
            o[j] = wv[j] + g / (1.f + __expf(-g));
        }
        if (OUT32) {
            float4* out4 = (float4*)wnew_;
            out4[idx * 2]     = make_float4(o[0], o[1], o[2], o[3]);
            out4[idx * 2 + 1] = make_float4(o[4], o[5], o[6], o[7]);
        } else {
            uint4 wo;
            wo.x = packbf(o[0], o[1]); wo.y = packbf(o[2], o[3]);
            wo.z = packbf(o[4], o[5]); wo.w = packbf(o[6], o[7]);
            ((uint4*)wnew_)[idx] = wo;
        }
    }
}

// ---------- launch ----------
extern "C" void kernel_launch(void* const* d_in, const int* in_sizes, int n_in,
                              void* d_out, int out_size, void* d_ws, size_t ws_size,
                              hipStream_t stream) {
    const float* x_in  = (const float*)d_in[0];
    const float* ea_in = (const float*)d_in[1];
    const int*   ei    = (const int*)d_in[2];
    const float* v_w   = (const float*)d_in[3];
    const float* v_b   = (const float*)d_in[4];
    const float* e_w   = (const float*)d_in[5];
    const float* e_b   = (const float*)d_in[6];
    const float* vbn_s = (const float*)d_in[7];
    const float* vbn_b = (const float*)d_in[8];
    const float* ebn_s = (const float*)d_in[9];
    const float* ebn_b = (const float*)d_in[10];

    const int Nn = in_sizes[0] / 64;
    const int E  = in_sizes[1] / 64;
    const int L  = in_sizes[3] / (4 * 64 * 64);

    const int* dst = ei;
    const int* src = ei + E;

    // workspace layout
    float* h_v    = (float*)d_ws;                       // [Nn][64] fp32
    float* nstats = h_v + (long long)Nn * 64;           // [L][8][128]
    float* estats = nstats + (long long)L * 1024;       // [L][8][128]
    float* fin    = estats + (long long)L * 1024;       // [4][64]
    __hip_bfloat16* xp   = (__hip_bfloat16*)(fin + 256);        // [4][Nn][64]
    __hip_bfloat16* h_e  = xp + (long long)4 * Nn * 64;         // [E][64]
    __hip_bfloat16* msg  = h_e + (long long)E * 64;             // [E][64]
    __hip_bfloat16* w_bf = msg + (long long)E * 64;             // [E][64] bf16 state
    short* vwp = (short*)(w_bf + (long long)E * 64);    // [L][4][4][2][64][8]
    short* ewp = vwp + (long long)L * 16384;            // [L][4][2][64][8]
    int* cnt  = (int*)(ewp + (long long)L * 4096);      // [Nn]
    int* off  = cnt + Nn;                               // [Nn+1]
    int* eidx = off + Nn + 1;                           // [E]

    size_t needed = ((size_t)Nn * 64 + (size_t)L * 2048 + 256) * 4 +
                    ((size_t)4 * Nn * 64 + (size_t)3 * E * 64 + (size_t)L * 20480) * 2 +
                    ((size_t)2 * Nn + 1 + (size_t)E) * 4;
    if (ws_size < needed) return;

    float* out_x = (float*)d_out;
    float* out_w = out_x + (long long)Nn * 64;

    // CSR build + zero stats + pack weights (once per call)
    zero_int_kernel<<<64, 256, 0, stream>>>(cnt, Nn);
    zero_int_kernel<<<8, 256, 0, stream>>>((int*)nstats, L * 2048);
    count_kernel<<<(E + 255) / 256, 256, 0, stream>>>(dst, cnt, E);
    scan_kernel<<<1, 1024, 0, stream>>>(cnt, off, Nn);
    fill_eidx_kernel<<<(E + 255) / 256, 256, 0, stream>>>(dst, off, cnt, eidx, E);
    pack_kernel<<<(L * 2560 + 255) / 256, 256, 0, stream>>>(v_w, e_w, vwp, ewp, L);

    const __hip_bfloat16* x1 = xp;
    const __hip_bfloat16* x2 = xp + (long long)Nn * 64;
    const __hip_bfloat16* x3 = xp + (long long)2 * Nn * 64;
    const __hip_bfloat16* x4 = xp + (long long)3 * Nn * 64;

    for (int l = 0; l < L; l++) {
        const float* xl = (l == 0) ? x_in : out_x;
        bool wf32 = (l == 0);
        bool last = (l == L - 1);
        float* nst = nstats + (long long)l * 1024;
        float* est = estats + (long long)l * 1024;

        // node projections -> xp[4] (bf16, MFMA)
        node_gemm_mfma<<<(Nn + 63) / 64, 256, 0, stream>>>(
            xl, vwp + (long long)l * 16384, v_b + l * 256, xp, Nn);

        // edge GEMM (MFMA) + gathers + h_e + msg (edge order) + edge stats
        if (wf32)
            edge_gemm_mfma<true><<<E / 64, 256, 0, stream>>>(
                ea_in, ewp + (long long)l * 4096, e_b + l * 64,
                x2, x3, x4, dst, src, h_e, msg, est);
        else
            edge_gemm_mfma<false><<<E / 64, 256, 0, stream>>>(
                w_bf, ewp + (long long)l * 4096, e_b + l * 64,
                x2, x3, x4, dst, src, h_e, msg, est);

        // h_v = x1 + mean(gathered msg); node stats
        node_finish_kernel<<<(Nn + 7) / 8, 256, 0, stream>>>(
            msg, x1, off, eidx, h_v, nst, Nn);

        finalize_kernel<<<1, 128, 0, stream>>>(
            nst, est, vbn_s + l * 64, vbn_b + l * 64,
            ebn_s + l * 64, ebn_b + l * 64, fin, 1.f / (float)Nn, 1.f / (float)E);

        node_apply_kernel<<<(Nn * 16 + 255) / 256, 256, 0, stream>>>(
            (const float4*)h_v, (const float4*)xl, (float4*)out_x, fin, Nn * 16);

        // edge update
        if (wf32 && !last)
            edge_update_kernel<true, false><<<4096, 256, 0, stream>>>(
                (const uint4*)h_e, ea_in, w_bf, fin, (long long)E * 8);
        else if (wf32 && last)
            edge_update_kernel<true, true><<<4096, 256, 0, stream>>>(
                (const uint4*)h_e, ea_in, out_w, fin, (long long)E * 8);
        else if (!wf32 && !last)
            edge_update_kernel<false, false><<<4096, 256, 0, stream>>>(
                (const uint4*)h_e, w_bf, w_bf, fin, (long long)E * 8);
        else
            edge_update_kernel<false, true><<<4096, 256, 0, stream>>>(
                (const uint4*)h_e, w_bf, out_w, fin, (long long)E * 8);
    }
}

// Round 6
// 1020.341 us; speedup vs baseline: 4.8378x; 1.2300x over previous
//
#include <hip/hip_runtime.h>
#include <hip/hip_bf16.h>
#include <math.h>

typedef __attribute__((ext_vector_type(8))) short bf16x8;
typedef __attribute__((ext_vector_type(4))) float f32x4;

// ---------- bf16 helpers ----------
__device__ __forceinline__ float bflo(unsigned u) { return __uint_as_float(u << 16); }
__device__ __forceinline__ float bfhi(unsigned u) { return __uint_as_float(u & 0xffff0000u); }
__device__ __forceinline__ unsigned packbf(float a, float b) {
    unsigned ua = __float_as_uint(a), ub = __float_as_uint(b);
    ua += 0x7fffu + ((ua >> 16) & 1u);
    ub += 0x7fffu + ((ub >> 16) & 1u);
    return (ua >> 16) | (ub & 0xffff0000u);
}

// ---------- setup ----------
__global__ void zero_int_kernel(int* __restrict__ p, int n) {
    int i = blockIdx.x * blockDim.x + threadIdx.x;
    int s = gridDim.x * blockDim.x;
    for (; i < n; i += s) p[i] = 0;
}

__global__ void count_kernel(const int* __restrict__ dst, int* __restrict__ cnt, int E) {
    int e = blockIdx.x * blockDim.x + threadIdx.x;
    if (e < E) atomicAdd(&cnt[dst[e]], 1);
}

__global__ __launch_bounds__(1024)
void scan_kernel(const int* __restrict__ cnt, int* __restrict__ off, int n) {
    __shared__ int wsum[16];
    __shared__ int carry;
    int tid = threadIdx.x, lane = tid & 63, wid = tid >> 6;
    if (tid == 0) carry = 0;
    __syncthreads();
    for (int base = 0; base < n; base += 1024) {
        int i = base + tid;
        int v = (i < n) ? cnt[i] : 0;
        int sc = v;
        #pragma unroll
        for (int s = 1; s < 64; s <<= 1) {
            int t = __shfl_up(sc, (unsigned)s, 64);
            if (lane >= s) sc += t;
        }
        if (lane == 63) wsum[wid] = sc;
        __syncthreads();
        int woff = 0;
        for (int k = 0; k < wid; k++) woff += wsum[k];
        int inc = carry + woff + sc;
        if (i < n) off[i + 1] = inc;
        if (i == 0) off[0] = 0;
        __syncthreads();
        if (tid == 0) {
            int t = 0;
            for (int k = 0; k < 16; k++) t += wsum[k];
            carry += t;
        }
        __syncthreads();
    }
}

__global__ void fill_eidx_kernel(const int* __restrict__ dst, const int* __restrict__ off,
                                 int* __restrict__ cnt, int* __restrict__ eidx, int E) {
    int e = blockIdx.x * blockDim.x + threadIdx.x;
    if (e < E) {
        int d = dst[e];
        int pos = atomicSub(&cnt[d], 1) - 1;
        eidx[off[d] + pos] = e;
    }
}

// ---------- pack weights into MFMA A-operand fragments (W^T, bf16) ----------
__global__ void pack_kernel(const float* __restrict__ v_w, const float* __restrict__ e_w,
                            short* __restrict__ vwp, short* __restrict__ ewp, int L) {
    int t = blockIdx.x * blockDim.x + threadIdx.x;
    if (t >= L * 5 * 4 * 2 * 64) return;
    int lane = t & 63;
    int ks = (t >> 6) & 1;
    int ft = (t >> 7) & 3;
    int mat = t >> 9;
    int layer = mat / 5, mi = mat % 5;
    const float* W = (mi < 4) ? (v_w + (long long)(layer * 4 + mi) * 4096)
                              : (e_w + (long long)layer * 4096);
    int m = ft * 16 + (lane & 15);
    int k0 = ks * 32 + (lane >> 4) * 8;
    short* dstp = (mi < 4)
        ? vwp + ((((long long)(layer * 4 + mi) * 4 + ft) * 2 + ks) * 64 + lane) * 8
        : ewp + ((((long long)layer * 4 + ft) * 2 + ks) * 64 + lane) * 8;
    #pragma unroll
    for (int j = 0; j < 8; j++) {
        unsigned u = __float_as_uint(W[(k0 + j) * 64 + m]);
        u += 0x7fffu + ((u >> 16) & 1u);
        dstp[j] = (short)(u >> 16);
    }
}

// ---------- node GEMM (MFMA): xp[g][n][f] = bf16(x@v_w[g] + v_b[g]) ----------
// Epilogue routed through LDS so global stores are contiguous full lines.
__global__ __launch_bounds__(256)
void node_gemm_mfma(const float* __restrict__ X, const short* __restrict__ vwp,
                    const float* __restrict__ vb, __hip_bfloat16* __restrict__ xp,
                    int Nn) {
    __shared__ short Xs[64 * 64];
    __shared__ short Hs[4][64 * 64];   // 32 KB: per-group bf16 result tile
    int tid = threadIdx.x;
    long long row0 = (long long)blockIdx.x * 64;

    {
        int r = tid >> 2, cq = tid & 3;
        long long row = row0 + r;
        float4 v0 = {0,0,0,0}, v1 = {0,0,0,0}, v2 = {0,0,0,0}, v3 = {0,0,0,0};
        if (row < Nn) {
            const float* sp = X + row * 64 + cq * 16;
            v0 = *(const float4*)(sp);     v1 = *(const float4*)(sp + 4);
            v2 = *(const float4*)(sp + 8); v3 = *(const float4*)(sp + 12);
        }
        uint4 w0, w1;
        w0.x = packbf(v0.x, v0.y); w0.y = packbf(v0.z, v0.w);
        w0.z = packbf(v1.x, v1.y); w0.w = packbf(v1.z, v1.w);
        w1.x = packbf(v2.x, v2.y); w1.y = packbf(v2.z, v2.w);
        w1.z = packbf(v3.x, v3.y); w1.w = packbf(v3.z, v3.w);
        int base = r * 128 + cq * 32, swz = (r & 7) << 4;
        *(uint4*)((char*)Xs + (base ^ swz)) = w0;
        *(uint4*)((char*)Xs + ((base + 16) ^ swz)) = w1;
    }
    __syncthreads();

    int l = tid & 63, wv = tid >> 6;
    int rl = wv * 16 + (l & 15);
    bf16x8 bfr[2];
    #pragma unroll
    for (int ks = 0; ks < 2; ks++) {
        int off = (rl * 128 + ks * 64 + (l >> 4) * 16) ^ ((rl & 7) << 4);
        bfr[ks] = *(bf16x8*)((char*)Xs + off);
    }
    int q4 = (l >> 4) * 4;
    for (int g = 0; g < 4; g++) {
        #pragma unroll
        for (int ft = 0; ft < 4; ft++) {
            f32x4 acc = f32x4{0.f, 0.f, 0.f, 0.f};
            #pragma unroll
            for (int ks = 0; ks < 2; ks++) {
                bf16x8 a = *(const bf16x8*)(vwp + (((long long)(g * 4 + ft) * 2 + ks) * 64 + l) * 8);
                acc = __builtin_amdgcn_mfma_f32_16x16x32_bf16(a, bfr[ks], acc, 0, 0, 0);
            }
            int f0 = ft * 16 + q4;
            float4 bv = *(const float4*)&vb[g * 64 + f0];
            uint2 o;
            o.x = packbf(acc[0] + bv.x, acc[1] + bv.y);
            o.y = packbf(acc[2] + bv.z, acc[3] + bv.w);
            int hoff = (rl * 128 + f0 * 2) ^ ((rl & 7) << 4);
            *(uint2*)((char*)Hs[g] + hoff) = o;
        }
    }
    __syncthreads();
    // coalesced stores: thread t -> node row0+(t>>2), features (t&3)*16..+15
    int r = tid >> 2, cc = (tid & 3) * 16;
    long long node = row0 + r;
    if (node < Nn) {
        int swz = (r & 7) << 4;
        #pragma unroll
        for (int g = 0; g < 4; g++) {
            uint4 a = *(uint4*)((char*)Hs[g] + ((r * 128 + cc * 2) ^ swz));
            uint4 b = *(uint4*)((char*)Hs[g] + ((r * 128 + cc * 2 + 16) ^ swz));
            __hip_bfloat16* op = xp + ((long long)g * Nn + node) * 64 + cc;
            *(uint4*)op = a;
            *(uint4*)(op + 8) = b;
        }
    }
}

// ---------- edge GEMM (MFMA) + gathers + h_e (coalesced) + edge stats ----------
template <bool WF32>
__global__ __launch_bounds__(256)
void edge_gemm_mfma(const void* __restrict__ Wl_, const short* __restrict__ ewp,
                    const float* __restrict__ eb,
                    const __hip_bfloat16* __restrict__ x3, const __hip_bfloat16* __restrict__ x4,
                    const int* __restrict__ dst, const int* __restrict__ src,
                    __hip_bfloat16* __restrict__ h_e, float* __restrict__ estats) {
    __shared__ short Ws[64 * 64];
    __shared__ short Hs[64 * 64];
    __shared__ int dstl[64], srcl[64];
    __shared__ float sred[2][4][64];
    int tid = threadIdx.x;
    long long row0 = (long long)blockIdx.x * 64;

    {
        int r = tid >> 2, cq = tid & 3;
        int base = r * 128 + cq * 32, swz = (r & 7) << 4;
        uint4 w0, w1;
        if (WF32) {
            const float* sp = (const float*)Wl_ + (row0 + r) * 64 + cq * 16;
            float4 v0 = *(const float4*)(sp),     v1 = *(const float4*)(sp + 4);
            float4 v2 = *(const float4*)(sp + 8), v3 = *(const float4*)(sp + 12);
            w0.x = packbf(v0.x, v0.y); w0.y = packbf(v0.z, v0.w);
            w0.z = packbf(v1.x, v1.y); w0.w = packbf(v1.z, v1.w);
            w1.x = packbf(v2.x, v2.y); w1.y = packbf(v2.z, v2.w);
            w1.z = packbf(v3.x, v3.y); w1.w = packbf(v3.z, v3.w);
        } else {
            const unsigned short* sp = (const unsigned short*)Wl_ + (row0 + r) * 64 + cq * 16;
            w0 = *(const uint4*)(sp);
            w1 = *(const uint4*)(sp + 8);
        }
        *(uint4*)((char*)Ws + (base ^ swz)) = w0;
        *(uint4*)((char*)Ws + ((base + 16) ^ swz)) = w1;
        if (tid < 64) {
            dstl[tid] = dst[row0 + tid];
            srcl[tid] = src[row0 + tid];
        }
    }
    __syncthreads();

    int l = tid & 63, wv = tid >> 6;
    int rl = wv * 16 + (l & 15);
    bf16x8 bfr[2];
    #pragma unroll
    for (int ks = 0; ks < 2; ks++) {
        int off = (rl * 128 + ks * 64 + (l >> 4) * 16) ^ ((rl & 7) << 4);
        bfr[ks] = *(bf16x8*)((char*)Ws + off);
    }
    int q4 = (l >> 4) * 4;
    int de = dstl[rl], se = srcl[rl];

    f32x4 acc[4];
    #pragma unroll
    for (int ft = 0; ft < 4; ft++) {
        acc[ft] = f32x4{0.f, 0.f, 0.f, 0.f};
        #pragma unroll
        for (int ks = 0; ks < 2; ks++) {
            bf16x8 a = *(const bf16x8*)(ewp + (((long long)ft * 2 + ks) * 64 + l) * 8);
            acc[ft] = __builtin_amdgcn_mfma_f32_16x16x32_bf16(a, bfr[ks], acc[ft], 0, 0, 0);
        }
    }

    #pragma unroll
    for (int ft = 0; ft < 4; ft++) {
        int f0 = ft * 16 + q4;
        float4 bv = *(const float4*)&eb[f0];
        uint2 g3 = *(const uint2*)&x3[(long long)de * 64 + f0];
        uint2 g4 = *(const uint2*)&x4[(long long)se * 64 + f0];
        float h0 = acc[ft][0] + bv.x + bflo(g3.x) + bflo(g4.x);
        float h1 = acc[ft][1] + bv.y + bfhi(g3.x) + bfhi(g4.x);
        float h2 = acc[ft][2] + bv.z + bflo(g3.y) + bflo(g4.y);
        float h3 = acc[ft][3] + bv.w + bfhi(g3.y) + bfhi(g4.y);
        uint2 ho;
        ho.x = packbf(h0, h1); ho.y = packbf(h2, h3);
        int hoff = (rl * 128 + f0 * 2) ^ ((rl & 7) << 4);
        *(uint2*)((char*)Hs + hoff) = ho;
        float s0 = h0, s1 = h1, s2 = h2, s3 = h3;
        float p0 = h0 * h0, p1 = h1 * h1, p2 = h2 * h2, p3 = h3 * h3;
        #pragma unroll
        for (int d = 1; d < 16; d <<= 1) {
            s0 += __shfl_xor(s0, d); s1 += __shfl_xor(s1, d);
            s2 += __shfl_xor(s2, d); s3 += __shfl_xor(s3, d);
            p0 += __shfl_xor(p0, d); p1 += __shfl_xor(p1, d);
            p2 += __shfl_xor(p2, d); p3 += __shfl_xor(p3, d);
        }
        if ((l & 15) == 0) {
            sred[0][wv][f0 + 0] = s0; sred[0][wv][f0 + 1] = s1;
            sred[0][wv][f0 + 2] = s2; sred[0][wv][f0 + 3] = s3;
            sred[1][wv][f0 + 0] = p0; sred[1][wv][f0 + 1] = p1;
            sred[1][wv][f0 + 2] = p2; sred[1][wv][f0 + 3] = p3;
        }
    }
    __syncthreads();
    // coalesced h_e store: thread t -> edge row0+(t>>2), features (t&3)*16..+15
    {
        int r = tid >> 2, cc = (tid & 3) * 16;
        int swz = (r & 7) << 4;
        uint4 a = *(uint4*)((char*)Hs + ((r * 128 + cc * 2) ^ swz));
        uint4 b = *(uint4*)((char*)Hs + ((r * 128 + cc * 2 + 16) ^ swz));
        __hip_bfloat16* op = h_e + (row0 + r) * 64 + cc;
        *(uint4*)op = a;
        *(uint4*)(op + 8) = b;
    }
    if (tid < 128) {
        int which = tid >> 6, f = tid & 63;
        float s = sred[which][0][f] + sred[which][1][f] + sred[which][2][f] + sred[which][3][f];
        atomicAdd(&estats[(blockIdx.x & 7) * 128 + which * 64 + f], s);
    }
}

// ---------- node finish: h = x1 + mean_e(sigmoid(w[e])*x2[src[e]]); node BN stats ----------
// half-wave (32 lanes) per node, lane k handles features 2k, 2k+1.
template <bool WF32>
__global__ __launch_bounds__(256)
void node_finish_kernel(const void* __restrict__ w_, const __hip_bfloat16* __restrict__ x2,
                        const __hip_bfloat16* __restrict__ x1,
                        const int* __restrict__ off, const int* __restrict__ eidx,
                        const int* __restrict__ src,
                        float* __restrict__ h_v, float* __restrict__ nstats, int Nn) {
    __shared__ float red[8 * 66];
    int tid = threadIdx.x;
    int hw = tid >> 5, k = tid & 31;
    int n = blockIdx.x * 8 + hw;
    float h0 = 0.f, h1 = 0.f;
    if (n < Nn) {
        int o0 = off[n], o1 = off[n + 1];
        float a0 = 0.f, a1 = 0.f;
        for (int j = o0; j < o1; j++) {
            int e = eidx[j];
            int s = src[e];
            float w0, w1;
            if (WF32) {
                float2 wf = *(const float2*)((const float*)w_ + (long long)e * 64 + 2 * k);
                w0 = wf.x; w1 = wf.y;
            } else {
                unsigned wu = *(const unsigned*)((const __hip_bfloat16*)w_ + (long long)e * 64 + 2 * k);
                w0 = bflo(wu); w1 = bfhi(wu);
            }
            unsigned xu = *(const unsigned*)&x2[(long long)s * 64 + 2 * k];
            a0 += bflo(xu) / (1.f + __expf(-w0));
            a1 += bfhi(xu) / (1.f + __expf(-w1));
        }
        float ic = 1.f / fmaxf((float)(o1 - o0), 1.f);
        unsigned xu = *(const unsigned*)&x1[(long long)n * 64 + 2 * k];
        h0 = bflo(xu) + a0 * ic;
        h1 = bfhi(xu) + a1 * ic;
        *(float2*)&h_v[(long long)n * 64 + 2 * k] = make_float2(h0, h1);
    }
    red[hw * 66 + 2 * k] = h0;
    red[hw * 66 + 2 * k + 1] = h1;
    __syncthreads();
    float* nst = nstats + (blockIdx.x & 7) * 128;
    if (tid < 64) {
        float s = 0.f;
        #pragma unroll
        for (int r = 0; r < 8; r++) s += red[r * 66 + tid];
        atomicAdd(&nst[tid], s);
    }
    __syncthreads();
    red[hw * 66 + 2 * k] = h0 * h0;
    red[hw * 66 + 2 * k + 1] = h1 * h1;
    __syncthreads();
    if (tid < 64) {
        float s = 0.f;
        #pragma unroll
        for (int r = 0; r < 8; r++) s += red[r * 66 + tid];
        atomicAdd(&nst[64 + tid], s);
    }
}

// ---------- finalize: stats -> (kmul, kadd) ----------
__global__ void finalize_kernel(const float* __restrict__ nstats, const float* __restrict__ estats,
                                const float* __restrict__ vs, const float* __restrict__ vb,
                                const float* __restrict__ es, const float* __restrict__ eb,
                                float* __restrict__ fin, float invN, float invE) {
    int t = threadIdx.x;   // 128
    const float* st = (t < 64) ? nstats : estats;
    float inv = (t < 64) ? invN : invE;
    int c = t & 63;
    float s = 0.f, q = 0.f;
    #pragma unroll
    for (int r = 0; r < 8; r++) { s += st[r * 128 + c]; q += st[r * 128 + 64 + c]; }
    float mean = s * inv;
    float var = q * inv - mean * mean;
    float rinv = rsqrtf(var + 1e-5f);
    float sc = (t < 64) ? vs[c] : es[c];
    float bi = (t < 64) ? vb[c] : eb[c];
    float kmul = rinv * sc;
    float kadd = bi - mean * kmul;
    int base = (t < 64) ? 0 : 128;
    fin[base + c] = kmul;
    fin[base + 64 + c] = kadd;
}

// ---------- node BN apply ----------
__global__ __launch_bounds__(256)
void node_apply_kernel(const float4* __restrict__ hv4, const float4* __restrict__ xold4,
                       float4* __restrict__ out4, const float* __restrict__ fin, int total) {
    __shared__ float km[64], ka[64];
    if (threadIdx.x < 64) { km[threadIdx.x] = fin[threadIdx.x]; ka[threadIdx.x] = fin[64 + threadIdx.x]; }
    __syncthreads();
    int idx = blockIdx.x * 256 + threadIdx.x;
    if (idx >= total) return;
    int c0 = (idx & 15) * 4;
    float4 h = hv4[idx], xo = xold4[idx];
    float4 m = *(float4*)&km[c0], a = *(float4*)&ka[c0];
    float g0 = h.x * m.x + a.x, g1 = h.y * m.y + a.y, g2 = h.z * m.z + a.z, g3 = h.w * m.w + a.w;
    out4[idx] = make_float4(xo.x + g0 / (1.f + __expf(-g0)),
                            xo.y + g1 / (1.f + __expf(-g1)),
                            xo.z + g2 / (1.f + __expf(-g2)),
                            xo.w + g3 / (1.f + __expf(-g3)));
}

// ---------- edge update: w_new = w_old + silu(h_e*kmul + kadd) ----------
template <bool RF32, bool OUT32>
__global__ __launch_bounds__(256)
void edge_update_kernel(const uint4* __restrict__ he, const void* __restrict__ wold_,
                        void* __restrict__ wnew_, const float* __restrict__ fin, long long total) {
    __shared__ float km[64], ka[64];
    if (threadIdx.x < 64) { km[threadIdx.x] = fin[128 + threadIdx.x]; ka[threadIdx.x] = fin[192 + threadIdx.x]; }
    __syncthreads();
    for (long long idx = blockIdx.x * 256LL + threadIdx.x; idx < total; idx += gridDim.x * 256LL) {
        int c0 = (int)(idx & 7) * 8;
        uint4 hp = he[idx];
        float hf[8] = {bflo(hp.x), bfhi(hp.x), bflo(hp.y), bfhi(hp.y),
                       bflo(hp.z), bfhi(hp.z), bflo(hp.w), bfhi(hp.w)};
        float wv[8];
        if (RF32) {
            const float4* w4 = (const float4*)wold_;
            float4 wa = w4[idx * 2], wb = w4[idx * 2 + 1];
            wv[0] = wa.x; wv[1] = wa.y; wv[2] = wa.z; wv[3] = wa.w;
            wv[4] = wb.x; wv[5] = wb.y; wv[6] = wb.z; wv[7] = wb.w;
        } else {
            uint4 wu = ((const uint4*)wold_)[idx];
            wv[0] = bflo(wu.x); wv[1] = bfhi(wu.x); wv[2] = bflo(wu.y); wv[3] = bfhi(wu.y);
            wv[4] = bflo(wu.z); wv[5] = bfhi(wu.z); wv[6] = bflo(wu.w); wv[7] = bfhi(wu.w);
        }
        float4 m0 = *(float4*)&km[c0], m1 = *(float4*)&km[c0 + 4];
        float4 a0 = *(float4*)&ka[c0], a1 = *(float4*)&ka[c0 + 4];
        float mv[8] = {m0.x, m0.y, m0.z, m0.w, m1.x, m1.y, m1.z, m1.w};
        float av[8] = {a0.x, a0.y, a0.z, a0.w, a1.x, a1.y, a1.z, a1.w};
        float o[8];
        #pragma unroll
        for (int j = 0; j < 8; j++) {
            float g = hf[j] * mv[j] + av[j];
            o[j] = wv[j] + g / (1.f + __expf(-g));
        }
        if (OUT32) {
            float4* out4 = (float4*)wnew_;
            out4[idx * 2]     = make_float4(o[0], o[1], o[2], o[3]);
            out4[idx * 2 + 1] = make_float4(o[4], o[5], o[6], o[7]);
        } else {
            uint4 wo;
            wo.x = packbf(o[0], o[1]); wo.y = packbf(o[2], o[3]);
            wo.z = packbf(o[4], o[5]); wo.w = packbf(o[6], o[7]);
            ((uint4*)wnew_)[idx] = wo;
        }
    }
}

// ---------- launch ----------
extern "C" void kernel_launch(void* const* d_in, const int* in_sizes, int n_in,
                              void* d_out, int out_size, void* d_ws, size_t ws_size,
                              hipStream_t stream) {
    const float* x_in  = (const float*)d_in[0];
    const float* ea_in = (const float*)d_in[1];
    const int*   ei    = (const int*)d_in[2];
    const float* v_w   = (const float*)d_in[3];
    const float* v_b   = (const float*)d_in[4];
    const float* e_w   = (const float*)d_in[5];
    const float* e_b   = (const float*)d_in[6];
    const float* vbn_s = (const float*)d_in[7];
    const float* vbn_b = (const float*)d_in[8];
    const float* ebn_s = (const float*)d_in[9];
    const float* ebn_b = (const float*)d_in[10];

    const int Nn = in_sizes[0] / 64;
    const int E  = in_sizes[1] / 64;
    const int L  = in_sizes[3] / (4 * 64 * 64);

    const int* dst = ei;
    const int* src = ei + E;

    // workspace layout
    float* h_v    = (float*)d_ws;                       // [Nn][64] fp32
    float* nstats = h_v + (long long)Nn * 64;           // [L][8][128]
    float* estats = nstats + (long long)L * 1024;       // [L][8][128]
    float* fin    = estats + (long long)L * 1024;       // [4][64]
    __hip_bfloat16* xp   = (__hip_bfloat16*)(fin + 256);        // [4][Nn][64]
    __hip_bfloat16* h_e  = xp + (long long)4 * Nn * 64;         // [E][64]
    __hip_bfloat16* w_bf = h_e + (long long)E * 64;             // [E][64] bf16 state
    short* vwp = (short*)(w_bf + (long long)E * 64);    // [L][4][4][2][64][8]
    short* ewp = vwp + (long long)L * 16384;            // [L][4][2][64][8]
    int* cnt  = (int*)(ewp + (long long)L * 4096);      // [Nn]
    int* off  = cnt + Nn;                               // [Nn+1]
    int* eidx = off + Nn + 1;                           // [E]

    size_t needed = ((size_t)Nn * 64 + (size_t)L * 2048 + 256) * 4 +
                    ((size_t)4 * Nn * 64 + (size_t)2 * E * 64 + (size_t)L * 20480) * 2 +
                    ((size_t)2 * Nn + 1 + (size_t)E) * 4;
    if (ws_size < needed) return;

    float* out_x = (float*)d_out;
    float* out_w = out_x + (long long)Nn * 64;

    // CSR build + zero stats + pack weights (once per call)
    zero_int_kernel<<<64, 256, 0, stream>>>(cnt, Nn);
    zero_int_kernel<<<8, 256, 0, stream>>>((int*)nstats, L * 2048);
    count_kernel<<<(E + 255) / 256, 256, 0, stream>>>(dst, cnt, E);
    scan_kernel<<<1, 1024, 0, stream>>>(cnt, off, Nn);
    fill_eidx_kernel<<<(E + 255) / 256, 256, 0, stream>>>(dst, off, cnt, eidx, E);
    pack_kernel<<<(L * 2560 + 255) / 256, 256, 0, stream>>>(v_w, e_w, vwp, ewp, L);

    const __hip_bfloat16* x1 = xp;
    const __hip_bfloat16* x2 = xp + (long long)Nn * 64;
    const __hip_bfloat16* x3 = xp + (long long)2 * Nn * 64;
    const __hip_bfloat16* x4 = xp + (long long)3 * Nn * 64;

    for (int l = 0; l < L; l++) {
        const float* xl = (l == 0) ? x_in : out_x;
        bool wf32 = (l == 0);
        bool last = (l == L - 1);
        float* nst = nstats + (long long)l * 1024;
        float* est = estats + (long long)l * 1024;

        // node projections -> xp[4] (bf16, MFMA, coalesced epilogue)
        node_gemm_mfma<<<(Nn + 63) / 64, 256, 0, stream>>>(
            xl, vwp + (long long)l * 16384, v_b + l * 256, xp, Nn);

        // edge GEMM (MFMA) + gathers + h_e (coalesced) + edge stats
        if (wf32)
            edge_gemm_mfma<true><<<E / 64, 256, 0, stream>>>(
                ea_in, ewp + (long long)l * 4096, e_b + l * 64,
                x3, x4, dst, src, h_e, est);
        else
            edge_gemm_mfma<false><<<E / 64, 256, 0, stream>>>(
                w_bf, ewp + (long long)l * 4096, e_b + l * 64,
                x3, x4, dst, src, h_e, est);

        // h_v = x1 + mean(sigmoid(w)*x2[src]) over CSR; node stats
        if (wf32)
            node_finish_kernel<true><<<(Nn + 7) / 8, 256, 0, stream>>>(
                ea_in, x2, x1, off, eidx, src, h_v, nst, Nn);
        else
            node_finish_kernel<false><<<(Nn + 7) / 8, 256, 0, stream>>>(
                w_bf, x2, x1, off, eidx, src, h_v, nst, Nn);

        finalize_kernel<<<1, 128, 0, stream>>>(
            nst, est, vbn_s + l * 64, vbn_b + l * 64,
            ebn_s + l * 64, ebn_b + l * 64, fin, 1.f / (float)Nn, 1.f / (float)E);

        node_apply_kernel<<<(Nn * 16 + 255) / 256, 256, 0, stream>>>(
            (const float4*)h_v, (const float4*)xl, (float4*)out_x, fin, Nn * 16);

        // edge update
        if (wf32 && !last)
            edge_update_kernel<true, false><<<4096, 256, 0, stream>>>(
                (const uint4*)h_e, ea_in, w_bf, fin, (long long)E * 8);
        else if (wf32 && last)
            edge_update_kernel<true, true><<<4096, 256, 0, stream>>>(
                (const uint4*)h_e, ea_in, out_w, fin, (long long)E * 8);
        else if (!wf32 && !last)
            edge_update_kernel<false, false><<<4096, 256, 0, stream>>>(
                (const uint4*)h_e, w_bf, w_bf, fin, (long long)E * 8);
        else
            edge_update_kernel<false, true><<<4096, 256, 0, stream>>>(
                (const uint4*)h_e, w_bf, out_w, fin, (long long)E * 8);
    }
}

// Round 7
// 859.740 us; speedup vs baseline: 5.7415x; 1.1868x over previous
//
#include <hip/hip_runtime.h>
#include <hip/hip_bf16.h>
#include <math.h>

typedef __attribute__((ext_vector_type(8))) short bf16x8;
typedef __attribute__((ext_vector_type(4))) float f32x4;

// ---------- bf16 helpers ----------
__device__ __forceinline__ float bflo(unsigned u) { return __uint_as_float(u << 16); }
__device__ __forceinline__ float bfhi(unsigned u) { return __uint_as_float(u & 0xffff0000u); }
__device__ __forceinline__ unsigned packbf(float a, float b) {
    unsigned ua = __float_as_uint(a), ub = __float_as_uint(b);
    ua += 0x7fffu + ((ua >> 16) & 1u);
    ub += 0x7fffu + ((ub >> 16) & 1u);
    return (ua >> 16) | (ub & 0xffff0000u);
}
__device__ __forceinline__ float silu(float g) { return g / (1.f + __expf(-g)); }

// ---------- setup ----------
__global__ void zero_int_kernel(int* __restrict__ p, int n) {
    int i = blockIdx.x * blockDim.x + threadIdx.x;
    int s = gridDim.x * blockDim.x;
    for (; i < n; i += s) p[i] = 0;
}

__global__ void count_kernel(const int* __restrict__ dst, int* __restrict__ cnt, int E) {
    int e = blockIdx.x * blockDim.x + threadIdx.x;
    if (e < E) atomicAdd(&cnt[dst[e]], 1);
}

__global__ __launch_bounds__(1024)
void scan_kernel(const int* __restrict__ cnt, int* __restrict__ off, int n) {
    __shared__ int wsum[16];
    __shared__ int carry;
    int tid = threadIdx.x, lane = tid & 63, wid = tid >> 6;
    if (tid == 0) carry = 0;
    __syncthreads();
    for (int base = 0; base < n; base += 1024) {
        int i = base + tid;
        int v = (i < n) ? cnt[i] : 0;
        int sc = v;
        #pragma unroll
        for (int s = 1; s < 64; s <<= 1) {
            int t = __shfl_up(sc, (unsigned)s, 64);
            if (lane >= s) sc += t;
        }
        if (lane == 63) wsum[wid] = sc;
        __syncthreads();
        int woff = 0;
        for (int k = 0; k < wid; k++) woff += wsum[k];
        int inc = carry + woff + sc;
        if (i < n) off[i + 1] = inc;
        if (i == 0) off[0] = 0;
        __syncthreads();
        if (tid == 0) {
            int t = 0;
            for (int k = 0; k < 16; k++) t += wsum[k];
            carry += t;
        }
        __syncthreads();
    }
}

// perm[e] = CSR slot; consumes cnt (leaves zeros)
__global__ void fill_perm_kernel(const int* __restrict__ dst, const int* __restrict__ off,
                                 int* __restrict__ cnt, int* __restrict__ perm, int E) {
    int e = blockIdx.x * blockDim.x + threadIdx.x;
    if (e < E) {
        int d = dst[e];
        int pos = atomicSub(&cnt[d], 1) - 1;
        perm[e] = off[d] + pos;
    }
}

// ---------- pack weights into MFMA A-operand fragments (W^T, bf16) ----------
__global__ void pack_kernel(const float* __restrict__ v_w, const float* __restrict__ e_w,
                            short* __restrict__ vwp, short* __restrict__ ewp, int L) {
    int t = blockIdx.x * blockDim.x + threadIdx.x;
    if (t >= L * 5 * 4 * 2 * 64) return;
    int lane = t & 63;
    int ks = (t >> 6) & 1;
    int ft = (t >> 7) & 3;
    int mat = t >> 9;
    int layer = mat / 5, mi = mat % 5;
    const float* W = (mi < 4) ? (v_w + (long long)(layer * 4 + mi) * 4096)
                              : (e_w + (long long)layer * 4096);
    int m = ft * 16 + (lane & 15);
    int k0 = ks * 32 + (lane >> 4) * 8;
    short* dstp = (mi < 4)
        ? vwp + ((((long long)(layer * 4 + mi) * 4 + ft) * 2 + ks) * 64 + lane) * 8
        : ewp + ((((long long)layer * 4 + ft) * 2 + ks) * 64 + lane) * 8;
    #pragma unroll
    for (int j = 0; j < 8; j++) {
        unsigned u = __float_as_uint(W[(k0 + j) * 64 + m]);
        u += 0x7fffu + ((u >> 16) & 1u);
        dstp[j] = (short)(u >> 16);
    }
}

// ---------- node GEMM (MFMA): xp[g][n][f] = bf16(x@v_w[g] + v_b[g]), LDS epilogue ----------
__global__ __launch_bounds__(256)
void node_gemm_mfma(const float* __restrict__ X, const short* __restrict__ vwp,
                    const float* __restrict__ vb, __hip_bfloat16* __restrict__ xp,
                    int Nn) {
    __shared__ short Xs[64 * 64];
    __shared__ short Hs[4][64 * 64];
    int tid = threadIdx.x;
    long long row0 = (long long)blockIdx.x * 64;

    {
        int r = tid >> 2, cq = tid & 3;
        long long row = row0 + r;
        float4 v0 = {0,0,0,0}, v1 = {0,0,0,0}, v2 = {0,0,0,0}, v3 = {0,0,0,0};
        if (row < Nn) {
            const float* sp = X + row * 64 + cq * 16;
            v0 = *(const float4*)(sp);     v1 = *(const float4*)(sp + 4);
            v2 = *(const float4*)(sp + 8); v3 = *(const float4*)(sp + 12);
        }
        uint4 w0, w1;
        w0.x = packbf(v0.x, v0.y); w0.y = packbf(v0.z, v0.w);
        w0.z = packbf(v1.x, v1.y); w0.w = packbf(v1.z, v1.w);
        w1.x = packbf(v2.x, v2.y); w1.y = packbf(v2.z, v2.w);
        w1.z = packbf(v3.x, v3.y); w1.w = packbf(v3.z, v3.w);
        int base = r * 128 + cq * 32, swz = (r & 7) << 4;
        *(uint4*)((char*)Xs + (base ^ swz)) = w0;
        *(uint4*)((char*)Xs + ((base + 16) ^ swz)) = w1;
    }
    __syncthreads();

    int l = tid & 63, wv = tid >> 6;
    int rl = wv * 16 + (l & 15);
    bf16x8 bfr[2];
    #pragma unroll
    for (int ks = 0; ks < 2; ks++) {
        int off = (rl * 128 + ks * 64 + (l >> 4) * 16) ^ ((rl & 7) << 4);
        bfr[ks] = *(bf16x8*)((char*)Xs + off);
    }
    int q4 = (l >> 4) * 4;
    for (int g = 0; g < 4; g++) {
        #pragma unroll
        for (int ft = 0; ft < 4; ft++) {
            f32x4 acc = f32x4{0.f, 0.f, 0.f, 0.f};
            #pragma unroll
            for (int ks = 0; ks < 2; ks++) {
                bf16x8 a = *(const bf16x8*)(vwp + (((long long)(g * 4 + ft) * 2 + ks) * 64 + l) * 8);
                acc = __builtin_amdgcn_mfma_f32_16x16x32_bf16(a, bfr[ks], acc, 0, 0, 0);
            }
            int f0 = ft * 16 + q4;
            float4 bv = *(const float4*)&vb[g * 64 + f0];
            uint2 o;
            o.x = packbf(acc[0] + bv.x, acc[1] + bv.y);
            o.y = packbf(acc[2] + bv.z, acc[3] + bv.w);
            int hoff = (rl * 128 + f0 * 2) ^ ((rl & 7) << 4);
            *(uint2*)((char*)Hs[g] + hoff) = o;
        }
    }
    __syncthreads();
    int r = tid >> 2, cc = (tid & 3) * 16;
    long long node = row0 + r;
    if (node < Nn) {
        int swz = (r & 7) << 4;
        #pragma unroll
        for (int g = 0; g < 4; g++) {
            uint4 a = *(uint4*)((char*)Hs[g] + ((r * 128 + cc * 2) ^ swz));
            uint4 b = *(uint4*)((char*)Hs[g] + ((r * 128 + cc * 2 + 16) ^ swz));
            __hip_bfloat16* op = xp + ((long long)g * Nn + node) * 64 + cc;
            *(uint4*)op = a;
            *(uint4*)(op + 8) = b;
        }
    }
}

// ---------- edge GEMM (MFMA), row-sliced epilogue, optional fused w-update ----------
// MODE 0: w read fp32 (layer 0). MODE 1: fused update, w_old fp32 (layer 1).
// MODE 2: fused update, w_old bf16 (layer >=2).
// Fused: w_new = w_old + silu(h_e_old*km + ka)  (fin = layer l-1 edge consts),
// written back to w_bf and used as this layer's w.
template <int MODE>
__global__ __launch_bounds__(256)
void edge_gemm_mfma(const float* __restrict__ Wl32, __hip_bfloat16* __restrict__ w_bf,
                    __hip_bfloat16* __restrict__ h_e, const float* __restrict__ fin,
                    const short* __restrict__ ewp, const float* __restrict__ eb,
                    const __hip_bfloat16* __restrict__ x2, const __hip_bfloat16* __restrict__ x3,
                    const __hip_bfloat16* __restrict__ x4,
                    const int* __restrict__ dst, const int* __restrict__ src,
                    const int* __restrict__ perm,
                    __hip_bfloat16* __restrict__ msg, float* __restrict__ estats) {
    __shared__ short Ws[64 * 64];            // 8 KB bf16 w tile, XOR-swizzled
    __shared__ float Hs[64 * 68];            // 17.4 KB fp32 acc+bias
    __shared__ float sredS[4][64], sredQ[4][64];
    __shared__ int dstl[64], srcl[64], perml[64];
    int tid = threadIdx.x;
    long long row0 = (long long)blockIdx.x * 64;

    // ---- staging: w tile -> Ws (+ fused update) ----
    {
        int r = tid >> 2, cq = tid & 3;
        long long grow = (row0 + r) * 64 + cq * 16;
        int base = r * 128 + cq * 32, swz = (r & 7) << 4;
        uint4 w0u, w1u;
        if (MODE == 0) {
            const float* sp = Wl32 + grow;
            float4 v0 = *(const float4*)(sp),     v1 = *(const float4*)(sp + 4);
            float4 v2 = *(const float4*)(sp + 8), v3 = *(const float4*)(sp + 12);
            w0u.x = packbf(v0.x, v0.y); w0u.y = packbf(v0.z, v0.w);
            w0u.z = packbf(v1.x, v1.y); w0u.w = packbf(v1.z, v1.w);
            w1u.x = packbf(v2.x, v2.y); w1u.y = packbf(v2.z, v2.w);
            w1u.z = packbf(v3.x, v3.y); w1u.w = packbf(v3.z, v3.w);
        } else {
            float wo[16];
            if (MODE == 1) {
                const float* sp = Wl32 + grow;
                #pragma unroll
                for (int j = 0; j < 16; j++) wo[j] = sp[j];
            } else {
                uint4 a = *(const uint4*)&w_bf[grow];
                uint4 b = *(const uint4*)&w_bf[grow + 8];
                unsigned ua[8] = {a.x, a.y, a.z, a.w, b.x, b.y, b.z, b.w};
                #pragma unroll
                for (int j = 0; j < 8; j++) { wo[2*j] = bflo(ua[j]); wo[2*j+1] = bfhi(ua[j]); }
            }
            uint4 ha = *(const uint4*)&h_e[grow];
            uint4 hb = *(const uint4*)&h_e[grow + 8];
            unsigned uh[8] = {ha.x, ha.y, ha.z, ha.w, hb.x, hb.y, hb.z, hb.w};
            const float* kmp = fin + 128 + cq * 16;
            const float* kap = fin + 192 + cq * 16;
            float wn[16];
            #pragma unroll
            for (int j = 0; j < 8; j++) {
                float h0 = bflo(uh[j]), h1 = bfhi(uh[j]);
                wn[2*j]   = wo[2*j]   + silu(h0 * kmp[2*j]   + kap[2*j]);
                wn[2*j+1] = wo[2*j+1] + silu(h1 * kmp[2*j+1] + kap[2*j+1]);
            }
            w0u.x = packbf(wn[0], wn[1]);  w0u.y = packbf(wn[2], wn[3]);
            w0u.z = packbf(wn[4], wn[5]);  w0u.w = packbf(wn[6], wn[7]);
            w1u.x = packbf(wn[8], wn[9]);  w1u.y = packbf(wn[10], wn[11]);
            w1u.z = packbf(wn[12], wn[13]); w1u.w = packbf(wn[14], wn[15]);
            *(uint4*)&w_bf[grow] = w0u;        // materialize w(l) for next consumer
            *(uint4*)&w_bf[grow + 8] = w1u;
        }
        *(uint4*)((char*)Ws + (base ^ swz)) = w0u;
        *(uint4*)((char*)Ws + ((base + 16) ^ swz)) = w1u;
        if (tid < 64) {
            dstl[tid] = dst[row0 + tid];
            srcl[tid] = src[row0 + tid];
            perml[tid] = perm[row0 + tid];
        }
    }
    __syncthreads();

    // ---- issue epilogue gathers early (overlap with MFMA) ----
    int rr0 = tid >> 3, rr1 = rr0 + 32;
    int c8 = (tid & 7) * 8;
    int de0 = dstl[rr0], se0 = srcl[rr0], pe0 = perml[rr0];
    int de1 = dstl[rr1], se1 = srcl[rr1], pe1 = perml[rr1];
    uint4 g3a = *(const uint4*)&x3[(long long)de0 * 64 + c8];
    uint4 g4a = *(const uint4*)&x4[(long long)se0 * 64 + c8];
    uint4 g2a = *(const uint4*)&x2[(long long)se0 * 64 + c8];
    uint4 g3b = *(const uint4*)&x3[(long long)de1 * 64 + c8];
    uint4 g4b = *(const uint4*)&x4[(long long)se1 * 64 + c8];
    uint4 g2b = *(const uint4*)&x2[(long long)se1 * 64 + c8];

    // ---- MFMA ----
    int l = tid & 63, wv = tid >> 6;
    int rl = wv * 16 + (l & 15);
    bf16x8 bfr[2];
    #pragma unroll
    for (int ks = 0; ks < 2; ks++) {
        int off = (rl * 128 + ks * 64 + (l >> 4) * 16) ^ ((rl & 7) << 4);
        bfr[ks] = *(bf16x8*)((char*)Ws + off);
    }
    int q4 = (l >> 4) * 4;
    #pragma unroll
    for (int ft = 0; ft < 4; ft++) {
        f32x4 acc = f32x4{0.f, 0.f, 0.f, 0.f};
        #pragma unroll
        for (int ks = 0; ks < 2; ks++) {
            bf16x8 a = *(const bf16x8*)(ewp + (((long long)ft * 2 + ks) * 64 + l) * 8);
            acc = __builtin_amdgcn_mfma_f32_16x16x32_bf16(a, bfr[ks], acc, 0, 0, 0);
        }
        int f0 = ft * 16 + q4;
        float4 bv = *(const float4*)&eb[f0];
        *(float4*)&Hs[rl * 68 + f0] = make_float4(acc[0] + bv.x, acc[1] + bv.y,
                                                  acc[2] + bv.z, acc[3] + bv.w);
    }
    __syncthreads();

    // ---- row-sliced epilogue: 2 passes, thread owns 8 contiguous feats of one edge ----
    float s[8], q[8];
    #pragma unroll
    for (int j = 0; j < 8; j++) { s[j] = 0.f; q[j] = 0.f; }
    #pragma unroll
    for (int p = 0; p < 2; p++) {
        int rr = p ? rr1 : rr0;
        int pe = p ? pe1 : pe0;
        uint4 g3 = p ? g3b : g3a;
        uint4 g4 = p ? g4b : g4a;
        uint4 g2 = p ? g2b : g2a;
        unsigned u3[4] = {g3.x, g3.y, g3.z, g3.w};
        unsigned u4[4] = {g4.x, g4.y, g4.z, g4.w};
        unsigned u2[4] = {g2.x, g2.y, g2.z, g2.w};
        float4 hA = *(float4*)&Hs[rr * 68 + c8];
        float4 hB = *(float4*)&Hs[rr * 68 + c8 + 4];
        float hs[8] = {hA.x, hA.y, hA.z, hA.w, hB.x, hB.y, hB.z, hB.w};
        uint4 wu = *(uint4*)((char*)Ws + ((rr * 128 + c8 * 2) ^ ((rr & 7) << 4)));
        unsigned uw[4] = {wu.x, wu.y, wu.z, wu.w};
        float h[8], m[8];
        #pragma unroll
        for (int j = 0; j < 4; j++) {
            float h0 = hs[2*j]   + bflo(u3[j]) + bflo(u4[j]);
            float h1 = hs[2*j+1] + bfhi(u3[j]) + bfhi(u4[j]);
            h[2*j] = h0; h[2*j+1] = h1;
            s[2*j] += h0; s[2*j+1] += h1;
            q[2*j] += h0 * h0; q[2*j+1] += h1 * h1;
            m[2*j]   = bflo(u2[j]) / (1.f + __expf(-bflo(uw[j])));
            m[2*j+1] = bfhi(u2[j]) / (1.f + __expf(-bfhi(uw[j])));
        }
        uint2 ho, mo;
        ho.x = packbf(h[0], h[1]); ho.y = packbf(h[2], h[3]);
        uint2 ho2; ho2.x = packbf(h[4], h[5]); ho2.y = packbf(h[6], h[7]);
        mo.x = packbf(m[0], m[1]); mo.y = packbf(m[2], m[3]);
        uint2 mo2; mo2.x = packbf(m[4], m[5]); mo2.y = packbf(m[6], m[7]);
        uint4 hv; hv.x = ho.x; hv.y = ho.y; hv.z = ho2.x; hv.w = ho2.y;
        uint4 mv; mv.x = mo.x; mv.y = mo.y; mv.z = mo2.x; mv.w = mo2.y;
        *(uint4*)&h_e[(row0 + rr) * 64 + c8] = hv;
        *(uint4*)&msg[(long long)pe * 64 + c8] = mv;
    }
    // reduce stats over the wave's 16 rows (lane bits 3-5)
    #pragma unroll
    for (int d = 8; d < 64; d <<= 1) {
        #pragma unroll
        for (int j = 0; j < 8; j++) {
            s[j] += __shfl_xor(s[j], d);
            q[j] += __shfl_xor(q[j], d);
        }
    }
    if ((l >> 3) == 0) {
        #pragma unroll
        for (int j = 0; j < 8; j++) {
            sredS[wv][(l & 7) * 8 + j] = s[j];
            sredQ[wv][(l & 7) * 8 + j] = q[j];
        }
    }
    __syncthreads();
    if (tid < 128) {
        int which = tid >> 6, f = tid & 63;
        float v = which ? (sredQ[0][f] + sredQ[1][f] + sredQ[2][f] + sredQ[3][f])
                        : (sredS[0][f] + sredS[1][f] + sredS[2][f] + sredS[3][f]);
        atomicAdd(&estats[(blockIdx.x & 7) * 128 + which * 64 + f], v);
    }
}

// ---------- node finish: h = x1 + mean(msg CSR segment); streaming; node BN stats ----------
__global__ __launch_bounds__(256)
void node_finish_kernel(const __hip_bfloat16* __restrict__ msg, const __hip_bfloat16* __restrict__ x1,
                        const int* __restrict__ off, float* __restrict__ h_v,
                        float* __restrict__ nstats, int Nn) {
    __shared__ float red[8 * 66];
    int tid = threadIdx.x;
    int hw = tid >> 5, k = tid & 31;
    int n = blockIdx.x * 8 + hw;
    float h0 = 0.f, h1 = 0.f;
    if (n < Nn) {
        int o0 = off[n], o1 = off[n + 1];
        float a0 = 0.f, a1 = 0.f;
        for (int j = o0; j < o1; j++) {
            unsigned u = *(const unsigned*)&msg[(long long)j * 64 + 2 * k];
            a0 += bflo(u);
            a1 += bfhi(u);
        }
        float ic = 1.f / fmaxf((float)(o1 - o0), 1.f);
        unsigned xu = *(const unsigned*)&x1[(long long)n * 64 + 2 * k];
        h0 = bflo(xu) + a0 * ic;
        h1 = bfhi(xu) + a1 * ic;
        *(float2*)&h_v[(long long)n * 64 + 2 * k] = make_float2(h0, h1);
    }
    red[hw * 66 + 2 * k] = h0;
    red[hw * 66 + 2 * k + 1] = h1;
    __syncthreads();
    float* nst = nstats + (blockIdx.x & 7) * 128;
    if (tid < 64) {
        float s = 0.f;
        #pragma unroll
        for (int r = 0; r < 8; r++) s += red[r * 66 + tid];
        atomicAdd(&nst[tid], s);
    }
    __syncthreads();
    red[hw * 66 + 2 * k] = h0 * h0;
    red[hw * 66 + 2 * k + 1] = h1 * h1;
    __syncthreads();
    if (tid < 64) {
        float s = 0.f;
        #pragma unroll
        for (int r = 0; r < 8; r++) s += red[r * 66 + tid];
        atomicAdd(&nst[64 + tid], s);
    }
}

// ---------- finalize: stats -> (kmul, kadd) ----------
__global__ void finalize_kernel(const float* __restrict__ nstats, const float* __restrict__ estats,
                                const float* __restrict__ vs, const float* __restrict__ vb,
                                const float* __restrict__ es, const float* __restrict__ eb,
                                float* __restrict__ fin, float invN, float invE) {
    int t = threadIdx.x;   // 128
    const float* st = (t < 64) ? nstats : estats;
    float inv = (t < 64) ? invN : invE;
    int c = t & 63;
    float s = 0.f, q = 0.f;
    #pragma unroll
    for (int r = 0; r < 8; r++) { s += st[r * 128 + c]; q += st[r * 128 + 64 + c]; }
    float mean = s * inv;
    float var = q * inv - mean * mean;
    float rinv = rsqrtf(var + 1e-5f);
    float sc = (t < 64) ? vs[c] : es[c];
    float bi = (t < 64) ? vb[c] : eb[c];
    float kmul = rinv * sc;
    float kadd = bi - mean * kmul;
    int base = (t < 64) ? 0 : 128;
    fin[base + c] = kmul;
    fin[base + 64 + c] = kadd;
}

// ---------- node BN apply ----------
__global__ __launch_bounds__(256)
void node_apply_kernel(const float4* __restrict__ hv4, const float4* __restrict__ xold4,
                       float4* __restrict__ out4, const float* __restrict__ fin, int total) {
    __shared__ float km[64], ka[64];
    if (threadIdx.x < 64) { km[threadIdx.x] = fin[threadIdx.x]; ka[threadIdx.x] = fin[64 + threadIdx.x]; }
    __syncthreads();
    int idx = blockIdx.x * 256 + threadIdx.x;
    if (idx >= total) return;
    int c0 = (idx & 15) * 4;
    float4 h = hv4[idx], xo = xold4[idx];
    float4 m = *(float4*)&km[c0], a = *(float4*)&ka[c0];
    float g0 = h.x * m.x + a.x, g1 = h.y * m.y + a.y, g2 = h.z * m.z + a.z, g3 = h.w * m.w + a.w;
    out4[idx] = make_float4(xo.x + silu(g0), xo.y + silu(g1),
                            xo.z + silu(g2), xo.w + silu(g3));
}

// ---------- final edge update (last layer only): out_w fp32 ----------
template <bool RF32>
__global__ __launch_bounds__(256)
void edge_update_kernel(const uint4* __restrict__ he, const void* __restrict__ wold_,
                        float4* __restrict__ out4, const float* __restrict__ fin, long long total) {
    __shared__ float km[64], ka[64];
    if (threadIdx.x < 64) { km[threadIdx.x] = fin[128 + threadIdx.x]; ka[threadIdx.x] = fin[192 + threadIdx.x]; }
    __syncthreads();
    for (long long idx = blockIdx.x * 256LL + threadIdx.x; idx < total; idx += gridDim.x * 256LL) {
        int c0 = (int)(idx & 7) * 8;
        uint4 hp = he[idx];
        float hf[8] = {bflo(hp.x), bfhi(hp.x), bflo(hp.y), bfhi(hp.y),
                       bflo(hp.z), bfhi(hp.z), bflo(hp.w), bfhi(hp.w)};
        float wv[8];
        if (RF32) {
            const float4* w4 = (const float4*)wold_;
            float4 wa = w4[idx * 2], wb = w4[idx * 2 + 1];
            wv[0] = wa.x; wv[1] = wa.y; wv[2] = wa.z; wv[3] = wa.w;
            wv[4] = wb.x; wv[5] = wb.y; wv[6] = wb.z; wv[7] = wb.w;
        } else {
            uint4 wu = ((const uint4*)wold_)[idx];
            wv[0] = bflo(wu.x); wv[1] = bfhi(wu.x); wv[2] = bflo(wu.y); wv[3] = bfhi(wu.y);
            wv[4] = bflo(wu.z); wv[5] = bfhi(wu.z); wv[6] = bflo(wu.w); wv[7] = bfhi(wu.w);
        }
        float4 m0 = *(float4*)&km[c0], m1 = *(float4*)&km[c0 + 4];
        float4 a0 = *(float4*)&ka[c0], a1 = *(float4*)&ka[c0 + 4];
        float mv[8] = {m0.x, m0.y, m0.z, m0.w, m1.x, m1.y, m1.z, m1.w};
        float av[8] = {a0.x, a0.y, a0.z, a0.w, a1.x, a1.y, a1.z, a1.w};
        float o[8];
        #pragma unroll
        for (int j = 0; j < 8; j++) o[j] = wv[j] + silu(hf[j] * mv[j] + av[j]);
        out4[idx * 2]     = make_float4(o[0], o[1], o[2], o[3]);
        out4[idx * 2 + 1] = make_float4(o[4], o[5], o[6], o[7]);
    }
}

// ---------- launch ----------
extern "C" void kernel_launch(void* const* d_in, const int* in_sizes, int n_in,
                              void* d_out, int out_size, void* d_ws, size_t ws_size,
                              hipStream_t stream) {
    const float* x_in  = (const float*)d_in[0];
    const float* ea_in = (const float*)d_in[1];
    const int*   ei    = (const int*)d_in[2];
    const float* v_w   = (const float*)d_in[3];
    const float* v_b   = (const float*)d_in[4];
    const float* e_w   = (const float*)d_in[5];
    const float* e_b   = (const float*)d_in[6];
    const float* vbn_s = (const float*)d_in[7];
    const float* vbn_b = (const float*)d_in[8];
    const float* ebn_s = (const float*)d_in[9];
    const float* ebn_b = (const float*)d_in[10];

    const int Nn = in_sizes[0] / 64;
    const int E  = in_sizes[1] / 64;
    const int L  = in_sizes[3] / (4 * 64 * 64);

    const int* dst = ei;
    const int* src = ei + E;

    // workspace layout
    float* h_v    = (float*)d_ws;                       // [Nn][64] fp32
    float* nstats = h_v + (long long)Nn * 64;           // [L][8][128]
    float* estats = nstats + (long long)L * 1024;       // [L][8][128]
    float* fin    = estats + (long long)L * 1024;       // [4][64]
    __hip_bfloat16* xp   = (__hip_bfloat16*)(fin + 256);        // [4][Nn][64]
    __hip_bfloat16* h_e  = xp + (long long)4 * Nn * 64;         // [E][64]
    __hip_bfloat16* msg  = h_e + (long long)E * 64;             // [E][64] CSR order
    __hip_bfloat16* w_bf = msg + (long long)E * 64;             // [E][64] bf16 state
    short* vwp = (short*)(w_bf + (long long)E * 64);    // [L][4][4][2][64][8]
    short* ewp = vwp + (long long)L * 16384;            // [L][4][2][64][8]
    int* cnt  = (int*)(ewp + (long long)L * 4096);      // [Nn]
    int* off  = cnt + Nn;                               // [Nn+1]
    int* perm = off + Nn + 1;                           // [E]

    size_t needed = ((size_t)Nn * 64 + (size_t)L * 2048 + 256) * 4 +
                    ((size_t)4 * Nn * 64 + (size_t)3 * E * 64 + (size_t)L * 20480) * 2 +
                    ((size_t)2 * Nn + 1 + (size_t)E) * 4;
    if (ws_size < needed) return;

    float* out_x = (float*)d_out;
    float* out_w = out_x + (long long)Nn * 64;

    // CSR build + zero stats + pack weights (once per call)
    zero_int_kernel<<<64, 256, 0, stream>>>(cnt, Nn);
    zero_int_kernel<<<8, 256, 0, stream>>>((int*)nstats, L * 2048);
    count_kernel<<<(E + 255) / 256, 256, 0, stream>>>(dst, cnt, E);
    scan_kernel<<<1, 1024, 0, stream>>>(cnt, off, Nn);
    fill_perm_kernel<<<(E + 255) / 256, 256, 0, stream>>>(dst, off, cnt, perm, E);
    pack_kernel<<<(L * 2560 + 255) / 256, 256, 0, stream>>>(v_w, e_w, vwp, ewp, L);

    const __hip_bfloat16* x1 = xp;
    const __hip_bfloat16* x2 = xp + (long long)Nn * 64;
    const __hip_bfloat16* x3 = xp + (long long)2 * Nn * 64;
    const __hip_bfloat16* x4 = xp + (long long)3 * Nn * 64;

    for (int l = 0; l < L; l++) {
        const float* xl = (l == 0) ? x_in : out_x;
        float* nst = nstats + (long long)l * 1024;
        float* est = estats + (long long)l * 1024;

        // node projections -> xp[4]
        node_gemm_mfma<<<(Nn + 63) / 64, 256, 0, stream>>>(
            xl, vwp + (long long)l * 16384, v_b + l * 256, xp, Nn);

        // edge GEMM + fused w-update (l>=1) + h_e + msg(CSR) + edge stats
        if (l == 0)
            edge_gemm_mfma<0><<<E / 64, 256, 0, stream>>>(
                ea_in, w_bf, h_e, fin, ewp + (long long)l * 4096, e_b + l * 64,
                x2, x3, x4, dst, src, perm, msg, est);
        else if (l == 1)
            edge_gemm_mfma<1><<<E / 64, 256, 0, stream>>>(
                ea_in, w_bf, h_e, fin, ewp + (long long)l * 4096, e_b + l * 64,
                x2, x3, x4, dst, src, perm, msg, est);
        else
            edge_gemm_mfma<2><<<E / 64, 256, 0, stream>>>(
                nullptr, w_bf, h_e, fin, ewp + (long long)l * 4096, e_b + l * 64,
                x2, x3, x4, dst, src, perm, msg, est);

        // h_v = x1 + mean(msg segment); node stats (streaming)
        node_finish_kernel<<<(Nn + 7) / 8, 256, 0, stream>>>(
            msg, x1, off, h_v, nst, Nn);

        finalize_kernel<<<1, 128, 0, stream>>>(
            nst, est, vbn_s + l * 64, vbn_b + l * 64,
            ebn_s + l * 64, ebn_b + l * 64, fin, 1.f / (float)Nn, 1.f / (float)E);

        node_apply_kernel<<<(Nn * 16 + 255) / 256, 256, 0, stream>>>(
            (const float4*)h_v, (const float4*)xl, (float4*)out_x, fin, Nn * 16);
    }

    // final edge update -> out_w (fp32), using last layer's fin
    if (L == 1)
        edge_update_kernel<true><<<4096, 256, 0, stream>>>(
            (const uint4*)h_e, ea_in, (float4*)out_w, fin, (long long)E * 8);
    else
        edge_update_kernel<false><<<4096, 256, 0, stream>>>(
            (const uint4*)h_e, w_bf, (float4*)out_w, fin, (long long)E * 8);
}

// Round 8
// 815.007 us; speedup vs baseline: 6.0566x; 1.0549x over previous
//
#include <hip/hip_runtime.h>
#include <hip/hip_bf16.h>
#include <math.h>

typedef __attribute__((ext_vector_type(8))) short bf16x8;
typedef __attribute__((ext_vector_type(4))) float f32x4;

// ---------- bf16 helpers ----------
__device__ __forceinline__ float bflo(unsigned u) { return __uint_as_float(u << 16); }
__device__ __forceinline__ float bfhi(unsigned u) { return __uint_as_float(u & 0xffff0000u); }
__device__ __forceinline__ unsigned packbf(float a, float b) {
    unsigned ua = __float_as_uint(a), ub = __float_as_uint(b);
    ua += 0x7fffu + ((ua >> 16) & 1u);
    ub += 0x7fffu + ((ub >> 16) & 1u);
    return (ua >> 16) | (ub & 0xffff0000u);
}
__device__ __forceinline__ float silu(float g) { return g / (1.f + __expf(-g)); }

// ---------- setup ----------
__global__ void zero_int_kernel(int* __restrict__ p, int n) {
    int i = blockIdx.x * blockDim.x + threadIdx.x;
    int s = gridDim.x * blockDim.x;
    for (; i < n; i += s) p[i] = 0;
}

__global__ void count_kernel(const int* __restrict__ dst, int* __restrict__ cnt, int E) {
    int e = blockIdx.x * blockDim.x + threadIdx.x;
    if (e < E) atomicAdd(&cnt[dst[e]], 1);
}

__global__ __launch_bounds__(1024)
void scan_kernel(const int* __restrict__ cnt, int* __restrict__ off, int n) {
    __shared__ int wsum[16];
    __shared__ int carry;
    int tid = threadIdx.x, lane = tid & 63, wid = tid >> 6;
    if (tid == 0) carry = 0;
    __syncthreads();
    for (int base = 0; base < n; base += 1024) {
        int i = base + tid;
        int v = (i < n) ? cnt[i] : 0;
        int sc = v;
        #pragma unroll
        for (int s = 1; s < 64; s <<= 1) {
            int t = __shfl_up(sc, (unsigned)s, 64);
            if (lane >= s) sc += t;
        }
        if (lane == 63) wsum[wid] = sc;
        __syncthreads();
        int woff = 0;
        for (int k = 0; k < wid; k++) woff += wsum[k];
        int inc = carry + woff + sc;
        if (i < n) off[i + 1] = inc;
        if (i == 0) off[0] = 0;
        __syncthreads();
        if (tid == 0) {
            int t = 0;
            for (int k = 0; k < 16; k++) t += wsum[k];
            carry += t;
        }
        __syncthreads();
    }
}

// CSR fill: eidx/dst_csr/src_csr per slot; consumes cnt (leaves zeros)
__global__ void fill_csr_kernel(const int* __restrict__ dst, const int* __restrict__ src,
                                const int* __restrict__ off, int* __restrict__ cnt,
                                int* __restrict__ eidx, int* __restrict__ dstc,
                                int* __restrict__ srcc, int E) {
    int e = blockIdx.x * blockDim.x + threadIdx.x;
    if (e < E) {
        int d = dst[e];
        int pos = atomicSub(&cnt[d], 1) - 1;
        int slot = off[d] + pos;
        eidx[slot] = e;
        dstc[slot] = d;
        srcc[slot] = src[e];
    }
}

// ---------- pack weights into MFMA A-operand fragments (W^T, bf16) ----------
__global__ void pack_kernel(const float* __restrict__ v_w, const float* __restrict__ e_w,
                            short* __restrict__ vwp, short* __restrict__ ewp, int L) {
    int t = blockIdx.x * blockDim.x + threadIdx.x;
    if (t >= L * 5 * 4 * 2 * 64) return;
    int lane = t & 63;
    int ks = (t >> 6) & 1;
    int ft = (t >> 7) & 3;
    int mat = t >> 9;
    int layer = mat / 5, mi = mat % 5;
    const float* W = (mi < 4) ? (v_w + (long long)(layer * 4 + mi) * 4096)
                              : (e_w + (long long)layer * 4096);
    int m = ft * 16 + (lane & 15);
    int k0 = ks * 32 + (lane >> 4) * 8;
    short* dstp = (mi < 4)
        ? vwp + ((((long long)(layer * 4 + mi) * 4 + ft) * 2 + ks) * 64 + lane) * 8
        : ewp + ((((long long)layer * 4 + ft) * 2 + ks) * 64 + lane) * 8;
    #pragma unroll
    for (int j = 0; j < 8; j++) {
        unsigned u = __float_as_uint(W[(k0 + j) * 64 + m]);
        u += 0x7fffu + ((u >> 16) & 1u);
        dstp[j] = (short)(u >> 16);
    }
}

// ---------- node GEMM (MFMA): xp[g][n][f] = bf16(x@v_w[g] + v_b[g]), LDS epilogue ----------
__global__ __launch_bounds__(256)
void node_gemm_mfma(const float* __restrict__ X, const short* __restrict__ vwp,
                    const float* __restrict__ vb, __hip_bfloat16* __restrict__ xp,
                    int Nn) {
    __shared__ short Xs[64 * 64];
    __shared__ short Hs[4][64 * 64];
    int tid = threadIdx.x;
    long long row0 = (long long)blockIdx.x * 64;

    {
        int r = tid >> 2, cq = tid & 3;
        long long row = row0 + r;
        float4 v0 = {0,0,0,0}, v1 = {0,0,0,0}, v2 = {0,0,0,0}, v3 = {0,0,0,0};
        if (row < Nn) {
            const float* sp = X + row * 64 + cq * 16;
            v0 = *(const float4*)(sp);     v1 = *(const float4*)(sp + 4);
            v2 = *(const float4*)(sp + 8); v3 = *(const float4*)(sp + 12);
        }
        uint4 w0, w1;
        w0.x = packbf(v0.x, v0.y); w0.y = packbf(v0.z, v0.w);
        w0.z = packbf(v1.x, v1.y); w0.w = packbf(v1.z, v1.w);
        w1.x = packbf(v2.x, v2.y); w1.y = packbf(v2.z, v2.w);
        w1.z = packbf(v3.x, v3.y); w1.w = packbf(v3.z, v3.w);
        int base = r * 128 + cq * 32, swz = (r & 7) << 4;
        *(uint4*)((char*)Xs + (base ^ swz)) = w0;
        *(uint4*)((char*)Xs + ((base + 16) ^ swz)) = w1;
    }
    __syncthreads();

    int l = tid & 63, wv = tid >> 6;
    int rl = wv * 16 + (l & 15);
    bf16x8 bfr[2];
    #pragma unroll
    for (int ks = 0; ks < 2; ks++) {
        int off = (rl * 128 + ks * 64 + (l >> 4) * 16) ^ ((rl & 7) << 4);
        bfr[ks] = *(bf16x8*)((char*)Xs + off);
    }
    int q4 = (l >> 4) * 4;
    for (int g = 0; g < 4; g++) {
        #pragma unroll
        for (int ft = 0; ft < 4; ft++) {
            f32x4 acc = f32x4{0.f, 0.f, 0.f, 0.f};
            #pragma unroll
            for (int ks = 0; ks < 2; ks++) {
                bf16x8 a = *(const bf16x8*)(vwp + (((long long)(g * 4 + ft) * 2 + ks) * 64 + l) * 8);
                acc = __builtin_amdgcn_mfma_f32_16x16x32_bf16(a, bfr[ks], acc, 0, 0, 0);
            }
            int f0 = ft * 16 + q4;
            float4 bv = *(const float4*)&vb[g * 64 + f0];
            uint2 o;
            o.x = packbf(acc[0] + bv.x, acc[1] + bv.y);
            o.y = packbf(acc[2] + bv.z, acc[3] + bv.w);
            int hoff = (rl * 128 + f0 * 2) ^ ((rl & 7) << 4);
            *(uint2*)((char*)Hs[g] + hoff) = o;
        }
    }
    __syncthreads();
    int r = tid >> 2, cc = (tid & 3) * 16;
    long long node = row0 + r;
    if (node < Nn) {
        int swz = (r & 7) << 4;
        #pragma unroll
        for (int g = 0; g < 4; g++) {
            uint4 a = *(uint4*)((char*)Hs[g] + ((r * 128 + cc * 2) ^ swz));
            uint4 b = *(uint4*)((char*)Hs[g] + ((r * 128 + cc * 2 + 16) ^ swz));
            __hip_bfloat16* op = xp + ((long long)g * Nn + node) * 64 + cc;
            *(uint4*)op = a;
            *(uint4*)(op + 8) = b;
        }
    }
}

// ---------- edge GEMM (MFMA), CSR-ordered edge state, fused w-update ----------
// MODE 0 (layer 0): w = bf16(ea_in[eidx[j]]), write w_csr.
// MODE 1 (layer >=1): w = w_csr + silu(h_e*km + ka) (fin of layer l-1), write back.
// Epilogue: h_e_csr[j] = bf16(acc + eb + x3[dst_csr] + x4[src_csr]); edge BN stats.
template <int MODE>
__global__ __launch_bounds__(256)
void edge_gemm_mfma(const float* __restrict__ ea, const int* __restrict__ eidx,
                    __hip_bfloat16* __restrict__ w_csr, __hip_bfloat16* __restrict__ h_e,
                    const float* __restrict__ fin,
                    const short* __restrict__ ewp, const float* __restrict__ eb,
                    const __hip_bfloat16* __restrict__ x3, const __hip_bfloat16* __restrict__ x4,
                    const int* __restrict__ dstc, const int* __restrict__ srcc,
                    float* __restrict__ estats) {
    __shared__ short Ws[64 * 64];            // 8 KB bf16 w tile, XOR-swizzled
    __shared__ short Hs[64 * 68];            // 8.5 KB bf16 acc+bias
    __shared__ float sredS[4][64], sredQ[4][64];
    __shared__ int dstl[64], srcl[64];
    int tid = threadIdx.x;
    long long row0 = (long long)blockIdx.x * 64;

    // ---- staging: w tile (+ fused update) -> Ws + w_csr ----
    {
        int r = tid >> 2, cq = tid & 3;
        long long grow = (row0 + r) * 64 + cq * 16;
        int base = r * 128 + cq * 32, swz = (r & 7) << 4;
        uint4 w0u, w1u;
        if (MODE == 0) {
            long long e0 = eidx[row0 + r];
            const float* sp = ea + e0 * 64 + cq * 16;
            float4 v0 = *(const float4*)(sp),     v1 = *(const float4*)(sp + 4);
            float4 v2 = *(const float4*)(sp + 8), v3 = *(const float4*)(sp + 12);
            w0u.x = packbf(v0.x, v0.y); w0u.y = packbf(v0.z, v0.w);
            w0u.z = packbf(v1.x, v1.y); w0u.w = packbf(v1.z, v1.w);
            w1u.x = packbf(v2.x, v2.y); w1u.y = packbf(v2.z, v2.w);
            w1u.z = packbf(v3.x, v3.y); w1u.w = packbf(v3.z, v3.w);
        } else {
            uint4 a = *(const uint4*)&w_csr[grow];
            uint4 b = *(const uint4*)&w_csr[grow + 8];
            unsigned ua[8] = {a.x, a.y, a.z, a.w, b.x, b.y, b.z, b.w};
            uint4 ha = *(const uint4*)&h_e[grow];
            uint4 hb = *(const uint4*)&h_e[grow + 8];
            unsigned uh[8] = {ha.x, ha.y, ha.z, ha.w, hb.x, hb.y, hb.z, hb.w};
            const float* kmp = fin + 128 + cq * 16;
            const float* kap = fin + 192 + cq * 16;
            float wn[16];
            #pragma unroll
            for (int j = 0; j < 8; j++) {
                wn[2*j]   = bflo(ua[j]) + silu(bflo(uh[j]) * kmp[2*j]   + kap[2*j]);
                wn[2*j+1] = bfhi(ua[j]) + silu(bfhi(uh[j]) * kmp[2*j+1] + kap[2*j+1]);
            }
            w0u.x = packbf(wn[0], wn[1]);  w0u.y = packbf(wn[2], wn[3]);
            w0u.z = packbf(wn[4], wn[5]);  w0u.w = packbf(wn[6], wn[7]);
            w1u.x = packbf(wn[8], wn[9]);  w1u.y = packbf(wn[10], wn[11]);
            w1u.z = packbf(wn[12], wn[13]); w1u.w = packbf(wn[14], wn[15]);
        }
        *(uint4*)&w_csr[grow] = w0u;           // materialize w(l) (node_finish + next layer)
        *(uint4*)&w_csr[grow + 8] = w1u;
        *(uint4*)((char*)Ws + (base ^ swz)) = w0u;
        *(uint4*)((char*)Ws + ((base + 16) ^ swz)) = w1u;
        if (tid < 64) {
            dstl[tid] = dstc[row0 + tid];
            srcl[tid] = srcc[row0 + tid];
        }
    }
    __syncthreads();

    // ---- issue epilogue gathers early (x3 near-sequential: CSR is dst-sorted) ----
    int rr0 = tid >> 3, rr1 = rr0 + 32;
    int c8 = (tid & 7) * 8;
    int de0 = dstl[rr0], se0 = srcl[rr0];
    int de1 = dstl[rr1], se1 = srcl[rr1];
    uint4 g3a = *(const uint4*)&x3[(long long)de0 * 64 + c8];
    uint4 g4a = *(const uint4*)&x4[(long long)se0 * 64 + c8];
    uint4 g3b = *(const uint4*)&x3[(long long)de1 * 64 + c8];
    uint4 g4b = *(const uint4*)&x4[(long long)se1 * 64 + c8];

    // ---- MFMA ----
    int l = tid & 63, wv = tid >> 6;
    int rl = wv * 16 + (l & 15);
    bf16x8 bfr[2];
    #pragma unroll
    for (int ks = 0; ks < 2; ks++) {
        int off = (rl * 128 + ks * 64 + (l >> 4) * 16) ^ ((rl & 7) << 4);
        bfr[ks] = *(bf16x8*)((char*)Ws + off);
    }
    int q4 = (l >> 4) * 4;
    #pragma unroll
    for (int ft = 0; ft < 4; ft++) {
        f32x4 acc = f32x4{0.f, 0.f, 0.f, 0.f};
        #pragma unroll
        for (int ks = 0; ks < 2; ks++) {
            bf16x8 a = *(const bf16x8*)(ewp + (((long long)ft * 2 + ks) * 64 + l) * 8);
            acc = __builtin_amdgcn_mfma_f32_16x16x32_bf16(a, bfr[ks], acc, 0, 0, 0);
        }
        int f0 = ft * 16 + q4;
        float4 bv = *(const float4*)&eb[f0];
        uint2 o;
        o.x = packbf(acc[0] + bv.x, acc[1] + bv.y);
        o.y = packbf(acc[2] + bv.z, acc[3] + bv.w);
        *(uint2*)&Hs[rl * 68 + f0] = o;
    }
    __syncthreads();

    // ---- row-sliced epilogue: 2 passes, thread owns 8 contiguous feats of one edge ----
    float s[8], q[8];
    #pragma unroll
    for (int j = 0; j < 8; j++) { s[j] = 0.f; q[j] = 0.f; }
    #pragma unroll
    for (int p = 0; p < 2; p++) {
        int rr = p ? rr1 : rr0;
        uint4 g3 = p ? g3b : g3a;
        uint4 g4 = p ? g4b : g4a;
        unsigned u3[4] = {g3.x, g3.y, g3.z, g3.w};
        unsigned u4[4] = {g4.x, g4.y, g4.z, g4.w};
        uint4 hu = *(uint4*)&Hs[rr * 68 + c8];
        unsigned uh[4] = {hu.x, hu.y, hu.z, hu.w};
        float h[8];
        #pragma unroll
        for (int j = 0; j < 4; j++) {
            float h0 = bflo(uh[j]) + bflo(u3[j]) + bflo(u4[j]);
            float h1 = bfhi(uh[j]) + bfhi(u3[j]) + bfhi(u4[j]);
            h[2*j] = h0; h[2*j+1] = h1;
            s[2*j] += h0; s[2*j+1] += h1;
            q[2*j] += h0 * h0; q[2*j+1] += h1 * h1;
        }
        uint4 hv;
        hv.x = packbf(h[0], h[1]); hv.y = packbf(h[2], h[3]);
        hv.z = packbf(h[4], h[5]); hv.w = packbf(h[6], h[7]);
        *(uint4*)&h_e[(row0 + rr) * 64 + c8] = hv;
    }
    // reduce stats over the wave's 16 rows (lane bits 3-5)
    #pragma unroll
    for (int d = 8; d < 64; d <<= 1) {
        #pragma unroll
        for (int j = 0; j < 8; j++) {
            s[j] += __shfl_xor(s[j], d);
            q[j] += __shfl_xor(q[j], d);
        }
    }
    if ((l >> 3) == 0) {
        #pragma unroll
        for (int j = 0; j < 8; j++) {
            sredS[wv][(l & 7) * 8 + j] = s[j];
            sredQ[wv][(l & 7) * 8 + j] = q[j];
        }
    }
    __syncthreads();
    if (tid < 128) {
        int which = tid >> 6, f = tid & 63;
        float v = which ? (sredQ[0][f] + sredQ[1][f] + sredQ[2][f] + sredQ[3][f])
                        : (sredS[0][f] + sredS[1][f] + sredS[2][f] + sredS[3][f]);
        atomicAdd(&estats[(blockIdx.x & 7) * 128 + which * 64 + f], v);
    }
}

// ---------- node finish: h = x1 + mean_j(sigmoid(w_csr[j])*x2[src_csr[j]]); node stats ----------
// half-wave (32 lanes) per node; w_csr segment rows are CONTIGUOUS.
__global__ __launch_bounds__(256)
void node_finish_kernel(const __hip_bfloat16* __restrict__ w_csr, const int* __restrict__ srcc,
                        const __hip_bfloat16* __restrict__ x2, const __hip_bfloat16* __restrict__ x1,
                        const int* __restrict__ off, float* __restrict__ h_v,
                        float* __restrict__ nstats, int Nn) {
    __shared__ float red[8 * 66];
    int tid = threadIdx.x;
    int hw = tid >> 5, k = tid & 31;
    int n = blockIdx.x * 8 + hw;
    float h0 = 0.f, h1 = 0.f;
    if (n < Nn) {
        int o0 = off[n], o1 = off[n + 1];
        float a0 = 0.f, a1 = 0.f;
        for (int j = o0; j < o1; j++) {
            int s = srcc[j];
            unsigned wu = *(const unsigned*)&w_csr[(long long)j * 64 + 2 * k];
            unsigned xu = *(const unsigned*)&x2[(long long)s * 64 + 2 * k];
            a0 += bflo(xu) / (1.f + __expf(-bflo(wu)));
            a1 += bfhi(xu) / (1.f + __expf(-bfhi(wu)));
        }
        float ic = 1.f / fmaxf((float)(o1 - o0), 1.f);
        unsigned xu = *(const unsigned*)&x1[(long long)n * 64 + 2 * k];
        h0 = bflo(xu) + a0 * ic;
        h1 = bfhi(xu) + a1 * ic;
        *(float2*)&h_v[(long long)n * 64 + 2 * k] = make_float2(h0, h1);
    }
    red[hw * 66 + 2 * k] = h0;
    red[hw * 66 + 2 * k + 1] = h1;
    __syncthreads();
    float* nst = nstats + (blockIdx.x & 7) * 128;
    if (tid < 64) {
        float s = 0.f;
        #pragma unroll
        for (int r = 0; r < 8; r++) s += red[r * 66 + tid];
        atomicAdd(&nst[tid], s);
    }
    __syncthreads();
    red[hw * 66 + 2 * k] = h0 * h0;
    red[hw * 66 + 2 * k + 1] = h1 * h1;
    __syncthreads();
    if (tid < 64) {
        float s = 0.f;
        #pragma unroll
        for (int r = 0; r < 8; r++) s += red[r * 66 + tid];
        atomicAdd(&nst[64 + tid], s);
    }
}

// ---------- finalize: stats -> (kmul, kadd) ----------
__global__ void finalize_kernel(const float* __restrict__ nstats, const float* __restrict__ estats,
                                const float* __restrict__ vs, const float* __restrict__ vb,
                                const float* __restrict__ es, const float* __restrict__ eb,
                                float* __restrict__ fin, float invN, float invE) {
    int t = threadIdx.x;   // 128
    const float* st = (t < 64) ? nstats : estats;
    float inv = (t < 64) ? invN : invE;
    int c = t & 63;
    float s = 0.f, q = 0.f;
    #pragma unroll
    for (int r = 0; r < 8; r++) { s += st[r * 128 + c]; q += st[r * 128 + 64 + c]; }
    float mean = s * inv;
    float var = q * inv - mean * mean;
    float rinv = rsqrtf(var + 1e-5f);
    float sc = (t < 64) ? vs[c] : es[c];
    float bi = (t < 64) ? vb[c] : eb[c];
    float kmul = rinv * sc;
    float kadd = bi - mean * kmul;
    int base = (t < 64) ? 0 : 128;
    fin[base + c] = kmul;
    fin[base + 64 + c] = kadd;
}

// ---------- node BN apply ----------
__global__ __launch_bounds__(256)
void node_apply_kernel(const float4* __restrict__ hv4, const float4* __restrict__ xold4,
                       float4* __restrict__ out4, const float* __restrict__ fin, int total) {
    __shared__ float km[64], ka[64];
    if (threadIdx.x < 64) { km[threadIdx.x] = fin[threadIdx.x]; ka[threadIdx.x] = fin[64 + threadIdx.x]; }
    __syncthreads();
    int idx = blockIdx.x * 256 + threadIdx.x;
    if (idx >= total) return;
    int c0 = (idx & 15) * 4;
    float4 h = hv4[idx], xo = xold4[idx];
    float4 m = *(float4*)&km[c0], a = *(float4*)&ka[c0];
    float g0 = h.x * m.x + a.x, g1 = h.y * m.y + a.y, g2 = h.z * m.z + a.z, g3 = h.w * m.w + a.w;
    out4[idx] = make_float4(xo.x + silu(g0), xo.y + silu(g1),
                            xo.z + silu(g2), xo.w + silu(g3));
}

// ---------- final edge update: out_w[eidx[j]] = w_csr[j] + silu(h_e[j]*km+ka), fp32 ----------
__global__ __launch_bounds__(256)
void edge_update_final(const __hip_bfloat16* __restrict__ h_e, const __hip_bfloat16* __restrict__ w_csr,
                       const int* __restrict__ eidx, float* __restrict__ out_w,
                       const float* __restrict__ fin, long long total8) {
    __shared__ float km[64], ka[64];
    if (threadIdx.x < 64) { km[threadIdx.x] = fin[128 + threadIdx.x]; ka[threadIdx.x] = fin[192 + threadIdx.x]; }
    __syncthreads();
    for (long long t = blockIdx.x * 256LL + threadIdx.x; t < total8; t += gridDim.x * 256LL) {
        long long j = t >> 3;
        int c8 = (int)(t & 7) * 8;
        uint4 hu = *(const uint4*)&h_e[j * 64 + c8];
        uint4 wu = *(const uint4*)&w_csr[j * 64 + c8];
        int e = eidx[j];
        unsigned uh[4] = {hu.x, hu.y, hu.z, hu.w};
        unsigned uw[4] = {wu.x, wu.y, wu.z, wu.w};
        float4 m0 = *(float4*)&km[c8], m1 = *(float4*)&km[c8 + 4];
        float4 a0 = *(float4*)&ka[c8], a1 = *(float4*)&ka[c8 + 4];
        float mv[8] = {m0.x, m0.y, m0.z, m0.w, m1.x, m1.y, m1.z, m1.w};
        float av[8] = {a0.x, a0.y, a0.z, a0.w, a1.x, a1.y, a1.z, a1.w};
        float o[8];
        #pragma unroll
        for (int j2 = 0; j2 < 4; j2++) {
            o[2*j2]   = bflo(uw[j2]) + silu(bflo(uh[j2]) * mv[2*j2]   + av[2*j2]);
            o[2*j2+1] = bfhi(uw[j2]) + silu(bfhi(uh[j2]) * mv[2*j2+1] + av[2*j2+1]);
        }
        float* op = out_w + (long long)e * 64 + c8;
        *(float4*)op       = make_float4(o[0], o[1], o[2], o[3]);
        *(float4*)(op + 4) = make_float4(o[4], o[5], o[6], o[7]);
    }
}

// ---------- launch ----------
extern "C" void kernel_launch(void* const* d_in, const int* in_sizes, int n_in,
                              void* d_out, int out_size, void* d_ws, size_t ws_size,
                              hipStream_t stream) {
    const float* x_in  = (const float*)d_in[0];
    const float* ea_in = (const float*)d_in[1];
    const int*   ei    = (const int*)d_in[2];
    const float* v_w   = (const float*)d_in[3];
    const float* v_b   = (const float*)d_in[4];
    const float* e_w   = (const float*)d_in[5];
    const float* e_b   = (const float*)d_in[6];
    const float* vbn_s = (const float*)d_in[7];
    const float* vbn_b = (const float*)d_in[8];
    const float* ebn_s = (const float*)d_in[9];
    const float* ebn_b = (const float*)d_in[10];

    const int Nn = in_sizes[0] / 64;
    const int E  = in_sizes[1] / 64;
    const int L  = in_sizes[3] / (4 * 64 * 64);

    const int* dst = ei;
    const int* src = ei + E;

    // workspace layout
    float* h_v    = (float*)d_ws;                       // [Nn][64] fp32
    float* nstats = h_v + (long long)Nn * 64;           // [L][8][128]
    float* estats = nstats + (long long)L * 1024;       // [L][8][128]
    float* fin    = estats + (long long)L * 1024;       // [4][64]
    __hip_bfloat16* xp    = (__hip_bfloat16*)(fin + 256);       // [4][Nn][64]
    __hip_bfloat16* h_e   = xp + (long long)4 * Nn * 64;        // [E][64] CSR order
    __hip_bfloat16* w_csr = h_e + (long long)E * 64;            // [E][64] CSR order
    short* vwp = (short*)(w_csr + (long long)E * 64);   // [L][4][4][2][64][8]
    short* ewp = vwp + (long long)L * 16384;            // [L][4][2][64][8]
    int* cnt  = (int*)(ewp + (long long)L * 4096);      // [Nn]
    int* off  = cnt + Nn;                               // [Nn+1]
    int* eidx = off + Nn + 1;                           // [E]
    int* dstc = eidx + E;                               // [E]
    int* srcc = dstc + E;                               // [E]

    size_t needed = ((size_t)Nn * 64 + (size_t)L * 2048 + 256) * 4 +
                    ((size_t)4 * Nn * 64 + (size_t)2 * E * 64 + (size_t)L * 20480) * 2 +
                    ((size_t)2 * Nn + 1 + (size_t)3 * E) * 4;
    if (ws_size < needed) return;

    float* out_x = (float*)d_out;
    float* out_w = out_x + (long long)Nn * 64;

    // CSR build + zero stats + pack weights (once per call)
    zero_int_kernel<<<64, 256, 0, stream>>>(cnt, Nn);
    zero_int_kernel<<<8, 256, 0, stream>>>((int*)nstats, L * 2048);
    count_kernel<<<(E + 255) / 256, 256, 0, stream>>>(dst, cnt, E);
    scan_kernel<<<1, 1024, 0, stream>>>(cnt, off, Nn);
    fill_csr_kernel<<<(E + 255) / 256, 256, 0, stream>>>(dst, src, off, cnt, eidx, dstc, srcc, E);
    pack_kernel<<<(L * 2560 + 255) / 256, 256, 0, stream>>>(v_w, e_w, vwp, ewp, L);

    const __hip_bfloat16* x1 = xp;
    const __hip_bfloat16* x2 = xp + (long long)Nn * 64;
    const __hip_bfloat16* x3 = xp + (long long)2 * Nn * 64;
    const __hip_bfloat16* x4 = xp + (long long)3 * Nn * 64;

    for (int l = 0; l < L; l++) {
        const float* xl = (l == 0) ? x_in : out_x;
        float* nst = nstats + (long long)l * 1024;
        float* est = estats + (long long)l * 1024;

        // node projections -> xp[4]
        node_gemm_mfma<<<(Nn + 63) / 64, 256, 0, stream>>>(
            xl, vwp + (long long)l * 16384, v_b + l * 256, xp, Nn);

        // edge GEMM (CSR) + fused w-update + h_e + edge stats
        if (l == 0)
            edge_gemm_mfma<0><<<E / 64, 256, 0, stream>>>(
                ea_in, eidx, w_csr, h_e, fin, ewp + (long long)l * 4096, e_b + l * 64,
                x3, x4, dstc, srcc, est);
        else
            edge_gemm_mfma<1><<<E / 64, 256, 0, stream>>>(
                ea_in, eidx, w_csr, h_e, fin, ewp + (long long)l * 4096, e_b + l * 64,
                x3, x4, dstc, srcc, est);

        // h_v = x1 + mean(sigmoid(w_csr)*x2[src_csr]); node stats (w_csr contiguous)
        node_finish_kernel<<<(Nn + 7) / 8, 256, 0, stream>>>(
            w_csr, srcc, x2, x1, off, h_v, nst, Nn);

        finalize_kernel<<<1, 128, 0, stream>>>(
            nst, est, vbn_s + l * 64, vbn_b + l * 64,
            ebn_s + l * 64, ebn_b + l * 64, fin, 1.f / (float)Nn, 1.f / (float)E);

        node_apply_kernel<<<(Nn * 16 + 255) / 256, 256, 0, stream>>>(
            (const float4*)h_v, (const float4*)xl, (float4*)out_x, fin, Nn * 16);
    }

    // final edge update -> out_w (fp32), scatter full rows to edge-id order
    edge_update_final<<<4096, 256, 0, stream>>>(
        h_e, w_csr, eidx, out_w, fin, (long long)E * 8);
}

// Round 9
// 796.283 us; speedup vs baseline: 6.1990x; 1.0235x over previous
//
#include <hip/hip_runtime.h>
#include <hip/hip_bf16.h>
#include <math.h>

typedef __attribute__((ext_vector_type(8))) short bf16x8;
typedef __attribute__((ext_vector_type(4))) float f32x4;

// ---------- bf16 helpers ----------
__device__ __forceinline__ float bflo(unsigned u) { return __uint_as_float(u << 16); }
__device__ __forceinline__ float bfhi(unsigned u) { return __uint_as_float(u & 0xffff0000u); }
__device__ __forceinline__ unsigned packbf(float a, float b) {
    unsigned ua = __float_as_uint(a), ub = __float_as_uint(b);
    ua += 0x7fffu + ((ua >> 16) & 1u);
    ub += 0x7fffu + ((ub >> 16) & 1u);
    return (ua >> 16) | (ub & 0xffff0000u);
}
__device__ __forceinline__ float silu(float g) { return g / (1.f + __expf(-g)); }

// ---------- setup ----------
__global__ void zero_int_kernel(int* __restrict__ p, int n) {
    int i = blockIdx.x * blockDim.x + threadIdx.x;
    int s = gridDim.x * blockDim.x;
    for (; i < n; i += s) p[i] = 0;
}

__global__ void count_kernel(const int* __restrict__ dst, int* __restrict__ cnt, int E) {
    int e = blockIdx.x * blockDim.x + threadIdx.x;
    if (e < E) atomicAdd(&cnt[dst[e]], 1);
}

// 3-phase scan: block-local inclusive -> top exclusive -> add
__global__ __launch_bounds__(1024)
void scan_block_kernel(const int* __restrict__ cnt, int* __restrict__ off,
                       int* __restrict__ bsum, int n) {
    __shared__ int wsum[16];
    int tid = threadIdx.x, lane = tid & 63, wid = tid >> 6;
    int i = blockIdx.x * 1024 + tid;
    int v = (i < n) ? cnt[i] : 0;
    int sc = v;
    #pragma unroll
    for (int s = 1; s < 64; s <<= 1) {
        int t = __shfl_up(sc, (unsigned)s, 64);
        if (lane >= s) sc += t;
    }
    if (lane == 63) wsum[wid] = sc;
    __syncthreads();
    int woff = 0;
    for (int k = 0; k < wid; k++) woff += wsum[k];
    if (i < n) off[i + 1] = woff + sc;
    if (tid == 0) {
        int t = 0;
        #pragma unroll
        for (int k = 0; k < 16; k++) t += wsum[k];
        bsum[blockIdx.x] = t;
    }
}

__global__ void scan_tops_kernel(int* __restrict__ bsum, int nb) {
    int lane = threadIdx.x;   // 64 threads, nb <= 64
    int v = (lane < nb) ? bsum[lane] : 0;
    int sc = v;
    #pragma unroll
    for (int s = 1; s < 64; s <<= 1) {
        int t = __shfl_up(sc, (unsigned)s, 64);
        if (lane >= s) sc += t;
    }
    if (lane < nb) bsum[lane] = sc - v;   // exclusive
}

__global__ __launch_bounds__(1024)
void scan_add_kernel(int* __restrict__ off, const int* __restrict__ bsum, int n) {
    int i = blockIdx.x * 1024 + threadIdx.x;
    int b = bsum[blockIdx.x];
    if (i < n) off[i + 1] += b;
    if (i == 0) off[0] = 0;
}

// CSR fill: eidx/dst_csr/src_csr per slot; consumes cnt (leaves zeros)
__global__ void fill_csr_kernel(const int* __restrict__ dst, const int* __restrict__ src,
                                const int* __restrict__ off, int* __restrict__ cnt,
                                int* __restrict__ eidx, int* __restrict__ dstc,
                                int* __restrict__ srcc, int E) {
    int e = blockIdx.x * blockDim.x + threadIdx.x;
    if (e < E) {
        int d = dst[e];
        int pos = atomicSub(&cnt[d], 1) - 1;
        int slot = off[d] + pos;
        eidx[slot] = e;
        dstc[slot] = d;
        srcc[slot] = src[e];
    }
}

// ---------- pack weights into MFMA A-operand fragments (W^T, bf16) ----------
__global__ void pack_kernel(const float* __restrict__ v_w, const float* __restrict__ e_w,
                            short* __restrict__ vwp, short* __restrict__ ewp, int L) {
    int t = blockIdx.x * blockDim.x + threadIdx.x;
    if (t >= L * 5 * 4 * 2 * 64) return;
    int lane = t & 63;
    int ks = (t >> 6) & 1;
    int ft = (t >> 7) & 3;
    int mat = t >> 9;
    int layer = mat / 5, mi = mat % 5;
    const float* W = (mi < 4) ? (v_w + (long long)(layer * 4 + mi) * 4096)
                              : (e_w + (long long)layer * 4096);
    int m = ft * 16 + (lane & 15);
    int k0 = ks * 32 + (lane >> 4) * 8;
    short* dstp = (mi < 4)
        ? vwp + ((((long long)(layer * 4 + mi) * 4 + ft) * 2 + ks) * 64 + lane) * 8
        : ewp + ((((long long)layer * 4 + ft) * 2 + ks) * 64 + lane) * 8;
    #pragma unroll
    for (int j = 0; j < 8; j++) {
        unsigned u = __float_as_uint(W[(k0 + j) * 64 + m]);
        u += 0x7fffu + ((u >> 16) & 1u);
        dstp[j] = (short)(u >> 16);
    }
}

// ---------- node GEMM (MFMA): xp[g][n][f] = bf16(x@v_w[g] + v_b[g]), LDS epilogue ----------
__global__ __launch_bounds__(256)
void node_gemm_mfma(const float* __restrict__ X, const short* __restrict__ vwp,
                    const float* __restrict__ vb, __hip_bfloat16* __restrict__ xp,
                    int Nn) {
    __shared__ short Xs[64 * 64];
    __shared__ short Hs[4][64 * 64];
    int tid = threadIdx.x;
    long long row0 = (long long)blockIdx.x * 64;

    {
        int r = tid >> 2, cq = tid & 3;
        long long row = row0 + r;
        float4 v0 = {0,0,0,0}, v1 = {0,0,0,0}, v2 = {0,0,0,0}, v3 = {0,0,0,0};
        if (row < Nn) {
            const float* sp = X + row * 64 + cq * 16;
            v0 = *(const float4*)(sp);     v1 = *(const float4*)(sp + 4);
            v2 = *(const float4*)(sp + 8); v3 = *(const float4*)(sp + 12);
        }
        uint4 w0, w1;
        w0.x = packbf(v0.x, v0.y); w0.y = packbf(v0.z, v0.w);
        w0.z = packbf(v1.x, v1.y); w0.w = packbf(v1.z, v1.w);
        w1.x = packbf(v2.x, v2.y); w1.y = packbf(v2.z, v2.w);
        w1.z = packbf(v3.x, v3.y); w1.w = packbf(v3.z, v3.w);
        int base = r * 128 + cq * 32, swz = (r & 7) << 4;
        *(uint4*)((char*)Xs + (base ^ swz)) = w0;
        *(uint4*)((char*)Xs + ((base + 16) ^ swz)) = w1;
    }
    __syncthreads();

    int l = tid & 63, wv = tid >> 6;
    int rl = wv * 16 + (l & 15);
    bf16x8 bfr[2];
    #pragma unroll
    for (int ks = 0; ks < 2; ks++) {
        int off = (rl * 128 + ks * 64 + (l >> 4) * 16) ^ ((rl & 7) << 4);
        bfr[ks] = *(bf16x8*)((char*)Xs + off);
    }
    int q4 = (l >> 4) * 4;
    for (int g = 0; g < 4; g++) {
        #pragma unroll
        for (int ft = 0; ft < 4; ft++) {
            f32x4 acc = f32x4{0.f, 0.f, 0.f, 0.f};
            #pragma unroll
            for (int ks = 0; ks < 2; ks++) {
                bf16x8 a = *(const bf16x8*)(vwp + (((long long)(g * 4 + ft) * 2 + ks) * 64 + l) * 8);
                acc = __builtin_amdgcn_mfma_f32_16x16x32_bf16(a, bfr[ks], acc, 0, 0, 0);
            }
            int f0 = ft * 16 + q4;
            float4 bv = *(const float4*)&vb[g * 64 + f0];
            uint2 o;
            o.x = packbf(acc[0] + bv.x, acc[1] + bv.y);
            o.y = packbf(acc[2] + bv.z, acc[3] + bv.w);
            int hoff = (rl * 128 + f0 * 2) ^ ((rl & 7) << 4);
            *(uint2*)((char*)Hs[g] + hoff) = o;
        }
    }
    __syncthreads();
    int r = tid >> 2, cc = (tid & 3) * 16;
    long long node = row0 + r;
    if (node < Nn) {
        int swz = (r & 7) << 4;
        #pragma unroll
        for (int g = 0; g < 4; g++) {
            uint4 a = *(uint4*)((char*)Hs[g] + ((r * 128 + cc * 2) ^ swz));
            uint4 b = *(uint4*)((char*)Hs[g] + ((r * 128 + cc * 2 + 16) ^ swz));
            __hip_bfloat16* op = xp + ((long long)g * Nn + node) * 64 + cc;
            *(uint4*)op = a;
            *(uint4*)(op + 8) = b;
        }
    }
}

// ---------- edge GEMM (MFMA), wave-autonomous, CSR state, fused w-update ----------
// MODE 0 (layer 0): w = bf16(ea_in[eidx[j]]), write w_csr.
// MODE 1 (layer >=1): w = w_csr + silu(h_e*km + ka) (fin of layer l-1), write back.
// Per wave: 16 edges. Fragments loaded per-lane from global (no staging barrier).
template <int MODE>
__global__ __launch_bounds__(256)
void edge_gemm_mfma(const float* __restrict__ ea, const int* __restrict__ eidx,
                    __hip_bfloat16* __restrict__ w_csr, __hip_bfloat16* __restrict__ h_e,
                    const float* __restrict__ fin,
                    const short* __restrict__ ewp, const float* __restrict__ eb,
                    const __hip_bfloat16* __restrict__ x3, const __hip_bfloat16* __restrict__ x4,
                    const int* __restrict__ dstc, const int* __restrict__ srcc,
                    float* __restrict__ estats) {
    __shared__ short Hs[4][16 * 72];          // per-wave bf16 acc+bias tile
    __shared__ float sred[4][128];            // per-wave stats partials
    int tid = threadIdx.x;
    int l = tid & 63, wv = tid >> 6;
    long long row0w = (long long)blockIdx.x * 64 + wv * 16;

    int rl = l & 15;            // edge within wave (fragment col)
    int kg = l >> 4;            // k-group 0..3
    long long myrow = row0w + rl;

    // ---- load/update w fragments (per-lane 16B, contiguous coverage) ----
    bf16x8 wfrag[2];
    #pragma unroll
    for (int ks = 0; ks < 2; ks++) {
        long long off = myrow * 64 + ks * 32 + kg * 8;
        uint4 p;
        if (MODE == 0) {
            long long e0 = eidx[myrow];
            const float* sp = ea + e0 * 64 + ks * 32 + kg * 8;
            float4 v0 = *(const float4*)sp, v1 = *(const float4*)(sp + 4);
            p.x = packbf(v0.x, v0.y); p.y = packbf(v0.z, v0.w);
            p.z = packbf(v1.x, v1.y); p.w = packbf(v1.z, v1.w);
        } else {
            uint4 wo = *(const uint4*)&w_csr[off];
            uint4 ho = *(const uint4*)&h_e[off];
            int f0 = ks * 32 + kg * 8;
            float4 km0 = *(const float4*)&fin[128 + f0], km1 = *(const float4*)&fin[128 + f0 + 4];
            float4 ka0 = *(const float4*)&fin[192 + f0], ka1 = *(const float4*)&fin[192 + f0 + 4];
            float kmv[8] = {km0.x, km0.y, km0.z, km0.w, km1.x, km1.y, km1.z, km1.w};
            float kav[8] = {ka0.x, ka0.y, ka0.z, ka0.w, ka1.x, ka1.y, ka1.z, ka1.w};
            unsigned uw[4] = {wo.x, wo.y, wo.z, wo.w};
            unsigned uh[4] = {ho.x, ho.y, ho.z, ho.w};
            float wn[8];
            #pragma unroll
            for (int j = 0; j < 4; j++) {
                wn[2*j]   = bflo(uw[j]) + silu(bflo(uh[j]) * kmv[2*j]   + kav[2*j]);
                wn[2*j+1] = bfhi(uw[j]) + silu(bfhi(uh[j]) * kmv[2*j+1] + kav[2*j+1]);
            }
            p.x = packbf(wn[0], wn[1]); p.y = packbf(wn[2], wn[3]);
            p.z = packbf(wn[4], wn[5]); p.w = packbf(wn[6], wn[7]);
        }
        *(uint4*)&w_csr[off] = p;             // materialize w(l)
        wfrag[ks] = *(bf16x8*)&p;
    }

    // ---- epilogue prefetch: x4 random gather issued before MFMA ----
    int rr = l >> 2, cq = l & 3;
    long long prow = row0w + rr;
    int de = dstc[prow], se = srcc[prow];
    int c16 = cq * 16;
    uint4 x4a = *(const uint4*)&x4[(long long)se * 64 + c16];
    uint4 x4b = *(const uint4*)&x4[(long long)se * 64 + c16 + 8];

    // ---- MFMA (A-frags L1-hot, shared by all blocks) ----
    f32x4 acc[4];
    #pragma unroll
    for (int ft = 0; ft < 4; ft++) {
        acc[ft] = f32x4{0.f, 0.f, 0.f, 0.f};
        #pragma unroll
        for (int ks = 0; ks < 2; ks++) {
            bf16x8 a = *(const bf16x8*)(ewp + (((long long)ft * 2 + ks) * 64 + l) * 8);
            acc[ft] = __builtin_amdgcn_mfma_f32_16x16x32_bf16(a, wfrag[ks], acc[ft], 0, 0, 0);
        }
    }

    // ---- write acc+bias to own wave's LDS tile ----
    #pragma unroll
    for (int ft = 0; ft < 4; ft++) {
        int f0 = ft * 16 + kg * 4;
        float4 bv = *(const float4*)&eb[f0];
        uint2 o;
        o.x = packbf(acc[ft][0] + bv.x, acc[ft][1] + bv.y);
        o.y = packbf(acc[ft][2] + bv.z, acc[ft][3] + bv.w);
        *(uint2*)&Hs[wv][rl * 72 + f0] = o;
    }

    // x3 gather (CSR dst-sorted -> near-broadcast, L1-hot)
    uint4 x3a = *(const uint4*)&x3[(long long)de * 64 + c16];
    uint4 x3b = *(const uint4*)&x3[(long long)de * 64 + c16 + 8];

    // ---- read back own wave's tile (wave-internal lgkmcnt ordering) ----
    uint4 h0u = *(uint4*)&Hs[wv][rr * 72 + c16];
    uint4 h1u = *(uint4*)&Hs[wv][rr * 72 + c16 + 8];
    unsigned uh2[8] = {h0u.x, h0u.y, h0u.z, h0u.w, h1u.x, h1u.y, h1u.z, h1u.w};
    unsigned u3[8] = {x3a.x, x3a.y, x3a.z, x3a.w, x3b.x, x3b.y, x3b.z, x3b.w};
    unsigned u4[8] = {x4a.x, x4a.y, x4a.z, x4a.w, x4b.x, x4b.y, x4b.z, x4b.w};
    float h[16];
    #pragma unroll
    for (int i = 0; i < 8; i++) {
        h[2*i]   = bflo(uh2[i]) + bflo(u3[i]) + bflo(u4[i]);
        h[2*i+1] = bfhi(uh2[i]) + bfhi(u3[i]) + bfhi(u4[i]);
    }
    uint4 hv0, hv1;
    hv0.x = packbf(h[0], h[1]);   hv0.y = packbf(h[2], h[3]);
    hv0.z = packbf(h[4], h[5]);   hv0.w = packbf(h[6], h[7]);
    hv1.x = packbf(h[8], h[9]);   hv1.y = packbf(h[10], h[11]);
    hv1.z = packbf(h[12], h[13]); hv1.w = packbf(h[14], h[15]);
    *(uint4*)&h_e[prow * 64 + c16] = hv0;
    *(uint4*)&h_e[prow * 64 + c16 + 8] = hv1;

    // ---- stats: reduce over 16 rows (lane bits 2-5); lanes 0-3 hold feats l*16+j ----
    #pragma unroll
    for (int j = 0; j < 16; j++) {
        float sv = h[j], qv = h[j] * h[j];
        sv += __shfl_xor(sv, 4);  qv += __shfl_xor(qv, 4);
        sv += __shfl_xor(sv, 8);  qv += __shfl_xor(qv, 8);
        sv += __shfl_xor(sv, 16); qv += __shfl_xor(qv, 16);
        sv += __shfl_xor(sv, 32); qv += __shfl_xor(qv, 32);
        if (l < 4) {
            sred[wv][c16 + j] = sv;
            sred[wv][64 + c16 + j] = qv;
        }
    }
    __syncthreads();   // only barrier in kernel
    if (tid < 128) {
        float v = sred[0][tid] + sred[1][tid] + sred[2][tid] + sred[3][tid];
        atomicAdd(&estats[(blockIdx.x & 7) * 128 + tid], v);
    }
}

// ---------- node finish: h = x1 + mean_j(sigmoid(w_csr[j])*x2[src_csr[j]]); node stats ----------
__global__ __launch_bounds__(256)
void node_finish_kernel(const __hip_bfloat16* __restrict__ w_csr, const int* __restrict__ srcc,
                        const __hip_bfloat16* __restrict__ x2, const __hip_bfloat16* __restrict__ x1,
                        const int* __restrict__ off, float* __restrict__ h_v,
                        float* __restrict__ nstats, int Nn) {
    __shared__ float red[8 * 66];
    int tid = threadIdx.x;
    int hw = tid >> 5, k = tid & 31;
    int n = blockIdx.x * 8 + hw;
    float h0 = 0.f, h1 = 0.f;
    if (n < Nn) {
        int o0 = off[n], o1 = off[n + 1];
        float a0 = 0.f, a1 = 0.f;
        for (int j = o0; j < o1; j++) {
            int s = srcc[j];
            unsigned wu = *(const unsigned*)&w_csr[(long long)j * 64 + 2 * k];
            unsigned xu = *(const unsigned*)&x2[(long long)s * 64 + 2 * k];
            a0 += bflo(xu) / (1.f + __expf(-bflo(wu)));
            a1 += bfhi(xu) / (1.f + __expf(-bfhi(wu)));
        }
        float ic = 1.f / fmaxf((float)(o1 - o0), 1.f);
        unsigned xu = *(const unsigned*)&x1[(long long)n * 64 + 2 * k];
        h0 = bflo(xu) + a0 * ic;
        h1 = bfhi(xu) + a1 * ic;
        *(float2*)&h_v[(long long)n * 64 + 2 * k] = make_float2(h0, h1);
    }
    red[hw * 66 + 2 * k] = h0;
    red[hw * 66 + 2 * k + 1] = h1;
    __syncthreads();
    float* nst = nstats + (blockIdx.x & 7) * 128;
    if (tid < 64) {
        float s = 0.f;
        #pragma unroll
        for (int r = 0; r < 8; r++) s += red[r * 66 + tid];
        atomicAdd(&nst[tid], s);
    }
    __syncthreads();
    red[hw * 66 + 2 * k] = h0 * h0;
    red[hw * 66 + 2 * k + 1] = h1 * h1;
    __syncthreads();
    if (tid < 64) {
        float s = 0.f;
        #pragma unroll
        for (int r = 0; r < 8; r++) s += red[r * 66 + tid];
        atomicAdd(&nst[64 + tid], s);
    }
}

// ---------- finalize: stats -> (kmul, kadd) ----------
__global__ void finalize_kernel(const float* __restrict__ nstats, const float* __restrict__ estats,
                                const float* __restrict__ vs, const float* __restrict__ vb,
                                const float* __restrict__ es, const float* __restrict__ eb,
                                float* __restrict__ fin, float invN, float invE) {
    int t = threadIdx.x;   // 128
    const float* st = (t < 64) ? nstats : estats;
    float inv = (t < 64) ? invN : invE;
    int c = t & 63;
    float s = 0.f, q = 0.f;
    #pragma unroll
    for (int r = 0; r < 8; r++) { s += st[r * 128 + c]; q += st[r * 128 + 64 + c]; }
    float mean = s * inv;
    float var = q * inv - mean * mean;
    float rinv = rsqrtf(var + 1e-5f);
    float sc = (t < 64) ? vs[c] : es[c];
    float bi = (t < 64) ? vb[c] : eb[c];
    float kmul = rinv * sc;
    float kadd = bi - mean * kmul;
    int base = (t < 64) ? 0 : 128;
    fin[base + c] = kmul;
    fin[base + 64 + c] = kadd;
}

// ---------- node BN apply ----------
__global__ __launch_bounds__(256)
void node_apply_kernel(const float4* __restrict__ hv4, const float4* __restrict__ xold4,
                       float4* __restrict__ out4, const float* __restrict__ fin, int total) {
    __shared__ float km[64], ka[64];
    if (threadIdx.x < 64) { km[threadIdx.x] = fin[threadIdx.x]; ka[threadIdx.x] = fin[64 + threadIdx.x]; }
    __syncthreads();
    int idx = blockIdx.x * 256 + threadIdx.x;
    if (idx >= total) return;
    int c0 = (idx & 15) * 4;
    float4 h = hv4[idx], xo = xold4[idx];
    float4 m = *(float4*)&km[c0], a = *(float4*)&ka[c0];
    float g0 = h.x * m.x + a.x, g1 = h.y * m.y + a.y, g2 = h.z * m.z + a.z, g3 = h.w * m.w + a.w;
    out4[idx] = make_float4(xo.x + silu(g0), xo.y + silu(g1),
                            xo.z + silu(g2), xo.w + silu(g3));
}

// ---------- final edge update: out_w[eidx[j]] = w_csr[j] + silu(h_e[j]*km+ka), fp32 ----------
__global__ __launch_bounds__(256)
void edge_update_final(const __hip_bfloat16* __restrict__ h_e, const __hip_bfloat16* __restrict__ w_csr,
                       const int* __restrict__ eidx, float* __restrict__ out_w,
                       const float* __restrict__ fin, long long total8) {
    __shared__ float km[64], ka[64];
    if (threadIdx.x < 64) { km[threadIdx.x] = fin[128 + threadIdx.x]; ka[threadIdx.x] = fin[192 + threadIdx.x]; }
    __syncthreads();
    for (long long t = blockIdx.x * 256LL + threadIdx.x; t < total8; t += gridDim.x * 256LL) {
        long long j = t >> 3;
        int c8 = (int)(t & 7) * 8;
        uint4 hu = *(const uint4*)&h_e[j * 64 + c8];
        uint4 wu = *(const uint4*)&w_csr[j * 64 + c8];
        int e = eidx[j];
        unsigned uh[4] = {hu.x, hu.y, hu.z, hu.w};
        unsigned uw[4] = {wu.x, wu.y, wu.z, wu.w};
        float4 m0 = *(float4*)&km[c8], m1 = *(float4*)&km[c8 + 4];
        float4 a0 = *(float4*)&ka[c8], a1 = *(float4*)&ka[c8 + 4];
        float mv[8] = {m0.x, m0.y, m0.z, m0.w, m1.x, m1.y, m1.z, m1.w};
        float av[8] = {a0.x, a0.y, a0.z, a0.w, a1.x, a1.y, a1.z, a1.w};
        float o[8];
        #pragma unroll
        for (int j2 = 0; j2 < 4; j2++) {
            o[2*j2]   = bflo(uw[j2]) + silu(bflo(uh[j2]) * mv[2*j2]   + av[2*j2]);
            o[2*j2+1] = bfhi(uw[j2]) + silu(bfhi(uh[j2]) * mv[2*j2+1] + av[2*j2+1]);
        }
        float* op = out_w + (long long)e * 64 + c8;
        *(float4*)op       = make_float4(o[0], o[1], o[2], o[3]);
        *(float4*)(op + 4) = make_float4(o[4], o[5], o[6], o[7]);
    }
}

// ---------- launch ----------
extern "C" void kernel_launch(void* const* d_in, const int* in_sizes, int n_in,
                              void* d_out, int out_size, void* d_ws, size_t ws_size,
                              hipStream_t stream) {
    const float* x_in  = (const float*)d_in[0];
    const float* ea_in = (const float*)d_in[1];
    const int*   ei    = (const int*)d_in[2];
    const float* v_w   = (const float*)d_in[3];
    const float* v_b   = (const float*)d_in[4];
    const float* e_w   = (const float*)d_in[5];
    const float* e_b   = (const float*)d_in[6];
    const float* vbn_s = (const float*)d_in[7];
    const float* vbn_b = (const float*)d_in[8];
    const float* ebn_s = (const float*)d_in[9];
    const float* ebn_b = (const float*)d_in[10];

    const int Nn = in_sizes[0] / 64;
    const int E  = in_sizes[1] / 64;
    const int L  = in_sizes[3] / (4 * 64 * 64);

    const int* dst = ei;
    const int* src = ei + E;

    // workspace layout
    float* h_v    = (float*)d_ws;                       // [Nn][64] fp32
    float* nstats = h_v + (long long)Nn * 64;           // [L][8][128]
    float* estats = nstats + (long long)L * 1024;       // [L][8][128]
    float* fin    = estats + (long long)L * 1024;       // [4][64]
    __hip_bfloat16* xp    = (__hip_bfloat16*)(fin + 256);       // [4][Nn][64]
    __hip_bfloat16* h_e   = xp + (long long)4 * Nn * 64;        // [E][64] CSR order
    __hip_bfloat16* w_csr = h_e + (long long)E * 64;            // [E][64] CSR order
    short* vwp = (short*)(w_csr + (long long)E * 64);   // [L][4][4][2][64][8]
    short* ewp = vwp + (long long)L * 16384;            // [L][4][2][64][8]
    int* cnt  = (int*)(ewp + (long long)L * 4096);      // [Nn]
    int* off  = cnt + Nn;                               // [Nn+1]
    int* eidx = off + Nn + 1;                           // [E]
    int* dstc = eidx + E;                               // [E]
    int* srcc = dstc + E;                               // [E]
    int* bsum = srcc + E;                               // [64]

    size_t needed = ((size_t)Nn * 64 + (size_t)L * 2048 + 256) * 4 +
                    ((size_t)4 * Nn * 64 + (size_t)2 * E * 64 + (size_t)L * 20480) * 2 +
                    ((size_t)2 * Nn + 1 + (size_t)3 * E + 64) * 4;
    if (ws_size < needed) return;

    float* out_x = (float*)d_out;
    float* out_w = out_x + (long long)Nn * 64;

    // CSR build + zero stats + pack weights (once per call)
    const int nb = (Nn + 1023) / 1024;
    zero_int_kernel<<<64, 256, 0, stream>>>(cnt, Nn);
    zero_int_kernel<<<8, 256, 0, stream>>>((int*)nstats, L * 2048);
    count_kernel<<<(E + 255) / 256, 256, 0, stream>>>(dst, cnt, E);
    scan_block_kernel<<<nb, 1024, 0, stream>>>(cnt, off, bsum, Nn);
    scan_tops_kernel<<<1, 64, 0, stream>>>(bsum, nb);
    scan_add_kernel<<<nb, 1024, 0, stream>>>(off, bsum, Nn);
    fill_csr_kernel<<<(E + 255) / 256, 256, 0, stream>>>(dst, src, off, cnt, eidx, dstc, srcc, E);
    pack_kernel<<<(L * 2560 + 255) / 256, 256, 0, stream>>>(v_w, e_w, vwp, ewp, L);

    const __hip_bfloat16* x1 = xp;
    const __hip_bfloat16* x2 = xp + (long long)Nn * 64;
    const __hip_bfloat16* x3 = xp + (long long)2 * Nn * 64;
    const __hip_bfloat16* x4 = xp + (long long)3 * Nn * 64;

    for (int l = 0; l < L; l++) {
        const float* xl = (l == 0) ? x_in : out_x;
        float* nst = nstats + (long long)l * 1024;
        float* est = estats + (long long)l * 1024;

        // node projections -> xp[4]
        node_gemm_mfma<<<(Nn + 63) / 64, 256, 0, stream>>>(
            xl, vwp + (long long)l * 16384, v_b + l * 256, xp, Nn);

        // edge GEMM (CSR, wave-autonomous) + fused w-update + h_e + edge stats
        if (l == 0)
            edge_gemm_mfma<0><<<E / 64, 256, 0, stream>>>(
                ea_in, eidx, w_csr, h_e, fin, ewp + (long long)l * 4096, e_b + l * 64,
                x3, x4, dstc, srcc, est);
        else
            edge_gemm_mfma<1><<<E / 64, 256, 0, stream>>>(
                ea_in, eidx, w_csr, h_e, fin, ewp + (long long)l * 4096, e_b + l * 64,
                x3, x4, dstc, srcc, est);

        // h_v = x1 + mean(sigmoid(w_csr)*x2[src_csr]); node stats
        node_finish_kernel<<<(Nn + 7) / 8, 256, 0, stream>>>(
            w_csr, srcc, x2, x1, off, h_v, nst, Nn);

        finalize_kernel<<<1, 128, 0, stream>>>(
            nst, est, vbn_s + l * 64, vbn_b + l * 64,
            ebn_s + l * 64, ebn_b + l * 64, fin, 1.f / (float)Nn, 1.f / (float)E);

        node_apply_kernel<<<(Nn * 16 + 255) / 256, 256, 0, stream>>>(
            (const float4*)h_v, (const float4*)xl, (float4*)out_x, fin, Nn * 16);
    }

    // final edge update -> out_w (fp32), scatter full rows to edge-id order
    edge_update_final<<<4096, 256, 0, stream>>>(
        h_e, w_csr, eidx, out_w, fin, (long long)E * 8);
}

// Round 10
// 717.969 us; speedup vs baseline: 6.8752x; 1.1091x over previous
//
#include <hip/hip_runtime.h>
#include <hip/hip_bf16.h>
#include <math.h>

typedef __attribute__((ext_vector_type(8))) short bf16x8;
typedef __attribute__((ext_vector_type(4))) float f32x4;

// ---------- bf16 helpers ----------
__device__ __forceinline__ float bflo(unsigned u) { return __uint_as_float(u << 16); }
__device__ __forceinline__ float bfhi(unsigned u) { return __uint_as_float(u & 0xffff0000u); }
__device__ __forceinline__ unsigned packbf(float a, float b) {
    unsigned ua = __float_as_uint(a), ub = __float_as_uint(b);
    ua += 0x7fffu + ((ua >> 16) & 1u);
    ub += 0x7fffu + ((ub >> 16) & 1u);
    return (ua >> 16) | (ub & 0xffff0000u);
}
__device__ __forceinline__ float silu(float g) { return g / (1.f + __expf(-g)); }

// ---------- setup ----------
__global__ void zero_int_kernel(int* __restrict__ p, int n) {
    int i = blockIdx.x * blockDim.x + threadIdx.x;
    int s = gridDim.x * blockDim.x;
    for (; i < n; i += s) p[i] = 0;
}

__global__ void count_kernel(const int* __restrict__ dst, int* __restrict__ cnt, int E) {
    int e = blockIdx.x * blockDim.x + threadIdx.x;
    if (e < E) atomicAdd(&cnt[dst[e]], 1);
}

// 3-phase scan: block-local inclusive -> top exclusive -> add
__global__ __launch_bounds__(1024)
void scan_block_kernel(const int* __restrict__ cnt, int* __restrict__ off,
                       int* __restrict__ bsum, int n) {
    __shared__ int wsum[16];
    int tid = threadIdx.x, lane = tid & 63, wid = tid >> 6;
    int i = blockIdx.x * 1024 + tid;
    int v = (i < n) ? cnt[i] : 0;
    int sc = v;
    #pragma unroll
    for (int s = 1; s < 64; s <<= 1) {
        int t = __shfl_up(sc, (unsigned)s, 64);
        if (lane >= s) sc += t;
    }
    if (lane == 63) wsum[wid] = sc;
    __syncthreads();
    int woff = 0;
    for (int k = 0; k < wid; k++) woff += wsum[k];
    if (i < n) off[i + 1] = woff + sc;
    if (tid == 0) {
        int t = 0;
        #pragma unroll
        for (int k = 0; k < 16; k++) t += wsum[k];
        bsum[blockIdx.x] = t;
    }
}

__global__ void scan_tops_kernel(int* __restrict__ bsum, int nb) {
    int lane = threadIdx.x;   // 64 threads, nb <= 64
    int v = (lane < nb) ? bsum[lane] : 0;
    int sc = v;
    #pragma unroll
    for (int s = 1; s < 64; s <<= 1) {
        int t = __shfl_up(sc, (unsigned)s, 64);
        if (lane >= s) sc += t;
    }
    if (lane < nb) bsum[lane] = sc - v;   // exclusive
}

__global__ __launch_bounds__(1024)
void scan_add_kernel(int* __restrict__ off, const int* __restrict__ bsum, int n) {
    int i = blockIdx.x * 1024 + threadIdx.x;
    int b = bsum[blockIdx.x];
    if (i < n) off[i + 1] += b;
    if (i == 0) off[0] = 0;
}

// CSR fill: eidx/dst_csr/src_csr per slot; consumes cnt (leaves zeros)
__global__ void fill_csr_kernel(const int* __restrict__ dst, const int* __restrict__ src,
                                const int* __restrict__ off, int* __restrict__ cnt,
                                int* __restrict__ eidx, int* __restrict__ dstc,
                                int* __restrict__ srcc, int E) {
    int e = blockIdx.x * blockDim.x + threadIdx.x;
    if (e < E) {
        int d = dst[e];
        int pos = atomicSub(&cnt[d], 1) - 1;
        int slot = off[d] + pos;
        eidx[slot] = e;
        dstc[slot] = d;
        srcc[slot] = src[e];
    }
}

// ---------- pack weights into MFMA A-operand fragments (W^T, bf16) ----------
__global__ void pack_kernel(const float* __restrict__ v_w, const float* __restrict__ e_w,
                            short* __restrict__ vwp, short* __restrict__ ewp, int L) {
    int t = blockIdx.x * blockDim.x + threadIdx.x;
    if (t >= L * 5 * 4 * 2 * 64) return;
    int lane = t & 63;
    int ks = (t >> 6) & 1;
    int ft = (t >> 7) & 3;
    int mat = t >> 9;
    int layer = mat / 5, mi = mat % 5;
    const float* W = (mi < 4) ? (v_w + (long long)(layer * 4 + mi) * 4096)
                              : (e_w + (long long)layer * 4096);
    int m = ft * 16 + (lane & 15);
    int k0 = ks * 32 + (lane >> 4) * 8;
    short* dstp = (mi < 4)
        ? vwp + ((((long long)(layer * 4 + mi) * 4 + ft) * 2 + ks) * 64 + lane) * 8
        : ewp + ((((long long)layer * 4 + ft) * 2 + ks) * 64 + lane) * 8;
    #pragma unroll
    for (int j = 0; j < 8; j++) {
        unsigned u = __float_as_uint(W[(k0 + j) * 64 + m]);
        u += 0x7fffu + ((u >> 16) & 1u);
        dstp[j] = (short)(u >> 16);
    }
}

// ---------- node GEMM (MFMA): xp[g][n][f] = bf16(x@v_w[g] + v_b[g]), LDS epilogue ----------
__global__ __launch_bounds__(256)
void node_gemm_mfma(const float* __restrict__ X, const short* __restrict__ vwp,
                    const float* __restrict__ vb, __hip_bfloat16* __restrict__ xp,
                    int Nn) {
    __shared__ short Xs[64 * 64];
    __shared__ short Hs[4][64 * 64];
    int tid = threadIdx.x;
    long long row0 = (long long)blockIdx.x * 64;

    {
        int r = tid >> 2, cq = tid & 3;
        long long row = row0 + r;
        float4 v0 = {0,0,0,0}, v1 = {0,0,0,0}, v2 = {0,0,0,0}, v3 = {0,0,0,0};
        if (row < Nn) {
            const float* sp = X + row * 64 + cq * 16;
            v0 = *(const float4*)(sp);     v1 = *(const float4*)(sp + 4);
            v2 = *(const float4*)(sp + 8); v3 = *(const float4*)(sp + 12);
        }
        uint4 w0, w1;
        w0.x = packbf(v0.x, v0.y); w0.y = packbf(v0.z, v0.w);
        w0.z = packbf(v1.x, v1.y); w0.w = packbf(v1.z, v1.w);
        w1.x = packbf(v2.x, v2.y); w1.y = packbf(v2.z, v2.w);
        w1.z = packbf(v3.x, v3.y); w1.w = packbf(v3.z, v3.w);
        int base = r * 128 + cq * 32, swz = (r & 7) << 4;
        *(uint4*)((char*)Xs + (base ^ swz)) = w0;
        *(uint4*)((char*)Xs + ((base + 16) ^ swz)) = w1;
    }
    __syncthreads();

    int l = tid & 63, wv = tid >> 6;
    int rl = wv * 16 + (l & 15);
    bf16x8 bfr[2];
    #pragma unroll
    for (int ks = 0; ks < 2; ks++) {
        int off = (rl * 128 + ks * 64 + (l >> 4) * 16) ^ ((rl & 7) << 4);
        bfr[ks] = *(bf16x8*)((char*)Xs + off);
    }
    int q4 = (l >> 4) * 4;
    for (int g = 0; g < 4; g++) {
        #pragma unroll
        for (int ft = 0; ft < 4; ft++) {
            f32x4 acc = f32x4{0.f, 0.f, 0.f, 0.f};
            #pragma unroll
            for (int ks = 0; ks < 2; ks++) {
                bf16x8 a = *(const bf16x8*)(vwp + (((long long)(g * 4 + ft) * 2 + ks) * 64 + l) * 8);
                acc = __builtin_amdgcn_mfma_f32_16x16x32_bf16(a, bfr[ks], acc, 0, 0, 0);
            }
            int f0 = ft * 16 + q4;
            float4 bv = *(const float4*)&vb[g * 64 + f0];
            uint2 o;
            o.x = packbf(acc[0] + bv.x, acc[1] + bv.y);
            o.y = packbf(acc[2] + bv.z, acc[3] + bv.w);
            int hoff = (rl * 128 + f0 * 2) ^ ((rl & 7) << 4);
            *(uint2*)((char*)Hs[g] + hoff) = o;
        }
    }
    __syncthreads();
    int r = tid >> 2, cc = (tid & 3) * 16;
    long long node = row0 + r;
    if (node < Nn) {
        int swz = (r & 7) << 4;
        #pragma unroll
        for (int g = 0; g < 4; g++) {
            uint4 a = *(uint4*)((char*)Hs[g] + ((r * 128 + cc * 2) ^ swz));
            uint4 b = *(uint4*)((char*)Hs[g] + ((r * 128 + cc * 2 + 16) ^ swz));
            __hip_bfloat16* op = xp + ((long long)g * Nn + node) * 64 + cc;
            *(uint4*)op = a;
            *(uint4*)(op + 8) = b;
        }
    }
}

// ---------- edge GEMM (MFMA), block-staged (round-7 form), CSR state, fused w-update ----------
// MODE 0 (layer 0): w = bf16(ea_in[eidx[j]]), write w_csr.
// MODE 1 (layer >=1): w = w_csr + silu(h_e*km + ka) (fin of layer l-1), write back.
template <int MODE>
__global__ __launch_bounds__(256)
void edge_gemm_mfma(const float* __restrict__ ea, const int* __restrict__ eidx,
                    __hip_bfloat16* __restrict__ w_csr, __hip_bfloat16* __restrict__ h_e,
                    const float* __restrict__ fin,
                    const short* __restrict__ ewp, const float* __restrict__ eb,
                    const __hip_bfloat16* __restrict__ x3, const __hip_bfloat16* __restrict__ x4,
                    const int* __restrict__ dstc, const int* __restrict__ srcc,
                    float* __restrict__ estats) {
    __shared__ short Ws[64 * 64];            // 8 KB bf16 w tile, XOR-swizzled
    __shared__ short Hs[64 * 68];            // 8.5 KB bf16 acc+bias
    __shared__ float sredS[4][64], sredQ[4][64];
    __shared__ int dstl[64], srcl[64];
    int tid = threadIdx.x;
    long long row0 = (long long)blockIdx.x * 64;

    // ---- staging: w tile (+ fused update) -> Ws + w_csr ----
    {
        int r = tid >> 2, cq = tid & 3;
        long long grow = (row0 + r) * 64 + cq * 16;
        int base = r * 128 + cq * 32, swz = (r & 7) << 4;
        uint4 w0u, w1u;
        if (MODE == 0) {
            long long e0 = eidx[row0 + r];
            const float* sp = ea + e0 * 64 + cq * 16;
            float4 v0 = *(const float4*)(sp),     v1 = *(const float4*)(sp + 4);
            float4 v2 = *(const float4*)(sp + 8), v3 = *(const float4*)(sp + 12);
            w0u.x = packbf(v0.x, v0.y); w0u.y = packbf(v0.z, v0.w);
            w0u.z = packbf(v1.x, v1.y); w0u.w = packbf(v1.z, v1.w);
            w1u.x = packbf(v2.x, v2.y); w1u.y = packbf(v2.z, v2.w);
            w1u.z = packbf(v3.x, v3.y); w1u.w = packbf(v3.z, v3.w);
        } else {
            uint4 a = *(const uint4*)&w_csr[grow];
            uint4 b = *(const uint4*)&w_csr[grow + 8];
            unsigned ua[8] = {a.x, a.y, a.z, a.w, b.x, b.y, b.z, b.w};
            uint4 ha = *(const uint4*)&h_e[grow];
            uint4 hb = *(const uint4*)&h_e[grow + 8];
            unsigned uh[8] = {ha.x, ha.y, ha.z, ha.w, hb.x, hb.y, hb.z, hb.w};
            const float* kmp = fin + 128 + cq * 16;
            const float* kap = fin + 192 + cq * 16;
            float wn[16];
            #pragma unroll
            for (int j = 0; j < 8; j++) {
                wn[2*j]   = bflo(ua[j]) + silu(bflo(uh[j]) * kmp[2*j]   + kap[2*j]);
                wn[2*j+1] = bfhi(ua[j]) + silu(bfhi(uh[j]) * kmp[2*j+1] + kap[2*j+1]);
            }
            w0u.x = packbf(wn[0], wn[1]);  w0u.y = packbf(wn[2], wn[3]);
            w0u.z = packbf(wn[4], wn[5]);  w0u.w = packbf(wn[6], wn[7]);
            w1u.x = packbf(wn[8], wn[9]);  w1u.y = packbf(wn[10], wn[11]);
            w1u.z = packbf(wn[12], wn[13]); w1u.w = packbf(wn[14], wn[15]);
        }
        *(uint4*)&w_csr[grow] = w0u;           // materialize w(l)
        *(uint4*)&w_csr[grow + 8] = w1u;
        *(uint4*)((char*)Ws + (base ^ swz)) = w0u;
        *(uint4*)((char*)Ws + ((base + 16) ^ swz)) = w1u;
        if (tid < 64) {
            dstl[tid] = dstc[row0 + tid];
            srcl[tid] = srcc[row0 + tid];
        }
    }
    __syncthreads();

    // ---- issue epilogue gathers early (x3 near-sequential: CSR is dst-sorted) ----
    int rr0 = tid >> 3, rr1 = rr0 + 32;
    int c8 = (tid & 7) * 8;
    int de0 = dstl[rr0], se0 = srcl[rr0];
    int de1 = dstl[rr1], se1 = srcl[rr1];
    uint4 g3a = *(const uint4*)&x3[(long long)de0 * 64 + c8];
    uint4 g4a = *(const uint4*)&x4[(long long)se0 * 64 + c8];
    uint4 g3b = *(const uint4*)&x3[(long long)de1 * 64 + c8];
    uint4 g4b = *(const uint4*)&x4[(long long)se1 * 64 + c8];

    // ---- MFMA ----
    int l = tid & 63, wv = tid >> 6;
    int rl = wv * 16 + (l & 15);
    bf16x8 bfr[2];
    #pragma unroll
    for (int ks = 0; ks < 2; ks++) {
        int off = (rl * 128 + ks * 64 + (l >> 4) * 16) ^ ((rl & 7) << 4);
        bfr[ks] = *(bf16x8*)((char*)Ws + off);
    }
    int q4 = (l >> 4) * 4;
    #pragma unroll
    for (int ft = 0; ft < 4; ft++) {
        f32x4 acc = f32x4{0.f, 0.f, 0.f, 0.f};
        #pragma unroll
        for (int ks = 0; ks < 2; ks++) {
            bf16x8 a = *(const bf16x8*)(ewp + (((long long)ft * 2 + ks) * 64 + l) * 8);
            acc = __builtin_amdgcn_mfma_f32_16x16x32_bf16(a, bfr[ks], acc, 0, 0, 0);
        }
        int f0 = ft * 16 + q4;
        float4 bv = *(const float4*)&eb[f0];
        uint2 o;
        o.x = packbf(acc[0] + bv.x, acc[1] + bv.y);
        o.y = packbf(acc[2] + bv.z, acc[3] + bv.w);
        *(uint2*)&Hs[rl * 68 + f0] = o;
    }
    __syncthreads();

    // ---- row-sliced epilogue: 2 passes, thread owns 8 contiguous feats of one edge ----
    float s[8], q[8];
    #pragma unroll
    for (int j = 0; j < 8; j++) { s[j] = 0.f; q[j] = 0.f; }
    #pragma unroll
    for (int p = 0; p < 2; p++) {
        int rr = p ? rr1 : rr0;
        uint4 g3 = p ? g3b : g3a;
        uint4 g4 = p ? g4b : g4a;
        unsigned u3[4] = {g3.x, g3.y, g3.z, g3.w};
        unsigned u4[4] = {g4.x, g4.y, g4.z, g4.w};
        uint4 hu = *(uint4*)&Hs[rr * 68 + c8];
        unsigned uh[4] = {hu.x, hu.y, hu.z, hu.w};
        float h[8];
        #pragma unroll
        for (int j = 0; j < 4; j++) {
            float h0 = bflo(uh[j]) + bflo(u3[j]) + bflo(u4[j]);
            float h1 = bfhi(uh[j]) + bfhi(u3[j]) + bfhi(u4[j]);
            h[2*j] = h0; h[2*j+1] = h1;
            s[2*j] += h0; s[2*j+1] += h1;
            q[2*j] += h0 * h0; q[2*j+1] += h1 * h1;
        }
        uint4 hv;
        hv.x = packbf(h[0], h[1]); hv.y = packbf(h[2], h[3]);
        hv.z = packbf(h[4], h[5]); hv.w = packbf(h[6], h[7]);
        *(uint4*)&h_e[(row0 + rr) * 64 + c8] = hv;
    }
    // reduce stats over the wave's 16 rows (lane bits 3-5)
    #pragma unroll
    for (int d = 8; d < 64; d <<= 1) {
        #pragma unroll
        for (int j = 0; j < 8; j++) {
            s[j] += __shfl_xor(s[j], d);
            q[j] += __shfl_xor(q[j], d);
        }
    }
    if ((l >> 3) == 0) {
        #pragma unroll
        for (int j = 0; j < 8; j++) {
            sredS[wv][(l & 7) * 8 + j] = s[j];
            sredQ[wv][(l & 7) * 8 + j] = q[j];
        }
    }
    __syncthreads();
    if (tid < 128) {
        int which = tid >> 6, f = tid & 63;
        float v = which ? (sredQ[0][f] + sredQ[1][f] + sredQ[2][f] + sredQ[3][f])
                        : (sredS[0][f] + sredS[1][f] + sredS[2][f] + sredS[3][f]);
        atomicAdd(&estats[(blockIdx.x & 7) * 128 + which * 64 + f], v);
    }
}

// ---------- node finish: h = x1 + mean_j(sigmoid(w_csr[j])*x2[src_csr[j]]); node stats ----------
// FINAL: additionally writes out_w[eidx[j]] = w_csr[j] + silu(h_e[j]*km+ka) (fp32).
template <bool FINAL>
__global__ __launch_bounds__(256)
void node_finish_kernel(const __hip_bfloat16* __restrict__ w_csr, const int* __restrict__ srcc,
                        const __hip_bfloat16* __restrict__ x2, const __hip_bfloat16* __restrict__ x1,
                        const int* __restrict__ off, float* __restrict__ h_v,
                        float* __restrict__ nstats,
                        const __hip_bfloat16* __restrict__ h_e, const int* __restrict__ eidx,
                        float* __restrict__ out_w, const float* __restrict__ fin,
                        int Nn, int E) {
    __shared__ float red[8 * 66];
    __shared__ float km[64], ka[64];
    int tid = threadIdx.x;
    if (FINAL) {
        if (tid < 64) { km[tid] = fin[128 + tid]; ka[tid] = fin[192 + tid]; }
        __syncthreads();
    }
    int hw = tid >> 5, k = tid & 31;
    int n = blockIdx.x * 8 + hw;
    float h0 = 0.f, h1 = 0.f;
    if (n < Nn) {
        int o0 = off[n], o1 = off[n + 1];
        float a0 = 0.f, a1 = 0.f;
        int j = o0;
        for (; j + 1 < o1; j += 2) {   // 2 independent load chains in flight
            int s0 = srcc[j], s1 = srcc[j + 1];
            unsigned wu0 = *(const unsigned*)&w_csr[(long long)j * 64 + 2 * k];
            unsigned wu1 = *(const unsigned*)&w_csr[(long long)(j + 1) * 64 + 2 * k];
            unsigned xu0 = *(const unsigned*)&x2[(long long)s0 * 64 + 2 * k];
            unsigned xu1 = *(const unsigned*)&x2[(long long)s1 * 64 + 2 * k];
            a0 += bflo(xu0) / (1.f + __expf(-bflo(wu0)))
                + bflo(xu1) / (1.f + __expf(-bflo(wu1)));
            a1 += bfhi(xu0) / (1.f + __expf(-bfhi(wu0)))
                + bfhi(xu1) / (1.f + __expf(-bfhi(wu1)));
        }
        if (j < o1) {
            int s0 = srcc[j];
            unsigned wu0 = *(const unsigned*)&w_csr[(long long)j * 64 + 2 * k];
            unsigned xu0 = *(const unsigned*)&x2[(long long)s0 * 64 + 2 * k];
            a0 += bflo(xu0) / (1.f + __expf(-bflo(wu0)));
            a1 += bfhi(xu0) / (1.f + __expf(-bfhi(wu0)));
        }
        float ic = 1.f / fmaxf((float)(o1 - o0), 1.f);
        unsigned xu = *(const unsigned*)&x1[(long long)n * 64 + 2 * k];
        h0 = bflo(xu) + a0 * ic;
        h1 = bfhi(xu) + a1 * ic;
        *(float2*)&h_v[(long long)n * 64 + 2 * k] = make_float2(h0, h1);
    }
    red[hw * 66 + 2 * k] = h0;
    red[hw * 66 + 2 * k + 1] = h1;
    __syncthreads();
    float* nst = nstats + (blockIdx.x & 7) * 128;
    if (tid < 64) {
        float s = 0.f;
        #pragma unroll
        for (int r = 0; r < 8; r++) s += red[r * 66 + tid];
        atomicAdd(&nst[tid], s);
    }
    __syncthreads();
    red[hw * 66 + 2 * k] = h0 * h0;
    red[hw * 66 + 2 * k + 1] = h1 * h1;
    __syncthreads();
    if (tid < 64) {
        float s = 0.f;
        #pragma unroll
        for (int r = 0; r < 8; r++) s += red[r * 66 + tid];
        atomicAdd(&nst[64 + tid], s);
    }
    if (FINAL) {
        // grid-stride final edge update: full 256B fp32 row per 32 lanes
        long long total = (long long)E * 32;
        for (long long u = (long long)blockIdx.x * 256 + tid; u < total;
             u += (long long)gridDim.x * 256) {
            long long row = u >> 5;
            int kk = (int)(u & 31);
            unsigned wu = *(const unsigned*)&w_csr[row * 64 + 2 * kk];
            unsigned hu = *(const unsigned*)&h_e[row * 64 + 2 * kk];
            int e = eidx[row];
            float o0 = bflo(wu) + silu(bflo(hu) * km[2 * kk]     + ka[2 * kk]);
            float o1 = bfhi(wu) + silu(bfhi(hu) * km[2 * kk + 1] + ka[2 * kk + 1]);
            *(float2*)&out_w[(long long)e * 64 + 2 * kk] = make_float2(o0, o1);
        }
    }
}

// ---------- finalize edge part: estats -> fin[128..256] ----------
__global__ void finalize_edge_kernel(const float* __restrict__ estats,
                                     const float* __restrict__ es, const float* __restrict__ eb,
                                     float* __restrict__ fin, float invE) {
    int c = threadIdx.x;   // 64
    float s = 0.f, q = 0.f;
    #pragma unroll
    for (int r = 0; r < 8; r++) { s += estats[r * 128 + c]; q += estats[r * 128 + 64 + c]; }
    float mean = s * invE;
    float var = q * invE - mean * mean;
    float kmul = rsqrtf(var + 1e-5f) * es[c];
    fin[128 + c] = kmul;
    fin[192 + c] = eb[c] - mean * kmul;
}

// ---------- finalize node part: nstats -> fin[0..128] ----------
__global__ void finalize_node_kernel(const float* __restrict__ nstats,
                                     const float* __restrict__ vs, const float* __restrict__ vb,
                                     float* __restrict__ fin, float invN) {
    int c = threadIdx.x;   // 64
    float s = 0.f, q = 0.f;
    #pragma unroll
    for (int r = 0; r < 8; r++) { s += nstats[r * 128 + c]; q += nstats[r * 128 + 64 + c]; }
    float mean = s * invN;
    float var = q * invN - mean * mean;
    float kmul = rsqrtf(var + 1e-5f) * vs[c];
    fin[c] = kmul;
    fin[64 + c] = vb[c] - mean * kmul;
}

// ---------- node BN apply ----------
__global__ __launch_bounds__(256)
void node_apply_kernel(const float4* __restrict__ hv4, const float4* __restrict__ xold4,
                       float4* __restrict__ out4, const float* __restrict__ fin, int total) {
    __shared__ float km[64], ka[64];
    if (threadIdx.x < 64) { km[threadIdx.x] = fin[threadIdx.x]; ka[threadIdx.x] = fin[64 + threadIdx.x]; }
    __syncthreads();
    int idx = blockIdx.x * 256 + threadIdx.x;
    if (idx >= total) return;
    int c0 = (idx & 15) * 4;
    float4 h = hv4[idx], xo = xold4[idx];
    float4 m = *(float4*)&km[c0], a = *(float4*)&ka[c0];
    float g0 = h.x * m.x + a.x, g1 = h.y * m.y + a.y, g2 = h.z * m.z + a.z, g3 = h.w * m.w + a.w;
    out4[idx] = make_float4(xo.x + silu(g0), xo.y + silu(g1),
                            xo.z + silu(g2), xo.w + silu(g3));
}

// ---------- launch ----------
extern "C" void kernel_launch(void* const* d_in, const int* in_sizes, int n_in,
                              void* d_out, int out_size, void* d_ws, size_t ws_size,
                              hipStream_t stream) {
    const float* x_in  = (const float*)d_in[0];
    const float* ea_in = (const float*)d_in[1];
    const int*   ei    = (const int*)d_in[2];
    const float* v_w   = (const float*)d_in[3];
    const float* v_b   = (const float*)d_in[4];
    const float* e_w   = (const float*)d_in[5];
    const float* e_b   = (const float*)d_in[6];
    const float* vbn_s = (const float*)d_in[7];
    const float* vbn_b = (const float*)d_in[8];
    const float* ebn_s = (const float*)d_in[9];
    const float* ebn_b = (const float*)d_in[10];

    const int Nn = in_sizes[0] / 64;
    const int E  = in_sizes[1] / 64;
    const int L  = in_sizes[3] / (4 * 64 * 64);

    const int* dst = ei;
    const int* src = ei + E;

    // workspace layout
    float* h_v    = (float*)d_ws;                       // [Nn][64] fp32
    float* nstats = h_v + (long long)Nn * 64;           // [L][8][128]
    float* estats = nstats + (long long)L * 1024;       // [L][8][128]
    float* fin    = estats + (long long)L * 1024;       // [4][64]
    __hip_bfloat16* xp    = (__hip_bfloat16*)(fin + 256);       // [4][Nn][64]
    __hip_bfloat16* h_e   = xp + (long long)4 * Nn * 64;        // [E][64] CSR order
    __hip_bfloat16* w_csr = h_e + (long long)E * 64;            // [E][64] CSR order
    short* vwp = (short*)(w_csr + (long long)E * 64);   // [L][4][4][2][64][8]
    short* ewp = vwp + (long long)L * 16384;            // [L][4][2][64][8]
    int* cnt  = (int*)(ewp + (long long)L * 4096);      // [Nn]
    int* off  = cnt + Nn;                               // [Nn+1]
    int* eidx = off + Nn + 1;                           // [E]
    int* dstc = eidx + E;                               // [E]
    int* srcc = dstc + E;                               // [E]
    int* bsum = srcc + E;                               // [64]

    size_t needed = ((size_t)Nn * 64 + (size_t)L * 2048 + 256) * 4 +
                    ((size_t)4 * Nn * 64 + (size_t)2 * E * 64 + (size_t)L * 20480) * 2 +
                    ((size_t)2 * Nn + 1 + (size_t)3 * E + 64) * 4;
    if (ws_size < needed) return;

    float* out_x = (float*)d_out;
    float* out_w = out_x + (long long)Nn * 64;

    // CSR build + zero stats + pack weights (once per call)
    const int nb = (Nn + 1023) / 1024;
    zero_int_kernel<<<64, 256, 0, stream>>>(cnt, Nn);
    zero_int_kernel<<<8, 256, 0, stream>>>((int*)nstats, L * 2048);
    count_kernel<<<(E + 255) / 256, 256, 0, stream>>>(dst, cnt, E);
    scan_block_kernel<<<nb, 1024, 0, stream>>>(cnt, off, bsum, Nn);
    scan_tops_kernel<<<1, 64, 0, stream>>>(bsum, nb);
    scan_add_kernel<<<nb, 1024, 0, stream>>>(off, bsum, Nn);
    fill_csr_kernel<<<(E + 255) / 256, 256, 0, stream>>>(dst, src, off, cnt, eidx, dstc, srcc, E);
    pack_kernel<<<(L * 2560 + 255) / 256, 256, 0, stream>>>(v_w, e_w, vwp, ewp, L);

    const __hip_bfloat16* x1 = xp;
    const __hip_bfloat16* x2 = xp + (long long)Nn * 64;
    const __hip_bfloat16* x3 = xp + (long long)2 * Nn * 64;
    const __hip_bfloat16* x4 = xp + (long long)3 * Nn * 64;

    for (int l = 0; l < L; l++) {
        const float* xl = (l == 0) ? x_in : out_x;
        bool last = (l == L - 1);
        float* nst = nstats + (long long)l * 1024;
        float* est = estats + (long long)l * 1024;

        // node projections -> xp[4]
        node_gemm_mfma<<<(Nn + 63) / 64, 256, 0, stream>>>(
            xl, vwp + (long long)l * 16384, v_b + l * 256, xp, Nn);

        // edge GEMM (CSR, block-staged) + fused w-update + h_e + edge stats
        if (l == 0)
            edge_gemm_mfma<0><<<E / 64, 256, 0, stream>>>(
                ea_in, eidx, w_csr, h_e, fin, ewp + (long long)l * 4096, e_b + l * 64,
                x3, x4, dstc, srcc, est);
        else
            edge_gemm_mfma<1><<<E / 64, 256, 0, stream>>>(
                ea_in, eidx, w_csr, h_e, fin, ewp + (long long)l * 4096, e_b + l * 64,
                x3, x4, dstc, srcc, est);

        // fold edge BN affine (needs only estats) -> fin[128..256]
        finalize_edge_kernel<<<1, 64, 0, stream>>>(
            est, ebn_s + l * 64, ebn_b + l * 64, fin, 1.f / (float)E);

        // h_v = x1 + mean(sigmoid(w_csr)*x2[src_csr]); node stats; FINAL: out_w
        if (last)
            node_finish_kernel<true><<<(Nn + 7) / 8, 256, 0, stream>>>(
                w_csr, srcc, x2, x1, off, h_v, nst, h_e, eidx, out_w, fin, Nn, E);
        else
            node_finish_kernel<false><<<(Nn + 7) / 8, 256, 0, stream>>>(
                w_csr, srcc, x2, x1, off, h_v, nst, h_e, eidx, out_w, fin, Nn, E);

        // fold node BN affine -> fin[0..128]
        finalize_node_kernel<<<1, 64, 0, stream>>>(
            nst, vbn_s + l * 64, vbn_b + l * 64, fin, 1.f / (float)Nn);

        node_apply_kernel<<<(Nn * 16 + 255) / 256, 256, 0, stream>>>(
            (const float4*)h_v, (const float4*)xl, (float4*)out_x, fin, Nn * 16);
    }
}

// Round 11
// 698.088 us; speedup vs baseline: 7.0710x; 1.0285x over previous
//
#include <hip/hip_runtime.h>
#include <hip/hip_bf16.h>
#include <math.h>

typedef __attribute__((ext_vector_type(8))) short bf16x8;
typedef __attribute__((ext_vector_type(4))) float f32x4;

// ---------- bf16 helpers ----------
__device__ __forceinline__ float bflo(unsigned u) { return __uint_as_float(u << 16); }
__device__ __forceinline__ float bfhi(unsigned u) { return __uint_as_float(u & 0xffff0000u); }
__device__ __forceinline__ unsigned packbf(float a, float b) {
    unsigned ua = __float_as_uint(a), ub = __float_as_uint(b);
    ua += 0x7fffu + ((ua >> 16) & 1u);
    ub += 0x7fffu + ((ub >> 16) & 1u);
    return (ua >> 16) | (ub & 0xffff0000u);
}
__device__ __forceinline__ float silu(float g) { return g / (1.f + __expf(-g)); }

// ---------- setup ----------
__global__ void zero_int_kernel(int* __restrict__ p, int n) {
    int i = blockIdx.x * blockDim.x + threadIdx.x;
    int s = gridDim.x * blockDim.x;
    for (; i < n; i += s) p[i] = 0;
}

__global__ void count_kernel(const int* __restrict__ dst, int* __restrict__ cnt, int E) {
    int e = blockIdx.x * blockDim.x + threadIdx.x;
    if (e < E) atomicAdd(&cnt[dst[e]], 1);
}

// 3-phase scan
__global__ __launch_bounds__(1024)
void scan_block_kernel(const int* __restrict__ cnt, int* __restrict__ off,
                       int* __restrict__ bsum, int n) {
    __shared__ int wsum[16];
    int tid = threadIdx.x, lane = tid & 63, wid = tid >> 6;
    int i = blockIdx.x * 1024 + tid;
    int v = (i < n) ? cnt[i] : 0;
    int sc = v;
    #pragma unroll
    for (int s = 1; s < 64; s <<= 1) {
        int t = __shfl_up(sc, (unsigned)s, 64);
        if (lane >= s) sc += t;
    }
    if (lane == 63) wsum[wid] = sc;
    __syncthreads();
    int woff = 0;
    for (int k = 0; k < wid; k++) woff += wsum[k];
    if (i < n) off[i + 1] = woff + sc;
    if (tid == 0) {
        int t = 0;
        #pragma unroll
        for (int k = 0; k < 16; k++) t += wsum[k];
        bsum[blockIdx.x] = t;
    }
}

__global__ void scan_tops_kernel(int* __restrict__ bsum, int nb) {
    int lane = threadIdx.x;
    int v = (lane < nb) ? bsum[lane] : 0;
    int sc = v;
    #pragma unroll
    for (int s = 1; s < 64; s <<= 1) {
        int t = __shfl_up(sc, (unsigned)s, 64);
        if (lane >= s) sc += t;
    }
    if (lane < nb) bsum[lane] = sc - v;
}

__global__ __launch_bounds__(1024)
void scan_add_kernel(int* __restrict__ off, const int* __restrict__ bsum, int n) {
    int i = blockIdx.x * 1024 + threadIdx.x;
    int b = bsum[blockIdx.x];
    if (i < n) off[i + 1] += b;
    if (i == 0) off[0] = 0;
}

__global__ void fill_csr_kernel(const int* __restrict__ dst, const int* __restrict__ src,
                                const int* __restrict__ off, int* __restrict__ cnt,
                                int* __restrict__ eidx, int* __restrict__ dstc,
                                int* __restrict__ srcc, int E) {
    int e = blockIdx.x * blockDim.x + threadIdx.x;
    if (e < E) {
        int d = dst[e];
        int pos = atomicSub(&cnt[d], 1) - 1;
        int slot = off[d] + pos;
        eidx[slot] = e;
        dstc[slot] = d;
        srcc[slot] = src[e];
    }
}

// ---------- pack weights into MFMA A-operand fragments (W^T, bf16) ----------
__global__ void pack_kernel(const float* __restrict__ v_w, const float* __restrict__ e_w,
                            short* __restrict__ vwp, short* __restrict__ ewp, int L) {
    int t = blockIdx.x * blockDim.x + threadIdx.x;
    if (t >= L * 5 * 4 * 2 * 64) return;
    int lane = t & 63;
    int ks = (t >> 6) & 1;
    int ft = (t >> 7) & 3;
    int mat = t >> 9;
    int layer = mat / 5, mi = mat % 5;
    const float* W = (mi < 4) ? (v_w + (long long)(layer * 4 + mi) * 4096)
                              : (e_w + (long long)layer * 4096);
    int m = ft * 16 + (lane & 15);
    int k0 = ks * 32 + (lane >> 4) * 8;
    short* dstp = (mi < 4)
        ? vwp + ((((long long)(layer * 4 + mi) * 4 + ft) * 2 + ks) * 64 + lane) * 8
        : ewp + ((((long long)layer * 4 + ft) * 2 + ks) * 64 + lane) * 8;
    #pragma unroll
    for (int j = 0; j < 8; j++) {
        unsigned u = __float_as_uint(W[(k0 + j) * 64 + m]);
        u += 0x7fffu + ((u >> 16) & 1u);
        dstp[j] = (short)(u >> 16);
    }
}

// ---------- node GEMM (MFMA): xp[g][n][f] = bf16(x@v_w[g] + v_b[g]), LDS epilogue ----------
__global__ __launch_bounds__(256)
void node_gemm_mfma(const float* __restrict__ X, const short* __restrict__ vwp,
                    const float* __restrict__ vb, __hip_bfloat16* __restrict__ xp,
                    int Nn) {
    __shared__ short Xs[64 * 64];
    __shared__ short Hs[4][64 * 64];
    int tid = threadIdx.x;
    long long row0 = (long long)blockIdx.x * 64;

    {
        int r = tid >> 2, cq = tid & 3;
        long long row = row0 + r;
        float4 v0 = {0,0,0,0}, v1 = {0,0,0,0}, v2 = {0,0,0,0}, v3 = {0,0,0,0};
        if (row < Nn) {
            const float* sp = X + row * 64 + cq * 16;
            v0 = *(const float4*)(sp);     v1 = *(const float4*)(sp + 4);
            v2 = *(const float4*)(sp + 8); v3 = *(const float4*)(sp + 12);
        }
        uint4 w0, w1;
        w0.x = packbf(v0.x, v0.y); w0.y = packbf(v0.z, v0.w);
        w0.z = packbf(v1.x, v1.y); w0.w = packbf(v1.z, v1.w);
        w1.x = packbf(v2.x, v2.y); w1.y = packbf(v2.z, v2.w);
        w1.z = packbf(v3.x, v3.y); w1.w = packbf(v3.z, v3.w);
        int base = r * 128 + cq * 32, swz = (r & 7) << 4;
        *(uint4*)((char*)Xs + (base ^ swz)) = w0;
        *(uint4*)((char*)Xs + ((base + 16) ^ swz)) = w1;
    }
    __syncthreads();

    int l = tid & 63, wv = tid >> 6;
    int rl = wv * 16 + (l & 15);
    bf16x8 bfr[2];
    #pragma unroll
    for (int ks = 0; ks < 2; ks++) {
        int off = (rl * 128 + ks * 64 + (l >> 4) * 16) ^ ((rl & 7) << 4);
        bfr[ks] = *(bf16x8*)((char*)Xs + off);
    }
    int q4 = (l >> 4) * 4;
    for (int g = 0; g < 4; g++) {
        #pragma unroll
        for (int ft = 0; ft < 4; ft++) {
            f32x4 acc = f32x4{0.f, 0.f, 0.f, 0.f};
            #pragma unroll
            for (int ks = 0; ks < 2; ks++) {
                bf16x8 a = *(const bf16x8*)(vwp + (((long long)(g * 4 + ft) * 2 + ks) * 64 + l) * 8);
                acc = __builtin_amdgcn_mfma_f32_16x16x32_bf16(a, bfr[ks], acc, 0, 0, 0);
            }
            int f0 = ft * 16 + q4;
            float4 bv = *(const float4*)&vb[g * 64 + f0];
            uint2 o;
            o.x = packbf(acc[0] + bv.x, acc[1] + bv.y);
            o.y = packbf(acc[2] + bv.z, acc[3] + bv.w);
            int hoff = (rl * 128 + f0 * 2) ^ ((rl & 7) << 4);
            *(uint2*)((char*)Hs[g] + hoff) = o;
        }
    }
    __syncthreads();
    int r = tid >> 2, cc = (tid & 3) * 16;
    long long node = row0 + r;
    if (node < Nn) {
        int swz = (r & 7) << 4;
        #pragma unroll
        for (int g = 0; g < 4; g++) {
            uint4 a = *(uint4*)((char*)Hs[g] + ((r * 128 + cc * 2) ^ swz));
            uint4 b = *(uint4*)((char*)Hs[g] + ((r * 128 + cc * 2 + 16) ^ swz));
            __hip_bfloat16* op = xp + ((long long)g * Nn + node) * 64 + cc;
            *(uint4*)op = a;
            *(uint4*)(op + 8) = b;
        }
    }
}

// ---------- edge GEMM (MFMA), CSR state, h_e RECOMPUTE scheme ----------
// FIRST: w(0) = bf16(ea_in[eidx]); no prev recompute.
// !FIRST: stage w_csr(l-1); recompute h(l-1) via MFMA(ewp_p) + prev gathers
//         (bit-identical to the h the stats were computed on); update
//         w(l) = w(l-1) + silu(h*km+ka) in-place in Ws + write w_csr.
// Always: MFMA(ewp) -> stats; h_e written to HBM ONLY if LAST.
template <bool FIRST, bool LAST>
__global__ __launch_bounds__(256)
void edge_gemm_mfma(const float* __restrict__ ea, const int* __restrict__ eidx,
                    __hip_bfloat16* __restrict__ w_csr, __hip_bfloat16* __restrict__ h_e,
                    const float* __restrict__ fin,
                    const short* __restrict__ ewp_p, const float* __restrict__ eb_p,
                    const short* __restrict__ ewp, const float* __restrict__ eb,
                    const __hip_bfloat16* __restrict__ x3p, const __hip_bfloat16* __restrict__ x4p,
                    const __hip_bfloat16* __restrict__ x3, const __hip_bfloat16* __restrict__ x4,
                    const int* __restrict__ dstc, const int* __restrict__ srcc,
                    float* __restrict__ estats) {
    __shared__ short Ws[64 * 64];            // 8 KB w tile (prev, then updated in-place)
    __shared__ short Hs[64 * 68];            // 8.5 KB bf16 acc+bias
    __shared__ float sredS[4][64], sredQ[4][64];
    __shared__ int dstl[64], srcl[64];
    int tid = threadIdx.x;
    long long row0 = (long long)blockIdx.x * 64;

    // ---- stage w tile -> Ws ----
    {
        int r = tid >> 2, cq = tid & 3;
        long long grow = (row0 + r) * 64 + cq * 16;
        int base = r * 128 + cq * 32, swz = (r & 7) << 4;
        uint4 w0u, w1u;
        if (FIRST) {
            long long e0 = eidx[row0 + r];
            const float* sp = ea + e0 * 64 + cq * 16;
            float4 v0 = *(const float4*)(sp),     v1 = *(const float4*)(sp + 4);
            float4 v2 = *(const float4*)(sp + 8), v3 = *(const float4*)(sp + 12);
            w0u.x = packbf(v0.x, v0.y); w0u.y = packbf(v0.z, v0.w);
            w0u.z = packbf(v1.x, v1.y); w0u.w = packbf(v1.z, v1.w);
            w1u.x = packbf(v2.x, v2.y); w1u.y = packbf(v2.z, v2.w);
            w1u.z = packbf(v3.x, v3.y); w1u.w = packbf(v3.z, v3.w);
            *(uint4*)&w_csr[grow] = w0u;
            *(uint4*)&w_csr[grow + 8] = w1u;
        } else {
            w0u = *(const uint4*)&w_csr[grow];
            w1u = *(const uint4*)&w_csr[grow + 8];
        }
        *(uint4*)((char*)Ws + (base ^ swz)) = w0u;
        *(uint4*)((char*)Ws + ((base + 16) ^ swz)) = w1u;
        if (tid < 64) {
            dstl[tid] = dstc[row0 + tid];
            srcl[tid] = srcc[row0 + tid];
        }
    }
    __syncthreads();

    int l = tid & 63, wv = tid >> 6;
    int rl = wv * 16 + (l & 15);
    int q4 = (l >> 4) * 4;
    int rr0 = tid >> 3, rr1 = rr0 + 32;
    int c8 = (tid & 7) * 8;
    int de0 = dstl[rr0], se0 = srcl[rr0];
    int de1 = dstl[rr1], se1 = srcl[rr1];

    if (!FIRST) {
        // prev-layer gathers (for completing h_prev)
        uint4 p3a = *(const uint4*)&x3p[(long long)de0 * 64 + c8];
        uint4 p4a = *(const uint4*)&x4p[(long long)se0 * 64 + c8];
        uint4 p3b = *(const uint4*)&x3p[(long long)de1 * 64 + c8];
        uint4 p4b = *(const uint4*)&x4p[(long long)se1 * 64 + c8];

        bf16x8 bfr[2];
        #pragma unroll
        for (int ks = 0; ks < 2; ks++) {
            int off = (rl * 128 + ks * 64 + (l >> 4) * 16) ^ ((rl & 7) << 4);
            bfr[ks] = *(bf16x8*)((char*)Ws + off);
        }
        #pragma unroll
        for (int ft = 0; ft < 4; ft++) {
            f32x4 acc = f32x4{0.f, 0.f, 0.f, 0.f};
            #pragma unroll
            for (int ks = 0; ks < 2; ks++) {
                bf16x8 a = *(const bf16x8*)(ewp_p + (((long long)ft * 2 + ks) * 64 + l) * 8);
                acc = __builtin_amdgcn_mfma_f32_16x16x32_bf16(a, bfr[ks], acc, 0, 0, 0);
            }
            int f0 = ft * 16 + q4;
            float4 bv = *(const float4*)&eb_p[f0];
            uint2 o;
            o.x = packbf(acc[0] + bv.x, acc[1] + bv.y);
            o.y = packbf(acc[2] + bv.z, acc[3] + bv.w);
            *(uint2*)&Hs[rl * 68 + f0] = o;
        }
        __syncthreads();

        // row-sliced w-update: w_new = w_prev + silu(h_prev*km + ka)
        float4 km0 = *(const float4*)&fin[128 + c8], km1 = *(const float4*)&fin[128 + c8 + 4];
        float4 ka0 = *(const float4*)&fin[192 + c8], ka1 = *(const float4*)&fin[192 + c8 + 4];
        float kmv[8] = {km0.x, km0.y, km0.z, km0.w, km1.x, km1.y, km1.z, km1.w};
        float kav[8] = {ka0.x, ka0.y, ka0.z, ka0.w, ka1.x, ka1.y, ka1.z, ka1.w};
        #pragma unroll
        for (int p = 0; p < 2; p++) {
            int rr = p ? rr1 : rr0;
            uint4 p3 = p ? p3b : p3a;
            uint4 p4 = p ? p4b : p4a;
            unsigned u3[4] = {p3.x, p3.y, p3.z, p3.w};
            unsigned u4[4] = {p4.x, p4.y, p4.z, p4.w};
            uint4 hu = *(uint4*)&Hs[rr * 68 + c8];
            unsigned uh[4] = {hu.x, hu.y, hu.z, hu.w};
            int woff = (rr * 128 + c8 * 2) ^ ((rr & 7) << 4);
            uint4 wu = *(uint4*)((char*)Ws + woff);
            unsigned uw[4] = {wu.x, wu.y, wu.z, wu.w};
            float wn[8];
            #pragma unroll
            for (int j = 0; j < 4; j++) {
                float h0 = bflo(uh[j]) + bflo(u3[j]) + bflo(u4[j]);
                float h1 = bfhi(uh[j]) + bfhi(u3[j]) + bfhi(u4[j]);
                wn[2*j]   = bflo(uw[j]) + silu(h0 * kmv[2*j]   + kav[2*j]);
                wn[2*j+1] = bfhi(uw[j]) + silu(h1 * kmv[2*j+1] + kav[2*j+1]);
            }
            uint4 wo;
            wo.x = packbf(wn[0], wn[1]); wo.y = packbf(wn[2], wn[3]);
            wo.z = packbf(wn[4], wn[5]); wo.w = packbf(wn[6], wn[7]);
            *(uint4*)((char*)Ws + woff) = wo;                       // in-place (this (rr,c8) owned by this thread)
            *(uint4*)&w_csr[(row0 + rr) * 64 + c8] = wo;            // materialize w(l)
        }
        __syncthreads();
    }

    // ---- current layer: gathers + fragment loads + MFMA ----
    uint4 g3a = *(const uint4*)&x3[(long long)de0 * 64 + c8];
    uint4 g4a = *(const uint4*)&x4[(long long)se0 * 64 + c8];
    uint4 g3b = *(const uint4*)&x3[(long long)de1 * 64 + c8];
    uint4 g4b = *(const uint4*)&x4[(long long)se1 * 64 + c8];
    bf16x8 bfr[2];
    #pragma unroll
    for (int ks = 0; ks < 2; ks++) {
        int off = (rl * 128 + ks * 64 + (l >> 4) * 16) ^ ((rl & 7) << 4);
        bfr[ks] = *(bf16x8*)((char*)Ws + off);
    }
    #pragma unroll
    for (int ft = 0; ft < 4; ft++) {
        f32x4 acc = f32x4{0.f, 0.f, 0.f, 0.f};
        #pragma unroll
        for (int ks = 0; ks < 2; ks++) {
            bf16x8 a = *(const bf16x8*)(ewp + (((long long)ft * 2 + ks) * 64 + l) * 8);
            acc = __builtin_amdgcn_mfma_f32_16x16x32_bf16(a, bfr[ks], acc, 0, 0, 0);
        }
        int f0 = ft * 16 + q4;
        float4 bv = *(const float4*)&eb[f0];
        uint2 o;
        o.x = packbf(acc[0] + bv.x, acc[1] + bv.y);
        o.y = packbf(acc[2] + bv.z, acc[3] + bv.w);
        *(uint2*)&Hs[rl * 68 + f0] = o;
    }
    __syncthreads();

    // ---- row-sliced epilogue: stats (+ h_e write if LAST) ----
    float s[8], q[8];
    #pragma unroll
    for (int j = 0; j < 8; j++) { s[j] = 0.f; q[j] = 0.f; }
    #pragma unroll
    for (int p = 0; p < 2; p++) {
        int rr = p ? rr1 : rr0;
        uint4 g3 = p ? g3b : g3a;
        uint4 g4 = p ? g4b : g4a;
        unsigned u3[4] = {g3.x, g3.y, g3.z, g3.w};
        unsigned u4[4] = {g4.x, g4.y, g4.z, g4.w};
        uint4 hu = *(uint4*)&Hs[rr * 68 + c8];
        unsigned uh[4] = {hu.x, hu.y, hu.z, hu.w};
        float h[8];
        #pragma unroll
        for (int j = 0; j < 4; j++) {
            float h0 = bflo(uh[j]) + bflo(u3[j]) + bflo(u4[j]);
            float h1 = bfhi(uh[j]) + bfhi(u3[j]) + bfhi(u4[j]);
            h[2*j] = h0; h[2*j+1] = h1;
            s[2*j] += h0; s[2*j+1] += h1;
            q[2*j] += h0 * h0; q[2*j+1] += h1 * h1;
        }
        if (LAST) {
            uint4 hv;
            hv.x = packbf(h[0], h[1]); hv.y = packbf(h[2], h[3]);
            hv.z = packbf(h[4], h[5]); hv.w = packbf(h[6], h[7]);
            *(uint4*)&h_e[(row0 + rr) * 64 + c8] = hv;
        }
    }
    #pragma unroll
    for (int d = 8; d < 64; d <<= 1) {
        #pragma unroll
        for (int j = 0; j < 8; j++) {
            s[j] += __shfl_xor(s[j], d);
            q[j] += __shfl_xor(q[j], d);
        }
    }
    if ((l >> 3) == 0) {
        #pragma unroll
        for (int j = 0; j < 8; j++) {
            sredS[wv][(l & 7) * 8 + j] = s[j];
            sredQ[wv][(l & 7) * 8 + j] = q[j];
        }
    }
    __syncthreads();
    if (tid < 128) {
        int which = tid >> 6, f = tid & 63;
        float v = which ? (sredQ[0][f] + sredQ[1][f] + sredQ[2][f] + sredQ[3][f])
                        : (sredS[0][f] + sredS[1][f] + sredS[2][f] + sredS[3][f]);
        atomicAdd(&estats[(blockIdx.x & 7) * 128 + which * 64 + f], v);
    }
}

// ---------- node finish: aggregation + node stats; FINAL also emits out_w in-loop ----------
template <bool FINAL>
__global__ __launch_bounds__(256)
void node_finish_kernel(const __hip_bfloat16* __restrict__ w_csr, const int* __restrict__ srcc,
                        const __hip_bfloat16* __restrict__ x2, const __hip_bfloat16* __restrict__ x1,
                        const int* __restrict__ off, float* __restrict__ h_v,
                        float* __restrict__ nstats,
                        const __hip_bfloat16* __restrict__ h_e, const int* __restrict__ eidx,
                        float* __restrict__ out_w, const float* __restrict__ fin, int Nn) {
    __shared__ float red[8 * 66];
    __shared__ float km[64], ka[64];
    int tid = threadIdx.x;
    if (FINAL) {
        if (tid < 64) { km[tid] = fin[128 + tid]; ka[tid] = fin[192 + tid]; }
        __syncthreads();
    }
    int hw = tid >> 5, k = tid & 31;
    int n = blockIdx.x * 8 + hw;
    float h0 = 0.f, h1 = 0.f;
    if (n < Nn) {
        int o0 = off[n], o1 = off[n + 1];
        float a0 = 0.f, a1 = 0.f;
        int j = o0;
        for (; j + 1 < o1; j += 2) {
            int s0 = srcc[j], s1 = srcc[j + 1];
            unsigned wu0 = *(const unsigned*)&w_csr[(long long)j * 64 + 2 * k];
            unsigned wu1 = *(const unsigned*)&w_csr[(long long)(j + 1) * 64 + 2 * k];
            unsigned xu0 = *(const unsigned*)&x2[(long long)s0 * 64 + 2 * k];
            unsigned xu1 = *(const unsigned*)&x2[(long long)s1 * 64 + 2 * k];
            a0 += bflo(xu0) / (1.f + __expf(-bflo(wu0)))
                + bflo(xu1) / (1.f + __expf(-bflo(wu1)));
            a1 += bfhi(xu0) / (1.f + __expf(-bfhi(wu0)))
                + bfhi(xu1) / (1.f + __expf(-bfhi(wu1)));
            if (FINAL) {
                unsigned hu0 = *(const unsigned*)&h_e[(long long)j * 64 + 2 * k];
                unsigned hu1 = *(const unsigned*)&h_e[(long long)(j + 1) * 64 + 2 * k];
                int e0 = eidx[j], e1 = eidx[j + 1];
                float o00 = bflo(wu0) + silu(bflo(hu0) * km[2*k]   + ka[2*k]);
                float o01 = bfhi(wu0) + silu(bfhi(hu0) * km[2*k+1] + ka[2*k+1]);
                float o10 = bflo(wu1) + silu(bflo(hu1) * km[2*k]   + ka[2*k]);
                float o11 = bfhi(wu1) + silu(bfhi(hu1) * km[2*k+1] + ka[2*k+1]);
                *(float2*)&out_w[(long long)e0 * 64 + 2 * k] = make_float2(o00, o01);
                *(float2*)&out_w[(long long)e1 * 64 + 2 * k] = make_float2(o10, o11);
            }
        }
        if (j < o1) {
            int s0 = srcc[j];
            unsigned wu0 = *(const unsigned*)&w_csr[(long long)j * 64 + 2 * k];
            unsigned xu0 = *(const unsigned*)&x2[(long long)s0 * 64 + 2 * k];
            a0 += bflo(xu0) / (1.f + __expf(-bflo(wu0)));
            a1 += bfhi(xu0) / (1.f + __expf(-bfhi(wu0)));
            if (FINAL) {
                unsigned hu0 = *(const unsigned*)&h_e[(long long)j * 64 + 2 * k];
                int e0 = eidx[j];
                float o00 = bflo(wu0) + silu(bflo(hu0) * km[2*k]   + ka[2*k]);
                float o01 = bfhi(wu0) + silu(bfhi(hu0) * km[2*k+1] + ka[2*k+1]);
                *(float2*)&out_w[(long long)e0 * 64 + 2 * k] = make_float2(o00, o01);
            }
        }
        float ic = 1.f / fmaxf((float)(o1 - o0), 1.f);
        unsigned xu = *(const unsigned*)&x1[(long long)n * 64 + 2 * k];
        h0 = bflo(xu) + a0 * ic;
        h1 = bfhi(xu) + a1 * ic;
        *(float2*)&h_v[(long long)n * 64 + 2 * k] = make_float2(h0, h1);
    }
    red[hw * 66 + 2 * k] = h0;
    red[hw * 66 + 2 * k + 1] = h1;
    __syncthreads();
    float* nst = nstats + (blockIdx.x & 7) * 128;
    if (tid < 64) {
        float s = 0.f;
        #pragma unroll
        for (int r = 0; r < 8; r++) s += red[r * 66 + tid];
        atomicAdd(&nst[tid], s);
    }
    __syncthreads();
    red[hw * 66 + 2 * k] = h0 * h0;
    red[hw * 66 + 2 * k + 1] = h1 * h1;
    __syncthreads();
    if (tid < 64) {
        float s = 0.f;
        #pragma unroll
        for (int r = 0; r < 8; r++) s += red[r * 66 + tid];
        atomicAdd(&nst[64 + tid], s);
    }
}

// ---------- finalize edge part: estats -> fin[128..256] ----------
__global__ void finalize_edge_kernel(const float* __restrict__ estats,
                                     const float* __restrict__ es, const float* __restrict__ eb,
                                     float* __restrict__ fin, float invE) {
    int c = threadIdx.x;
    float s = 0.f, q = 0.f;
    #pragma unroll
    for (int r = 0; r < 8; r++) { s += estats[r * 128 + c]; q += estats[r * 128 + 64 + c]; }
    float mean = s * invE;
    float var = q * invE - mean * mean;
    float kmul = rsqrtf(var + 1e-5f) * es[c];
    fin[128 + c] = kmul;
    fin[192 + c] = eb[c] - mean * kmul;
}

// ---------- finalize node part: nstats -> fin[0..128] ----------
__global__ void finalize_node_kernel(const float* __restrict__ nstats,
                                     const float* __restrict__ vs, const float* __restrict__ vb,
                                     float* __restrict__ fin, float invN) {
    int c = threadIdx.x;
    float s = 0.f, q = 0.f;
    #pragma unroll
    for (int r = 0; r < 8; r++) { s += nstats[r * 128 + c]; q += nstats[r * 128 + 64 + c]; }
    float mean = s * invN;
    float var = q * invN - mean * mean;
    float kmul = rsqrtf(var + 1e-5f) * vs[c];
    fin[c] = kmul;
    fin[64 + c] = vb[c] - mean * kmul;
}

// ---------- node BN apply ----------
__global__ __launch_bounds__(256)
void node_apply_kernel(const float4* __restrict__ hv4, const float4* __restrict__ xold4,
                       float4* __restrict__ out4, const float* __restrict__ fin, int total) {
    __shared__ float km[64], ka[64];
    if (threadIdx.x < 64) { km[threadIdx.x] = fin[threadIdx.x]; ka[threadIdx.x] = fin[64 + threadIdx.x]; }
    __syncthreads();
    int idx = blockIdx.x * 256 + threadIdx.x;
    if (idx >= total) return;
    int c0 = (idx & 15) * 4;
    float4 h = hv4[idx], xo = xold4[idx];
    float4 m = *(float4*)&km[c0], a = *(float4*)&ka[c0];
    float g0 = h.x * m.x + a.x, g1 = h.y * m.y + a.y, g2 = h.z * m.z + a.z, g3 = h.w * m.w + a.w;
    out4[idx] = make_float4(xo.x + silu(g0), xo.y + silu(g1),
                            xo.z + silu(g2), xo.w + silu(g3));
}

// ---------- launch ----------
extern "C" void kernel_launch(void* const* d_in, const int* in_sizes, int n_in,
                              void* d_out, int out_size, void* d_ws, size_t ws_size,
                              hipStream_t stream) {
    const float* x_in  = (const float*)d_in[0];
    const float* ea_in = (const float*)d_in[1];
    const int*   ei    = (const int*)d_in[2];
    const float* v_w   = (const float*)d_in[3];
    const float* v_b   = (const float*)d_in[4];
    const float* e_w   = (const float*)d_in[5];
    const float* e_b   = (const float*)d_in[6];
    const float* vbn_s = (const float*)d_in[7];
    const float* vbn_b = (const float*)d_in[8];
    const float* ebn_s = (const float*)d_in[9];
    const float* ebn_b = (const float*)d_in[10];

    const int Nn = in_sizes[0] / 64;
    const int E  = in_sizes[1] / 64;
    const int L  = in_sizes[3] / (4 * 64 * 64);

    const int* dst = ei;
    const int* src = ei + E;

    // workspace layout
    float* h_v    = (float*)d_ws;                       // [Nn][64] fp32
    float* nstats = h_v + (long long)Nn * 64;           // [L][8][128]
    float* estats = nstats + (long long)L * 1024;       // [L][8][128]
    float* fin    = estats + (long long)L * 1024;       // [4][64]
    __hip_bfloat16* xp0   = (__hip_bfloat16*)(fin + 256);      // [4][Nn][64]
    __hip_bfloat16* xp1   = xp0 + (long long)4 * Nn * 64;      // [4][Nn][64]
    __hip_bfloat16* h_e   = xp1 + (long long)4 * Nn * 64;      // [E][64] CSR (last layer only)
    __hip_bfloat16* w_csr = h_e + (long long)E * 64;           // [E][64] CSR
    short* vwp = (short*)(w_csr + (long long)E * 64);   // [L][4][4][2][64][8]
    short* ewp = vwp + (long long)L * 16384;            // [L][4][2][64][8]
    int* cnt  = (int*)(ewp + (long long)L * 4096);      // [Nn]
    int* off  = cnt + Nn;                               // [Nn+1]
    int* eidx = off + Nn + 1;                           // [E]
    int* dstc = eidx + E;                               // [E]
    int* srcc = dstc + E;                               // [E]
    int* bsum = srcc + E;                               // [64]

    size_t needed = ((size_t)Nn * 64 + (size_t)L * 2048 + 256) * 4 +
                    ((size_t)8 * Nn * 64 + (size_t)2 * E * 64 + (size_t)L * 20480) * 2 +
                    ((size_t)2 * Nn + 1 + (size_t)3 * E + 64) * 4;
    if (ws_size < needed) return;

    float* out_x = (float*)d_out;
    float* out_w = out_x + (long long)Nn * 64;

    // CSR build + zero stats + pack weights (once per call)
    const int nb = (Nn + 1023) / 1024;
    zero_int_kernel<<<64, 256, 0, stream>>>(cnt, Nn);
    zero_int_kernel<<<8, 256, 0, stream>>>((int*)nstats, L * 2048);
    count_kernel<<<(E + 255) / 256, 256, 0, stream>>>(dst, cnt, E);
    scan_block_kernel<<<nb, 1024, 0, stream>>>(cnt, off, bsum, Nn);
    scan_tops_kernel<<<1, 64, 0, stream>>>(bsum, nb);
    scan_add_kernel<<<nb, 1024, 0, stream>>>(off, bsum, Nn);
    fill_csr_kernel<<<(E + 255) / 256, 256, 0, stream>>>(dst, src, off, cnt, eidx, dstc, srcc, E);
    pack_kernel<<<(L * 2560 + 255) / 256, 256, 0, stream>>>(v_w, e_w, vwp, ewp, L);

    for (int l = 0; l < L; l++) {
        const float* xl = (l == 0) ? x_in : out_x;
        bool first = (l == 0);
        bool last = (l == L - 1);
        float* nst = nstats + (long long)l * 1024;
        float* est = estats + (long long)l * 1024;
        __hip_bfloat16* xp_cur  = (l & 1) ? xp1 : xp0;
        __hip_bfloat16* xp_prev = (l & 1) ? xp0 : xp1;
        const __hip_bfloat16* x1 = xp_cur;
        const __hip_bfloat16* x2 = xp_cur + (long long)Nn * 64;
        const __hip_bfloat16* x3 = xp_cur + (long long)2 * Nn * 64;
        const __hip_bfloat16* x4 = xp_cur + (long long)3 * Nn * 64;
        const __hip_bfloat16* x3p = xp_prev + (long long)2 * Nn * 64;
        const __hip_bfloat16* x4p = xp_prev + (long long)3 * Nn * 64;

        // node projections -> xp_cur
        node_gemm_mfma<<<(Nn + 63) / 64, 256, 0, stream>>>(
            xl, vwp + (long long)l * 16384, v_b + l * 256, xp_cur, Nn);

        // edge GEMM: stage w + (recompute h_prev + fused update) + stats (+ h_e if last)
        const short* ewp_c = ewp + (long long)l * 4096;
        const short* ewp_pv = (l > 0) ? ewp + (long long)(l - 1) * 4096 : ewp_c;
        const float* eb_c = e_b + l * 64;
        const float* eb_pv = (l > 0) ? e_b + (l - 1) * 64 : eb_c;
        if (first && !last)
            edge_gemm_mfma<true, false><<<E / 64, 256, 0, stream>>>(
                ea_in, eidx, w_csr, h_e, fin, ewp_pv, eb_pv, ewp_c, eb_c,
                x3p, x4p, x3, x4, dstc, srcc, est);
        else if (first && last)
            edge_gemm_mfma<true, true><<<E / 64, 256, 0, stream>>>(
                ea_in, eidx, w_csr, h_e, fin, ewp_pv, eb_pv, ewp_c, eb_c,
                x3p, x4p, x3, x4, dstc, srcc, est);
        else if (!first && !last)
            edge_gemm_mfma<false, false><<<E / 64, 256, 0, stream>>>(
                ea_in, eidx, w_csr, h_e, fin, ewp_pv, eb_pv, ewp_c, eb_c,
                x3p, x4p, x3, x4, dstc, srcc, est);
        else
            edge_gemm_mfma<false, true><<<E / 64, 256, 0, stream>>>(
                ea_in, eidx, w_csr, h_e, fin, ewp_pv, eb_pv, ewp_c, eb_c,
                x3p, x4p, x3, x4, dstc, srcc, est);

        // fold edge BN affine -> fin[128..256] (consumed by node_finish FINAL / next edge_gemm)
        finalize_edge_kernel<<<1, 64, 0, stream>>>(
            est, ebn_s + l * 64, ebn_b + l * 64, fin, 1.f / (float)E);

        // aggregation + node stats (+ out_w emission on last layer)
        if (last)
            node_finish_kernel<true><<<(Nn + 7) / 8, 256, 0, stream>>>(
                w_csr, srcc, x2, x1, off, h_v, nst, h_e, eidx, out_w, fin, Nn);
        else
            node_finish_kernel<false><<<(Nn + 7) / 8, 256, 0, stream>>>(
                w_csr, srcc, x2, x1, off, h_v, nst, h_e, eidx, out_w, fin, Nn);

        // fold node BN affine -> fin[0..128]
        finalize_node_kernel<<<1, 64, 0, stream>>>(
            nst, vbn_s + l * 64, vbn_b + l * 64, fin, 1.f / (float)Nn);

        node_apply_kernel<<<(Nn * 16 + 255) / 256, 256, 0, stream>>>(
            (const float4*)h_v, (const float4*)xl, (float4*)out_x, fin, Nn * 16);
    }
}

// Round 12
// 649.034 us; speedup vs baseline: 7.6054x; 1.0756x over previous
//
#include <hip/hip_runtime.h>
#include <hip/hip_bf16.h>
#include <math.h>

typedef __attribute__((ext_vector_type(8))) short bf16x8;
typedef __attribute__((ext_vector_type(4))) float f32x4;

// ---------- bf16 helpers ----------
__device__ __forceinline__ float bflo(unsigned u) { return __uint_as_float(u << 16); }
__device__ __forceinline__ float bfhi(unsigned u) { return __uint_as_float(u & 0xffff0000u); }
__device__ __forceinline__ unsigned packbf(float a, float b) {
    unsigned ua = __float_as_uint(a), ub = __float_as_uint(b);
    ua += 0x7fffu + ((ua >> 16) & 1u);
    ub += 0x7fffu + ((ub >> 16) & 1u);
    return (ua >> 16) | (ub & 0xffff0000u);
}
// fast sigmoid/silu: v_rcp_f32 (~1 ulp) instead of IEEE divide (10+ instrs)
__device__ __forceinline__ float fsig(float w) {
    return __builtin_amdgcn_rcpf(1.f + __expf(-w));
}
__device__ __forceinline__ float silu(float g) { return g * fsig(g); }

// ---------- setup ----------
__global__ void zero_int_kernel(int* __restrict__ p, int n) {
    int i = blockIdx.x * blockDim.x + threadIdx.x;
    int s = gridDim.x * blockDim.x;
    for (; i < n; i += s) p[i] = 0;
}

__global__ void count_kernel(const int* __restrict__ dst, int* __restrict__ cnt, int E) {
    int e = blockIdx.x * blockDim.x + threadIdx.x;
    if (e < E) atomicAdd(&cnt[dst[e]], 1);
}

// 3-phase scan
__global__ __launch_bounds__(1024)
void scan_block_kernel(const int* __restrict__ cnt, int* __restrict__ off,
                       int* __restrict__ bsum, int n) {
    __shared__ int wsum[16];
    int tid = threadIdx.x, lane = tid & 63, wid = tid >> 6;
    int i = blockIdx.x * 1024 + tid;
    int v = (i < n) ? cnt[i] : 0;
    int sc = v;
    #pragma unroll
    for (int s = 1; s < 64; s <<= 1) {
        int t = __shfl_up(sc, (unsigned)s, 64);
        if (lane >= s) sc += t;
    }
    if (lane == 63) wsum[wid] = sc;
    __syncthreads();
    int woff = 0;
    for (int k = 0; k < wid; k++) woff += wsum[k];
    if (i < n) off[i + 1] = woff + sc;
    if (tid == 0) {
        int t = 0;
        #pragma unroll
        for (int k = 0; k < 16; k++) t += wsum[k];
        bsum[blockIdx.x] = t;
    }
}

__global__ void scan_tops_kernel(int* __restrict__ bsum, int nb) {
    int lane = threadIdx.x;
    int v = (lane < nb) ? bsum[lane] : 0;
    int sc = v;
    #pragma unroll
    for (int s = 1; s < 64; s <<= 1) {
        int t = __shfl_up(sc, (unsigned)s, 64);
        if (lane >= s) sc += t;
    }
    if (lane < nb) bsum[lane] = sc - v;
}

__global__ __launch_bounds__(1024)
void scan_add_kernel(int* __restrict__ off, const int* __restrict__ bsum, int n) {
    int i = blockIdx.x * 1024 + threadIdx.x;
    int b = bsum[blockIdx.x];
    if (i < n) off[i + 1] += b;
    if (i == 0) off[0] = 0;
}

__global__ void fill_csr_kernel(const int* __restrict__ dst, const int* __restrict__ src,
                                const int* __restrict__ off, int* __restrict__ cnt,
                                int* __restrict__ eidx, int* __restrict__ dstc,
                                int* __restrict__ srcc, int E) {
    int e = blockIdx.x * blockDim.x + threadIdx.x;
    if (e < E) {
        int d = dst[e];
        int pos = atomicSub(&cnt[d], 1) - 1;
        int slot = off[d] + pos;
        eidx[slot] = e;
        dstc[slot] = d;
        srcc[slot] = src[e];
    }
}

// ---------- pack weights into MFMA A-operand fragments (W^T, bf16) ----------
__global__ void pack_kernel(const float* __restrict__ v_w, const float* __restrict__ e_w,
                            short* __restrict__ vwp, short* __restrict__ ewp, int L) {
    int t = blockIdx.x * blockDim.x + threadIdx.x;
    if (t >= L * 5 * 4 * 2 * 64) return;
    int lane = t & 63;
    int ks = (t >> 6) & 1;
    int ft = (t >> 7) & 3;
    int mat = t >> 9;
    int layer = mat / 5, mi = mat % 5;
    const float* W = (mi < 4) ? (v_w + (long long)(layer * 4 + mi) * 4096)
                              : (e_w + (long long)layer * 4096);
    int m = ft * 16 + (lane & 15);
    int k0 = ks * 32 + (lane >> 4) * 8;
    short* dstp = (mi < 4)
        ? vwp + ((((long long)(layer * 4 + mi) * 4 + ft) * 2 + ks) * 64 + lane) * 8
        : ewp + ((((long long)layer * 4 + ft) * 2 + ks) * 64 + lane) * 8;
    #pragma unroll
    for (int j = 0; j < 8; j++) {
        unsigned u = __float_as_uint(W[(k0 + j) * 64 + m]);
        u += 0x7fffu + ((u >> 16) & 1u);
        dstp[j] = (short)(u >> 16);
    }
}

// ---------- node GEMM (MFMA): xp[g][n][f] = bf16(x@v_w[g] + v_b[g]), LDS epilogue ----------
__global__ __launch_bounds__(256)
void node_gemm_mfma(const float* __restrict__ X, const short* __restrict__ vwp,
                    const float* __restrict__ vb, __hip_bfloat16* __restrict__ xp,
                    int Nn) {
    __shared__ short Xs[64 * 64];
    __shared__ short Hs[4][64 * 64];
    int tid = threadIdx.x;
    long long row0 = (long long)blockIdx.x * 64;

    {
        int r = tid >> 2, cq = tid & 3;
        long long row = row0 + r;
        float4 v0 = {0,0,0,0}, v1 = {0,0,0,0}, v2 = {0,0,0,0}, v3 = {0,0,0,0};
        if (row < Nn) {
            const float* sp = X + row * 64 + cq * 16;
            v0 = *(const float4*)(sp);     v1 = *(const float4*)(sp + 4);
            v2 = *(const float4*)(sp + 8); v3 = *(const float4*)(sp + 12);
        }
        uint4 w0, w1;
        w0.x = packbf(v0.x, v0.y); w0.y = packbf(v0.z, v0.w);
        w0.z = packbf(v1.x, v1.y); w0.w = packbf(v1.z, v1.w);
        w1.x = packbf(v2.x, v2.y); w1.y = packbf(v2.z, v2.w);
        w1.z = packbf(v3.x, v3.y); w1.w = packbf(v3.z, v3.w);
        int base = r * 128 + cq * 32, swz = (r & 7) << 4;
        *(uint4*)((char*)Xs + (base ^ swz)) = w0;
        *(uint4*)((char*)Xs + ((base + 16) ^ swz)) = w1;
    }
    __syncthreads();

    int l = tid & 63, wv = tid >> 6;
    int rl = wv * 16 + (l & 15);
    bf16x8 bfr[2];
    #pragma unroll
    for (int ks = 0; ks < 2; ks++) {
        int off = (rl * 128 + ks * 64 + (l >> 4) * 16) ^ ((rl & 7) << 4);
        bfr[ks] = *(bf16x8*)((char*)Xs + off);
    }
    int q4 = (l >> 4) * 4;
    for (int g = 0; g < 4; g++) {
        #pragma unroll
        for (int ft = 0; ft < 4; ft++) {
            f32x4 acc = f32x4{0.f, 0.f, 0.f, 0.f};
            #pragma unroll
            for (int ks = 0; ks < 2; ks++) {
                bf16x8 a = *(const bf16x8*)(vwp + (((long long)(g * 4 + ft) * 2 + ks) * 64 + l) * 8);
                acc = __builtin_amdgcn_mfma_f32_16x16x32_bf16(a, bfr[ks], acc, 0, 0, 0);
            }
            int f0 = ft * 16 + q4;
            float4 bv = *(const float4*)&vb[g * 64 + f0];
            uint2 o;
            o.x = packbf(acc[0] + bv.x, acc[1] + bv.y);
            o.y = packbf(acc[2] + bv.z, acc[3] + bv.w);
            int hoff = (rl * 128 + f0 * 2) ^ ((rl & 7) << 4);
            *(uint2*)((char*)Hs[g] + hoff) = o;
        }
    }
    __syncthreads();
    int r = tid >> 2, cc = (tid & 3) * 16;
    long long node = row0 + r;
    if (node < Nn) {
        int swz = (r & 7) << 4;
        #pragma unroll
        for (int g = 0; g < 4; g++) {
            uint4 a = *(uint4*)((char*)Hs[g] + ((r * 128 + cc * 2) ^ swz));
            uint4 b = *(uint4*)((char*)Hs[g] + ((r * 128 + cc * 2 + 16) ^ swz));
            __hip_bfloat16* op = xp + ((long long)g * Nn + node) * 64 + cc;
            *(uint4*)op = a;
            *(uint4*)(op + 8) = b;
        }
    }
}

// ---------- edge GEMM (MFMA), CSR state, h_e RECOMPUTE scheme ----------
template <bool FIRST, bool LAST>
__global__ __launch_bounds__(256)
void edge_gemm_mfma(const float* __restrict__ ea, const int* __restrict__ eidx,
                    __hip_bfloat16* __restrict__ w_csr, __hip_bfloat16* __restrict__ h_e,
                    const float* __restrict__ fin,
                    const short* __restrict__ ewp_p, const float* __restrict__ eb_p,
                    const short* __restrict__ ewp, const float* __restrict__ eb,
                    const __hip_bfloat16* __restrict__ x3p, const __hip_bfloat16* __restrict__ x4p,
                    const __hip_bfloat16* __restrict__ x3, const __hip_bfloat16* __restrict__ x4,
                    const int* __restrict__ dstc, const int* __restrict__ srcc,
                    float* __restrict__ estats) {
    __shared__ short Ws[64 * 64];
    __shared__ short Hs[64 * 68];
    __shared__ float sredS[4][64], sredQ[4][64];
    __shared__ int dstl[64], srcl[64];
    int tid = threadIdx.x;
    long long row0 = (long long)blockIdx.x * 64;

    // ---- stage w tile -> Ws ----
    {
        int r = tid >> 2, cq = tid & 3;
        long long grow = (row0 + r) * 64 + cq * 16;
        int base = r * 128 + cq * 32, swz = (r & 7) << 4;
        uint4 w0u, w1u;
        if (FIRST) {
            long long e0 = eidx[row0 + r];
            const float* sp = ea + e0 * 64 + cq * 16;
            float4 v0 = *(const float4*)(sp),     v1 = *(const float4*)(sp + 4);
            float4 v2 = *(const float4*)(sp + 8), v3 = *(const float4*)(sp + 12);
            w0u.x = packbf(v0.x, v0.y); w0u.y = packbf(v0.z, v0.w);
            w0u.z = packbf(v1.x, v1.y); w0u.w = packbf(v1.z, v1.w);
            w1u.x = packbf(v2.x, v2.y); w1u.y = packbf(v2.z, v2.w);
            w1u.z = packbf(v3.x, v3.y); w1u.w = packbf(v3.z, v3.w);
            *(uint4*)&w_csr[grow] = w0u;
            *(uint4*)&w_csr[grow + 8] = w1u;
        } else {
            w0u = *(const uint4*)&w_csr[grow];
            w1u = *(const uint4*)&w_csr[grow + 8];
        }
        *(uint4*)((char*)Ws + (base ^ swz)) = w0u;
        *(uint4*)((char*)Ws + ((base + 16) ^ swz)) = w1u;
        if (tid < 64) {
            dstl[tid] = dstc[row0 + tid];
            srcl[tid] = srcc[row0 + tid];
        }
    }
    __syncthreads();

    int l = tid & 63, wv = tid >> 6;
    int rl = wv * 16 + (l & 15);
    int q4 = (l >> 4) * 4;
    int rr0 = tid >> 3, rr1 = rr0 + 32;
    int c8 = (tid & 7) * 8;
    int de0 = dstl[rr0], se0 = srcl[rr0];
    int de1 = dstl[rr1], se1 = srcl[rr1];

    if (!FIRST) {
        uint4 p3a = *(const uint4*)&x3p[(long long)de0 * 64 + c8];
        uint4 p4a = *(const uint4*)&x4p[(long long)se0 * 64 + c8];
        uint4 p3b = *(const uint4*)&x3p[(long long)de1 * 64 + c8];
        uint4 p4b = *(const uint4*)&x4p[(long long)se1 * 64 + c8];

        bf16x8 bfr[2];
        #pragma unroll
        for (int ks = 0; ks < 2; ks++) {
            int off = (rl * 128 + ks * 64 + (l >> 4) * 16) ^ ((rl & 7) << 4);
            bfr[ks] = *(bf16x8*)((char*)Ws + off);
        }
        #pragma unroll
        for (int ft = 0; ft < 4; ft++) {
            f32x4 acc = f32x4{0.f, 0.f, 0.f, 0.f};
            #pragma unroll
            for (int ks = 0; ks < 2; ks++) {
                bf16x8 a = *(const bf16x8*)(ewp_p + (((long long)ft * 2 + ks) * 64 + l) * 8);
                acc = __builtin_amdgcn_mfma_f32_16x16x32_bf16(a, bfr[ks], acc, 0, 0, 0);
            }
            int f0 = ft * 16 + q4;
            float4 bv = *(const float4*)&eb_p[f0];
            uint2 o;
            o.x = packbf(acc[0] + bv.x, acc[1] + bv.y);
            o.y = packbf(acc[2] + bv.z, acc[3] + bv.w);
            *(uint2*)&Hs[rl * 68 + f0] = o;
        }
        __syncthreads();

        float4 km0 = *(const float4*)&fin[128 + c8], km1 = *(const float4*)&fin[128 + c8 + 4];
        float4 ka0 = *(const float4*)&fin[192 + c8], ka1 = *(const float4*)&fin[192 + c8 + 4];
        float kmv[8] = {km0.x, km0.y, km0.z, km0.w, km1.x, km1.y, km1.z, km1.w};
        float kav[8] = {ka0.x, ka0.y, ka0.z, ka0.w, ka1.x, ka1.y, ka1.z, ka1.w};
        #pragma unroll
        for (int p = 0; p < 2; p++) {
            int rr = p ? rr1 : rr0;
            uint4 p3 = p ? p3b : p3a;
            uint4 p4 = p ? p4b : p4a;
            unsigned u3[4] = {p3.x, p3.y, p3.z, p3.w};
            unsigned u4[4] = {p4.x, p4.y, p4.z, p4.w};
            uint4 hu = *(uint4*)&Hs[rr * 68 + c8];
            unsigned uh[4] = {hu.x, hu.y, hu.z, hu.w};
            int woff = (rr * 128 + c8 * 2) ^ ((rr & 7) << 4);
            uint4 wu = *(uint4*)((char*)Ws + woff);
            unsigned uw[4] = {wu.x, wu.y, wu.z, wu.w};
            float wn[8];
            #pragma unroll
            for (int j = 0; j < 4; j++) {
                float h0 = bflo(uh[j]) + bflo(u3[j]) + bflo(u4[j]);
                float h1 = bfhi(uh[j]) + bfhi(u3[j]) + bfhi(u4[j]);
                wn[2*j]   = bflo(uw[j]) + silu(h0 * kmv[2*j]   + kav[2*j]);
                wn[2*j+1] = bfhi(uw[j]) + silu(h1 * kmv[2*j+1] + kav[2*j+1]);
            }
            uint4 wo;
            wo.x = packbf(wn[0], wn[1]); wo.y = packbf(wn[2], wn[3]);
            wo.z = packbf(wn[4], wn[5]); wo.w = packbf(wn[6], wn[7]);
            *(uint4*)((char*)Ws + woff) = wo;
            *(uint4*)&w_csr[(row0 + rr) * 64 + c8] = wo;
        }
        __syncthreads();
    }

    // ---- current layer: gathers + fragment loads + MFMA ----
    uint4 g3a = *(const uint4*)&x3[(long long)de0 * 64 + c8];
    uint4 g4a = *(const uint4*)&x4[(long long)se0 * 64 + c8];
    uint4 g3b = *(const uint4*)&x3[(long long)de1 * 64 + c8];
    uint4 g4b = *(const uint4*)&x4[(long long)se1 * 64 + c8];
    bf16x8 bfr[2];
    #pragma unroll
    for (int ks = 0; ks < 2; ks++) {
        int off = (rl * 128 + ks * 64 + (l >> 4) * 16) ^ ((rl & 7) << 4);
        bfr[ks] = *(bf16x8*)((char*)Ws + off);
    }
    #pragma unroll
    for (int ft = 0; ft < 4; ft++) {
        f32x4 acc = f32x4{0.f, 0.f, 0.f, 0.f};
        #pragma unroll
        for (int ks = 0; ks < 2; ks++) {
            bf16x8 a = *(const bf16x8*)(ewp + (((long long)ft * 2 + ks) * 64 + l) * 8);
            acc = __builtin_amdgcn_mfma_f32_16x16x32_bf16(a, bfr[ks], acc, 0, 0, 0);
        }
        int f0 = ft * 16 + q4;
        float4 bv = *(const float4*)&eb[f0];
        uint2 o;
        o.x = packbf(acc[0] + bv.x, acc[1] + bv.y);
        o.y = packbf(acc[2] + bv.z, acc[3] + bv.w);
        *(uint2*)&Hs[rl * 68 + f0] = o;
    }
    __syncthreads();

    // ---- row-sliced epilogue: stats (+ h_e write if LAST) ----
    float s[8], q[8];
    #pragma unroll
    for (int j = 0; j < 8; j++) { s[j] = 0.f; q[j] = 0.f; }
    #pragma unroll
    for (int p = 0; p < 2; p++) {
        int rr = p ? rr1 : rr0;
        uint4 g3 = p ? g3b : g3a;
        uint4 g4 = p ? g4b : g4a;
        unsigned u3[4] = {g3.x, g3.y, g3.z, g3.w};
        unsigned u4[4] = {g4.x, g4.y, g4.z, g4.w};
        uint4 hu = *(uint4*)&Hs[rr * 68 + c8];
        unsigned uh[4] = {hu.x, hu.y, hu.z, hu.w};
        float h[8];
        #pragma unroll
        for (int j = 0; j < 4; j++) {
            float h0 = bflo(uh[j]) + bflo(u3[j]) + bflo(u4[j]);
            float h1 = bfhi(uh[j]) + bfhi(u3[j]) + bfhi(u4[j]);
            h[2*j] = h0; h[2*j+1] = h1;
            s[2*j] += h0; s[2*j+1] += h1;
            q[2*j] += h0 * h0; q[2*j+1] += h1 * h1;
        }
        if (LAST) {
            uint4 hv;
            hv.x = packbf(h[0], h[1]); hv.y = packbf(h[2], h[3]);
            hv.z = packbf(h[4], h[5]); hv.w = packbf(h[6], h[7]);
            *(uint4*)&h_e[(row0 + rr) * 64 + c8] = hv;
        }
    }
    #pragma unroll
    for (int d = 8; d < 64; d <<= 1) {
        #pragma unroll
        for (int j = 0; j < 8; j++) {
            s[j] += __shfl_xor(s[j], d);
            q[j] += __shfl_xor(q[j], d);
        }
    }
    if ((l >> 3) == 0) {
        #pragma unroll
        for (int j = 0; j < 8; j++) {
            sredS[wv][(l & 7) * 8 + j] = s[j];
            sredQ[wv][(l & 7) * 8 + j] = q[j];
        }
    }
    __syncthreads();
    if (tid < 128) {
        int which = tid >> 6, f = tid & 63;
        float v = which ? (sredQ[0][f] + sredQ[1][f] + sredQ[2][f] + sredQ[3][f])
                        : (sredS[0][f] + sredS[1][f] + sredS[2][f] + sredS[3][f]);
        atomicAdd(&estats[(blockIdx.x & 7) * 128 + which * 64 + f], v);
    }
}

// ---------- node finish: aggregation + node stats; FINAL also emits out_w in-loop ----------
template <bool FINAL>
__global__ __launch_bounds__(256)
void node_finish_kernel(const __hip_bfloat16* __restrict__ w_csr, const int* __restrict__ srcc,
                        const __hip_bfloat16* __restrict__ x2, const __hip_bfloat16* __restrict__ x1,
                        const int* __restrict__ off, float* __restrict__ h_v,
                        float* __restrict__ nstats,
                        const __hip_bfloat16* __restrict__ h_e, const int* __restrict__ eidx,
                        float* __restrict__ out_w, const float* __restrict__ fin, int Nn) {
    __shared__ float red[8 * 66];
    __shared__ float km[64], ka[64];
    int tid = threadIdx.x;
    if (FINAL) {
        if (tid < 64) { km[tid] = fin[128 + tid]; ka[tid] = fin[192 + tid]; }
        __syncthreads();
    }
    int hw = tid >> 5, k = tid & 31;
    int n = blockIdx.x * 8 + hw;
    float h0 = 0.f, h1 = 0.f;
    if (n < Nn) {
        int o0 = off[n], o1 = off[n + 1];
        float a0 = 0.f, a1 = 0.f;
        int j = o0;
        for (; j + 3 < o1; j += 4) {   // 4 independent load chains in flight
            int s0 = srcc[j], s1 = srcc[j + 1], s2 = srcc[j + 2], s3 = srcc[j + 3];
            unsigned wu0 = *(const unsigned*)&w_csr[(long long)j * 64 + 2 * k];
            unsigned wu1 = *(const unsigned*)&w_csr[(long long)(j + 1) * 64 + 2 * k];
            unsigned wu2 = *(const unsigned*)&w_csr[(long long)(j + 2) * 64 + 2 * k];
            unsigned wu3 = *(const unsigned*)&w_csr[(long long)(j + 3) * 64 + 2 * k];
            unsigned xu0 = *(const unsigned*)&x2[(long long)s0 * 64 + 2 * k];
            unsigned xu1 = *(const unsigned*)&x2[(long long)s1 * 64 + 2 * k];
            unsigned xu2 = *(const unsigned*)&x2[(long long)s2 * 64 + 2 * k];
            unsigned xu3 = *(const unsigned*)&x2[(long long)s3 * 64 + 2 * k];
            a0 += bflo(xu0) * fsig(bflo(wu0)) + bflo(xu1) * fsig(bflo(wu1))
                + bflo(xu2) * fsig(bflo(wu2)) + bflo(xu3) * fsig(bflo(wu3));
            a1 += bfhi(xu0) * fsig(bfhi(wu0)) + bfhi(xu1) * fsig(bfhi(wu1))
                + bfhi(xu2) * fsig(bfhi(wu2)) + bfhi(xu3) * fsig(bfhi(wu3));
            if (FINAL) {
                unsigned hu0 = *(const unsigned*)&h_e[(long long)j * 64 + 2 * k];
                unsigned hu1 = *(const unsigned*)&h_e[(long long)(j + 1) * 64 + 2 * k];
                unsigned hu2 = *(const unsigned*)&h_e[(long long)(j + 2) * 64 + 2 * k];
                unsigned hu3 = *(const unsigned*)&h_e[(long long)(j + 3) * 64 + 2 * k];
                int e0 = eidx[j], e1 = eidx[j + 1], e2 = eidx[j + 2], e3 = eidx[j + 3];
                *(float2*)&out_w[(long long)e0 * 64 + 2 * k] = make_float2(
                    bflo(wu0) + silu(bflo(hu0) * km[2*k]   + ka[2*k]),
                    bfhi(wu0) + silu(bfhi(hu0) * km[2*k+1] + ka[2*k+1]));
                *(float2*)&out_w[(long long)e1 * 64 + 2 * k] = make_float2(
                    bflo(wu1) + silu(bflo(hu1) * km[2*k]   + ka[2*k]),
                    bfhi(wu1) + silu(bfhi(hu1) * km[2*k+1] + ka[2*k+1]));
                *(float2*)&out_w[(long long)e2 * 64 + 2 * k] = make_float2(
                    bflo(wu2) + silu(bflo(hu2) * km[2*k]   + ka[2*k]),
                    bfhi(wu2) + silu(bfhi(hu2) * km[2*k+1] + ka[2*k+1]));
                *(float2*)&out_w[(long long)e3 * 64 + 2 * k] = make_float2(
                    bflo(wu3) + silu(bflo(hu3) * km[2*k]   + ka[2*k]),
                    bfhi(wu3) + silu(bfhi(hu3) * km[2*k+1] + ka[2*k+1]));
            }
        }
        for (; j < o1; j++) {
            int s0 = srcc[j];
            unsigned wu0 = *(const unsigned*)&w_csr[(long long)j * 64 + 2 * k];
            unsigned xu0 = *(const unsigned*)&x2[(long long)s0 * 64 + 2 * k];
            a0 += bflo(xu0) * fsig(bflo(wu0));
            a1 += bfhi(xu0) * fsig(bfhi(wu0));
            if (FINAL) {
                unsigned hu0 = *(const unsigned*)&h_e[(long long)j * 64 + 2 * k];
                int e0 = eidx[j];
                *(float2*)&out_w[(long long)e0 * 64 + 2 * k] = make_float2(
                    bflo(wu0) + silu(bflo(hu0) * km[2*k]   + ka[2*k]),
                    bfhi(wu0) + silu(bfhi(hu0) * km[2*k+1] + ka[2*k+1]));
            }
        }
        float ic = 1.f / fmaxf((float)(o1 - o0), 1.f);
        unsigned xu = *(const unsigned*)&x1[(long long)n * 64 + 2 * k];
        h0 = bflo(xu) + a0 * ic;
        h1 = bfhi(xu) + a1 * ic;
        *(float2*)&h_v[(long long)n * 64 + 2 * k] = make_float2(h0, h1);
    }
    red[hw * 66 + 2 * k] = h0;
    red[hw * 66 + 2 * k + 1] = h1;
    __syncthreads();
    float* nst = nstats + (blockIdx.x & 7) * 128;
    if (tid < 64) {
        float s = 0.f;
        #pragma unroll
        for (int r = 0; r < 8; r++) s += red[r * 66 + tid];
        atomicAdd(&nst[tid], s);
    }
    __syncthreads();
    red[hw * 66 + 2 * k] = h0 * h0;
    red[hw * 66 + 2 * k + 1] = h1 * h1;
    __syncthreads();
    if (tid < 64) {
        float s = 0.f;
        #pragma unroll
        for (int r = 0; r < 8; r++) s += red[r * 66 + tid];
        atomicAdd(&nst[64 + tid], s);
    }
}

// ---------- finalize edge part: estats -> fin[128..256] ----------
__global__ void finalize_edge_kernel(const float* __restrict__ estats,
                                     const float* __restrict__ es, const float* __restrict__ eb,
                                     float* __restrict__ fin, float invE) {
    int c = threadIdx.x;
    float s = 0.f, q = 0.f;
    #pragma unroll
    for (int r = 0; r < 8; r++) { s += estats[r * 128 + c]; q += estats[r * 128 + 64 + c]; }
    float mean = s * invE;
    float var = q * invE - mean * mean;
    float kmul = rsqrtf(var + 1e-5f) * es[c];
    fin[128 + c] = kmul;
    fin[192 + c] = eb[c] - mean * kmul;
}

// ---------- finalize node part: nstats -> fin[0..128] ----------
__global__ void finalize_node_kernel(const float* __restrict__ nstats,
                                     const float* __restrict__ vs, const float* __restrict__ vb,
                                     float* __restrict__ fin, float invN) {
    int c = threadIdx.x;
    float s = 0.f, q = 0.f;
    #pragma unroll
    for (int r = 0; r < 8; r++) { s += nstats[r * 128 + c]; q += nstats[r * 128 + 64 + c]; }
    float mean = s * invN;
    float var = q * invN - mean * mean;
    float kmul = rsqrtf(var + 1e-5f) * vs[c];
    fin[c] = kmul;
    fin[64 + c] = vb[c] - mean * kmul;
}

// ---------- node BN apply ----------
__global__ __launch_bounds__(256)
void node_apply_kernel(const float4* __restrict__ hv4, const float4* __restrict__ xold4,
                       float4* __restrict__ out4, const float* __restrict__ fin, int total) {
    __shared__ float km[64], ka[64];
    if (threadIdx.x < 64) { km[threadIdx.x] = fin[threadIdx.x]; ka[threadIdx.x] = fin[64 + threadIdx.x]; }
    __syncthreads();
    int idx = blockIdx.x * 256 + threadIdx.x;
    if (idx >= total) return;
    int c0 = (idx & 15) * 4;
    float4 h = hv4[idx], xo = xold4[idx];
    float4 m = *(float4*)&km[c0], a = *(float4*)&ka[c0];
    float g0 = h.x * m.x + a.x, g1 = h.y * m.y + a.y, g2 = h.z * m.z + a.z, g3 = h.w * m.w + a.w;
    out4[idx] = make_float4(xo.x + silu(g0), xo.y + silu(g1),
                            xo.z + silu(g2), xo.w + silu(g3));
}

// ---------- launch ----------
extern "C" void kernel_launch(void* const* d_in, const int* in_sizes, int n_in,
                              void* d_out, int out_size, void* d_ws, size_t ws_size,
                              hipStream_t stream) {
    const float* x_in  = (const float*)d_in[0];
    const float* ea_in = (const float*)d_in[1];
    const int*   ei    = (const int*)d_in[2];
    const float* v_w   = (const float*)d_in[3];
    const float* v_b   = (const float*)d_in[4];
    const float* e_w   = (const float*)d_in[5];
    const float* e_b   = (const float*)d_in[6];
    const float* vbn_s = (const float*)d_in[7];
    const float* vbn_b = (const float*)d_in[8];
    const float* ebn_s = (const float*)d_in[9];
    const float* ebn_b = (const float*)d_in[10];

    const int Nn = in_sizes[0] / 64;
    const int E  = in_sizes[1] / 64;
    const int L  = in_sizes[3] / (4 * 64 * 64);

    const int* dst = ei;
    const int* src = ei + E;

    // workspace layout
    float* h_v    = (float*)d_ws;                       // [Nn][64] fp32
    float* nstats = h_v + (long long)Nn * 64;           // [L][8][128]
    float* estats = nstats + (long long)L * 1024;       // [L][8][128]
    float* fin    = estats + (long long)L * 1024;       // [4][64]
    __hip_bfloat16* xp0   = (__hip_bfloat16*)(fin + 256);      // [4][Nn][64]
    __hip_bfloat16* xp1   = xp0 + (long long)4 * Nn * 64;      // [4][Nn][64]
    __hip_bfloat16* h_e   = xp1 + (long long)4 * Nn * 64;      // [E][64] CSR (last layer only)
    __hip_bfloat16* w_csr = h_e + (long long)E * 64;           // [E][64] CSR
    short* vwp = (short*)(w_csr + (long long)E * 64);   // [L][4][4][2][64][8]
    short* ewp = vwp + (long long)L * 16384;            // [L][4][2][64][8]
    int* cnt  = (int*)(ewp + (long long)L * 4096);      // [Nn]
    int* off  = cnt + Nn;                               // [Nn+1]
    int* eidx = off + Nn + 1;                           // [E]
    int* dstc = eidx + E;                               // [E]
    int* srcc = dstc + E;                               // [E]
    int* bsum = srcc + E;                               // [64]

    size_t needed = ((size_t)Nn * 64 + (size_t)L * 2048 + 256) * 4 +
                    ((size_t)8 * Nn * 64 + (size_t)2 * E * 64 + (size_t)L * 20480) * 2 +
                    ((size_t)2 * Nn + 1 + (size_t)3 * E + 64) * 4;
    if (ws_size < needed) return;

    float* out_x = (float*)d_out;
    float* out_w = out_x + (long long)Nn * 64;

    // CSR build + zero stats + pack weights (once per call)
    const int nb = (Nn + 1023) / 1024;
    zero_int_kernel<<<64, 256, 0, stream>>>(cnt, Nn);
    zero_int_kernel<<<8, 256, 0, stream>>>((int*)nstats, L * 2048);
    count_kernel<<<(E + 255) / 256, 256, 0, stream>>>(dst, cnt, E);
    scan_block_kernel<<<nb, 1024, 0, stream>>>(cnt, off, bsum, Nn);
    scan_tops_kernel<<<1, 64, 0, stream>>>(bsum, nb);
    scan_add_kernel<<<nb, 1024, 0, stream>>>(off, bsum, Nn);
    fill_csr_kernel<<<(E + 255) / 256, 256, 0, stream>>>(dst, src, off, cnt, eidx, dstc, srcc, E);
    pack_kernel<<<(L * 2560 + 255) / 256, 256, 0, stream>>>(v_w, e_w, vwp, ewp, L);

    for (int l = 0; l < L; l++) {
        const float* xl = (l == 0) ? x_in : out_x;
        bool first = (l == 0);
        bool last = (l == L - 1);
        float* nst = nstats + (long long)l * 1024;
        float* est = estats + (long long)l * 1024;
        __hip_bfloat16* xp_cur  = (l & 1) ? xp1 : xp0;
        __hip_bfloat16* xp_prev = (l & 1) ? xp0 : xp1;
        const __hip_bfloat16* x1 = xp_cur;
        const __hip_bfloat16* x2 = xp_cur + (long long)Nn * 64;
        const __hip_bfloat16* x3 = xp_cur + (long long)2 * Nn * 64;
        const __hip_bfloat16* x4 = xp_cur + (long long)3 * Nn * 64;
        const __hip_bfloat16* x3p = xp_prev + (long long)2 * Nn * 64;
        const __hip_bfloat16* x4p = xp_prev + (long long)3 * Nn * 64;

        // node projections -> xp_cur
        node_gemm_mfma<<<(Nn + 63) / 64, 256, 0, stream>>>(
            xl, vwp + (long long)l * 16384, v_b + l * 256, xp_cur, Nn);

        // edge GEMM: stage w + (recompute h_prev + fused update) + stats (+ h_e if last)
        const short* ewp_c = ewp + (long long)l * 4096;
        const short* ewp_pv = (l > 0) ? ewp + (long long)(l - 1) * 4096 : ewp_c;
        const float* eb_c = e_b + l * 64;
        const float* eb_pv = (l > 0) ? e_b + (l - 1) * 64 : eb_c;
        if (first && !last)
            edge_gemm_mfma<true, false><<<E / 64, 256, 0, stream>>>(
                ea_in, eidx, w_csr, h_e, fin, ewp_pv, eb_pv, ewp_c, eb_c,
                x3p, x4p, x3, x4, dstc, srcc, est);
        else if (first && last)
            edge_gemm_mfma<true, true><<<E / 64, 256, 0, stream>>>(
                ea_in, eidx, w_csr, h_e, fin, ewp_pv, eb_pv, ewp_c, eb_c,
                x3p, x4p, x3, x4, dstc, srcc, est);
        else if (!first && !last)
            edge_gemm_mfma<false, false><<<E / 64, 256, 0, stream>>>(
                ea_in, eidx, w_csr, h_e, fin, ewp_pv, eb_pv, ewp_c, eb_c,
                x3p, x4p, x3, x4, dstc, srcc, est);
        else
            edge_gemm_mfma<false, true><<<E / 64, 256, 0, stream>>>(
                ea_in, eidx, w_csr, h_e, fin, ewp_pv, eb_pv, ewp_c, eb_c,
                x3p, x4p, x3, x4, dstc, srcc, est);

        // fold edge BN affine -> fin[128..256]
        finalize_edge_kernel<<<1, 64, 0, stream>>>(
            est, ebn_s + l * 64, ebn_b + l * 64, fin, 1.f / (float)E);

        // aggregation + node stats (+ out_w emission on last layer)
        if (last)
            node_finish_kernel<true><<<(Nn + 7) / 8, 256, 0, stream>>>(
                w_csr, srcc, x2, x1, off, h_v, nst, h_e, eidx, out_w, fin, Nn);
        else
            node_finish_kernel<false><<<(Nn + 7) / 8, 256, 0, stream>>>(
                w_csr, srcc, x2, x1, off, h_v, nst, h_e, eidx, out_w, fin, Nn);

        // fold node BN affine -> fin[0..128]
        finalize_node_kernel<<<1, 64, 0, stream>>>(
            nst, vbn_s + l * 64, vbn_b + l * 64, fin, 1.f / (float)Nn);

        node_apply_kernel<<<(Nn * 16 + 255) / 256, 256, 0, stream>>>(
            (const float4*)h_v, (const float4*)xl, (float4*)out_x, fin, Nn * 16);
    }
}

// Round 13
// 646.681 us; speedup vs baseline: 7.6331x; 1.0036x over previous
//
#include <hip/hip_runtime.h>
#include <hip/hip_bf16.h>
#include <math.h>

typedef __attribute__((ext_vector_type(8))) short bf16x8;
typedef __attribute__((ext_vector_type(4))) float f32x4;

// ---------- bf16 helpers ----------
__device__ __forceinline__ float bflo(unsigned u) { return __uint_as_float(u << 16); }
__device__ __forceinline__ float bfhi(unsigned u) { return __uint_as_float(u & 0xffff0000u); }
__device__ __forceinline__ unsigned packbf(float a, float b) {
    unsigned ua = __float_as_uint(a), ub = __float_as_uint(b);
    ua += 0x7fffu + ((ua >> 16) & 1u);
    ub += 0x7fffu + ((ub >> 16) & 1u);
    return (ua >> 16) | (ub & 0xffff0000u);
}
// fast sigmoid/silu: v_rcp_f32 (~1 ulp) instead of IEEE divide
__device__ __forceinline__ float fsig(float w) {
    return __builtin_amdgcn_rcpf(1.f + __expf(-w));
}
__device__ __forceinline__ float silu(float g) { return g * fsig(g); }

// ---------- setup ----------
__global__ void zero_int_kernel(int* __restrict__ p, int n) {
    int i = blockIdx.x * blockDim.x + threadIdx.x;
    int s = gridDim.x * blockDim.x;
    for (; i < n; i += s) p[i] = 0;
}

__global__ void count_kernel(const int* __restrict__ dst, int* __restrict__ cnt, int E) {
    int e = blockIdx.x * blockDim.x + threadIdx.x;
    if (e < E) atomicAdd(&cnt[dst[e]], 1);
}

// 3-phase scan
__global__ __launch_bounds__(1024)
void scan_block_kernel(const int* __restrict__ cnt, int* __restrict__ off,
                       int* __restrict__ bsum, int n) {
    __shared__ int wsum[16];
    int tid = threadIdx.x, lane = tid & 63, wid = tid >> 6;
    int i = blockIdx.x * 1024 + tid;
    int v = (i < n) ? cnt[i] : 0;
    int sc = v;
    #pragma unroll
    for (int s = 1; s < 64; s <<= 1) {
        int t = __shfl_up(sc, (unsigned)s, 64);
        if (lane >= s) sc += t;
    }
    if (lane == 63) wsum[wid] = sc;
    __syncthreads();
    int woff = 0;
    for (int k = 0; k < wid; k++) woff += wsum[k];
    if (i < n) off[i + 1] = woff + sc;
    if (tid == 0) {
        int t = 0;
        #pragma unroll
        for (int k = 0; k < 16; k++) t += wsum[k];
        bsum[blockIdx.x] = t;
    }
}

__global__ void scan_tops_kernel(int* __restrict__ bsum, int nb) {
    int lane = threadIdx.x;
    int v = (lane < nb) ? bsum[lane] : 0;
    int sc = v;
    #pragma unroll
    for (int s = 1; s < 64; s <<= 1) {
        int t = __shfl_up(sc, (unsigned)s, 64);
        if (lane >= s) sc += t;
    }
    if (lane < nb) bsum[lane] = sc - v;
}

__global__ __launch_bounds__(1024)
void scan_add_kernel(int* __restrict__ off, const int* __restrict__ bsum, int n) {
    int i = blockIdx.x * 1024 + threadIdx.x;
    int b = bsum[blockIdx.x];
    if (i < n) off[i + 1] += b;
    if (i == 0) off[0] = 0;
}

__global__ void fill_csr_kernel(const int* __restrict__ dst, const int* __restrict__ src,
                                const int* __restrict__ off, int* __restrict__ cnt,
                                int* __restrict__ eidx, int* __restrict__ dstc,
                                int* __restrict__ srcc, int E) {
    int e = blockIdx.x * blockDim.x + threadIdx.x;
    if (e < E) {
        int d = dst[e];
        int pos = atomicSub(&cnt[d], 1) - 1;
        int slot = off[d] + pos;
        eidx[slot] = e;
        dstc[slot] = d;
        srcc[slot] = src[e];
    }
}

// ---------- pack weights into MFMA A-operand fragments (W^T, bf16) ----------
__global__ void pack_kernel(const float* __restrict__ v_w, const float* __restrict__ e_w,
                            short* __restrict__ vwp, short* __restrict__ ewp, int L) {
    int t = blockIdx.x * blockDim.x + threadIdx.x;
    if (t >= L * 5 * 4 * 2 * 64) return;
    int lane = t & 63;
    int ks = (t >> 6) & 1;
    int ft = (t >> 7) & 3;
    int mat = t >> 9;
    int layer = mat / 5, mi = mat % 5;
    const float* W = (mi < 4) ? (v_w + (long long)(layer * 4 + mi) * 4096)
                              : (e_w + (long long)layer * 4096);
    int m = ft * 16 + (lane & 15);
    int k0 = ks * 32 + (lane >> 4) * 8;
    short* dstp = (mi < 4)
        ? vwp + ((((long long)(layer * 4 + mi) * 4 + ft) * 2 + ks) * 64 + lane) * 8
        : ewp + ((((long long)layer * 4 + ft) * 2 + ks) * 64 + lane) * 8;
    #pragma unroll
    for (int j = 0; j < 8; j++) {
        unsigned u = __float_as_uint(W[(k0 + j) * 64 + m]);
        u += 0x7fffu + ((u >> 16) & 1u);
        dstp[j] = (short)(u >> 16);
    }
}

// ---------- node GEMM (MFMA) + optional fused residual-apply of previous layer ----------
// APPLY: x_cur = Xold + silu(h_v*km + ka) (fin[0..128] = prev layer node consts),
//        written to out_x and staged; else stage Xold directly.
template <bool APPLY>
__global__ __launch_bounds__(256)
void node_gemm_mfma(const float* __restrict__ Xold, const float* __restrict__ h_v,
                    float* __restrict__ out_x, const float* __restrict__ fin,
                    const short* __restrict__ vwp, const float* __restrict__ vb,
                    __hip_bfloat16* __restrict__ xp, int Nn) {
    __shared__ short Xs[64 * 64];
    __shared__ short Hs[64 * 64];     // single 8 KB tile, reused per group
    int tid = threadIdx.x;
    long long row0 = (long long)blockIdx.x * 64;

    {
        int r = tid >> 2, cq = tid & 3;
        long long row = row0 + r;
        float xv[16];
        #pragma unroll
        for (int j = 0; j < 16; j++) xv[j] = 0.f;
        if (row < Nn) {
            const float* sp = Xold + row * 64 + cq * 16;
            #pragma unroll
            for (int j = 0; j < 4; j++) {
                float4 v = *(const float4*)(sp + j * 4);
                xv[j*4] = v.x; xv[j*4+1] = v.y; xv[j*4+2] = v.z; xv[j*4+3] = v.w;
            }
            if (APPLY) {
                const float* hp = h_v + row * 64 + cq * 16;
                const float* kmp = fin + cq * 16;
                const float* kap = fin + 64 + cq * 16;
                #pragma unroll
                for (int j = 0; j < 16; j++) {
                    float g = hp[j] * kmp[j] + kap[j];
                    xv[j] = xv[j] + silu(g);
                }
                float* op = out_x + row * 64 + cq * 16;
                #pragma unroll
                for (int j = 0; j < 4; j++)
                    *(float4*)(op + j * 4) = make_float4(xv[j*4], xv[j*4+1], xv[j*4+2], xv[j*4+3]);
            }
        }
        uint4 w0, w1;
        w0.x = packbf(xv[0], xv[1]);   w0.y = packbf(xv[2], xv[3]);
        w0.z = packbf(xv[4], xv[5]);   w0.w = packbf(xv[6], xv[7]);
        w1.x = packbf(xv[8], xv[9]);   w1.y = packbf(xv[10], xv[11]);
        w1.z = packbf(xv[12], xv[13]); w1.w = packbf(xv[14], xv[15]);
        int base = r * 128 + cq * 32, swz = (r & 7) << 4;
        *(uint4*)((char*)Xs + (base ^ swz)) = w0;
        *(uint4*)((char*)Xs + ((base + 16) ^ swz)) = w1;
    }
    __syncthreads();

    int l = tid & 63;
    int rl = (tid >> 6) * 16 + (l & 15);
    bf16x8 bfr[2];
    #pragma unroll
    for (int ks = 0; ks < 2; ks++) {
        int off = (rl * 128 + ks * 64 + (l >> 4) * 16) ^ ((rl & 7) << 4);
        bfr[ks] = *(bf16x8*)((char*)Xs + off);
    }
    int q4 = (l >> 4) * 4;
    int r = tid >> 2, cc = (tid & 3) * 16;
    long long node = row0 + r;
    int swz = (r & 7) << 4;
    for (int g = 0; g < 4; g++) {
        #pragma unroll
        for (int ft = 0; ft < 4; ft++) {
            f32x4 acc = f32x4{0.f, 0.f, 0.f, 0.f};
            #pragma unroll
            for (int ks = 0; ks < 2; ks++) {
                bf16x8 a = *(const bf16x8*)(vwp + (((long long)(g * 4 + ft) * 2 + ks) * 64 + l) * 8);
                acc = __builtin_amdgcn_mfma_f32_16x16x32_bf16(a, bfr[ks], acc, 0, 0, 0);
            }
            int f0 = ft * 16 + q4;
            float4 bv = *(const float4*)&vb[g * 64 + f0];
            uint2 o;
            o.x = packbf(acc[0] + bv.x, acc[1] + bv.y);
            o.y = packbf(acc[2] + bv.z, acc[3] + bv.w);
            int hoff = (rl * 128 + f0 * 2) ^ ((rl & 7) << 4);
            *(uint2*)((char*)Hs + hoff) = o;
        }
        __syncthreads();
        if (node < Nn) {
            uint4 a = *(uint4*)((char*)Hs + ((r * 128 + cc * 2) ^ swz));
            uint4 b = *(uint4*)((char*)Hs + ((r * 128 + cc * 2 + 16) ^ swz));
            __hip_bfloat16* op = xp + ((long long)g * Nn + node) * 64 + cc;
            *(uint4*)op = a;
            *(uint4*)(op + 8) = b;
        }
        __syncthreads();
    }
}

// ---------- edge GEMM (MFMA), CSR state, h_e RECOMPUTE scheme ----------
template <bool FIRST, bool LAST>
__global__ __launch_bounds__(256)
void edge_gemm_mfma(const float* __restrict__ ea, const int* __restrict__ eidx,
                    __hip_bfloat16* __restrict__ w_csr, __hip_bfloat16* __restrict__ h_e,
                    const float* __restrict__ fin,
                    const short* __restrict__ ewp_p, const float* __restrict__ eb_p,
                    const short* __restrict__ ewp, const float* __restrict__ eb,
                    const __hip_bfloat16* __restrict__ x3p, const __hip_bfloat16* __restrict__ x4p,
                    const __hip_bfloat16* __restrict__ x3, const __hip_bfloat16* __restrict__ x4,
                    const int* __restrict__ dstc, const int* __restrict__ srcc,
                    float* __restrict__ estats) {
    __shared__ short Ws[64 * 64];
    __shared__ short Hs[64 * 68];
    __shared__ float sredS[4][64], sredQ[4][64];
    __shared__ int dstl[64], srcl[64];
    int tid = threadIdx.x;
    long long row0 = (long long)blockIdx.x * 64;

    // ---- stage w tile -> Ws ----
    {
        int r = tid >> 2, cq = tid & 3;
        long long grow = (row0 + r) * 64 + cq * 16;
        int base = r * 128 + cq * 32, swz = (r & 7) << 4;
        uint4 w0u, w1u;
        if (FIRST) {
            long long e0 = eidx[row0 + r];
            const float* sp = ea + e0 * 64 + cq * 16;
            float4 v0 = *(const float4*)(sp),     v1 = *(const float4*)(sp + 4);
            float4 v2 = *(const float4*)(sp + 8), v3 = *(const float4*)(sp + 12);
            w0u.x = packbf(v0.x, v0.y); w0u.y = packbf(v0.z, v0.w);
            w0u.z = packbf(v1.x, v1.y); w0u.w = packbf(v1.z, v1.w);
            w1u.x = packbf(v2.x, v2.y); w1u.y = packbf(v2.z, v2.w);
            w1u.z = packbf(v3.x, v3.y); w1u.w = packbf(v3.z, v3.w);
            *(uint4*)&w_csr[grow] = w0u;
            *(uint4*)&w_csr[grow + 8] = w1u;
        } else {
            w0u = *(const uint4*)&w_csr[grow];
            w1u = *(const uint4*)&w_csr[grow + 8];
        }
        *(uint4*)((char*)Ws + (base ^ swz)) = w0u;
        *(uint4*)((char*)Ws + ((base + 16) ^ swz)) = w1u;
        if (tid < 64) {
            dstl[tid] = dstc[row0 + tid];
            srcl[tid] = srcc[row0 + tid];
        }
    }
    __syncthreads();

    int l = tid & 63, wv = tid >> 6;
    int rl = wv * 16 + (l & 15);
    int q4 = (l >> 4) * 4;
    int rr0 = tid >> 3, rr1 = rr0 + 32;
    int c8 = (tid & 7) * 8;
    int de0 = dstl[rr0], se0 = srcl[rr0];
    int de1 = dstl[rr1], se1 = srcl[rr1];

    if (!FIRST) {
        uint4 p3a = *(const uint4*)&x3p[(long long)de0 * 64 + c8];
        uint4 p4a = *(const uint4*)&x4p[(long long)se0 * 64 + c8];
        uint4 p3b = *(const uint4*)&x3p[(long long)de1 * 64 + c8];
        uint4 p4b = *(const uint4*)&x4p[(long long)se1 * 64 + c8];

        bf16x8 bfr[2];
        #pragma unroll
        for (int ks = 0; ks < 2; ks++) {
            int off = (rl * 128 + ks * 64 + (l >> 4) * 16) ^ ((rl & 7) << 4);
            bfr[ks] = *(bf16x8*)((char*)Ws + off);
        }
        #pragma unroll
        for (int ft = 0; ft < 4; ft++) {
            f32x4 acc = f32x4{0.f, 0.f, 0.f, 0.f};
            #pragma unroll
            for (int ks = 0; ks < 2; ks++) {
                bf16x8 a = *(const bf16x8*)(ewp_p + (((long long)ft * 2 + ks) * 64 + l) * 8);
                acc = __builtin_amdgcn_mfma_f32_16x16x32_bf16(a, bfr[ks], acc, 0, 0, 0);
            }
            int f0 = ft * 16 + q4;
            float4 bv = *(const float4*)&eb_p[f0];
            uint2 o;
            o.x = packbf(acc[0] + bv.x, acc[1] + bv.y);
            o.y = packbf(acc[2] + bv.z, acc[3] + bv.w);
            *(uint2*)&Hs[rl * 68 + f0] = o;
        }
        __syncthreads();

        float4 km0 = *(const float4*)&fin[128 + c8], km1 = *(const float4*)&fin[128 + c8 + 4];
        float4 ka0 = *(const float4*)&fin[192 + c8], ka1 = *(const float4*)&fin[192 + c8 + 4];
        float kmv[8] = {km0.x, km0.y, km0.z, km0.w, km1.x, km1.y, km1.z, km1.w};
        float kav[8] = {ka0.x, ka0.y, ka0.z, ka0.w, ka1.x, ka1.y, ka1.z, ka1.w};
        #pragma unroll
        for (int p = 0; p < 2; p++) {
            int rr = p ? rr1 : rr0;
            uint4 p3 = p ? p3b : p3a;
            uint4 p4 = p ? p4b : p4a;
            unsigned u3[4] = {p3.x, p3.y, p3.z, p3.w};
            unsigned u4[4] = {p4.x, p4.y, p4.z, p4.w};
            uint4 hu = *(uint4*)&Hs[rr * 68 + c8];
            unsigned uh[4] = {hu.x, hu.y, hu.z, hu.w};
            int woff = (rr * 128 + c8 * 2) ^ ((rr & 7) << 4);
            uint4 wu = *(uint4*)((char*)Ws + woff);
            unsigned uw[4] = {wu.x, wu.y, wu.z, wu.w};
            float wn[8];
            #pragma unroll
            for (int j = 0; j < 4; j++) {
                float h0 = bflo(uh[j]) + bflo(u3[j]) + bflo(u4[j]);
                float h1 = bfhi(uh[j]) + bfhi(u3[j]) + bfhi(u4[j]);
                wn[2*j]   = bflo(uw[j]) + silu(h0 * kmv[2*j]   + kav[2*j]);
                wn[2*j+1] = bfhi(uw[j]) + silu(h1 * kmv[2*j+1] + kav[2*j+1]);
            }
            uint4 wo;
            wo.x = packbf(wn[0], wn[1]); wo.y = packbf(wn[2], wn[3]);
            wo.z = packbf(wn[4], wn[5]); wo.w = packbf(wn[6], wn[7]);
            *(uint4*)((char*)Ws + woff) = wo;
            *(uint4*)&w_csr[(row0 + rr) * 64 + c8] = wo;
        }
        __syncthreads();
    }

    // ---- current layer: gathers + fragment loads + MFMA ----
    uint4 g3a = *(const uint4*)&x3[(long long)de0 * 64 + c8];
    uint4 g4a = *(const uint4*)&x4[(long long)se0 * 64 + c8];
    uint4 g3b = *(const uint4*)&x3[(long long)de1 * 64 + c8];
    uint4 g4b = *(const uint4*)&x4[(long long)se1 * 64 + c8];
    bf16x8 bfr[2];
    #pragma unroll
    for (int ks = 0; ks < 2; ks++) {
        int off = (rl * 128 + ks * 64 + (l >> 4) * 16) ^ ((rl & 7) << 4);
        bfr[ks] = *(bf16x8*)((char*)Ws + off);
    }
    #pragma unroll
    for (int ft = 0; ft < 4; ft++) {
        f32x4 acc = f32x4{0.f, 0.f, 0.f, 0.f};
        #pragma unroll
        for (int ks = 0; ks < 2; ks++) {
            bf16x8 a = *(const bf16x8*)(ewp + (((long long)ft * 2 + ks) * 64 + l) * 8);
            acc = __builtin_amdgcn_mfma_f32_16x16x32_bf16(a, bfr[ks], acc, 0, 0, 0);
        }
        int f0 = ft * 16 + q4;
        float4 bv = *(const float4*)&eb[f0];
        uint2 o;
        o.x = packbf(acc[0] + bv.x, acc[1] + bv.y);
        o.y = packbf(acc[2] + bv.z, acc[3] + bv.w);
        *(uint2*)&Hs[rl * 68 + f0] = o;
    }
    __syncthreads();

    // ---- row-sliced epilogue: stats (+ h_e write if LAST) ----
    float s[8], q[8];
    #pragma unroll
    for (int j = 0; j < 8; j++) { s[j] = 0.f; q[j] = 0.f; }
    #pragma unroll
    for (int p = 0; p < 2; p++) {
        int rr = p ? rr1 : rr0;
        uint4 g3 = p ? g3b : g3a;
        uint4 g4 = p ? g4b : g4a;
        unsigned u3[4] = {g3.x, g3.y, g3.z, g3.w};
        unsigned u4[4] = {g4.x, g4.y, g4.z, g4.w};
        uint4 hu = *(uint4*)&Hs[rr * 68 + c8];
        unsigned uh[4] = {hu.x, hu.y, hu.z, hu.w};
        float h[8];
        #pragma unroll
        for (int j = 0; j < 4; j++) {
            float h0 = bflo(uh[j]) + bflo(u3[j]) + bflo(u4[j]);
            float h1 = bfhi(uh[j]) + bfhi(u3[j]) + bfhi(u4[j]);
            h[2*j] = h0; h[2*j+1] = h1;
            s[2*j] += h0; s[2*j+1] += h1;
            q[2*j] += h0 * h0; q[2*j+1] += h1 * h1;
        }
        if (LAST) {
            uint4 hv;
            hv.x = packbf(h[0], h[1]); hv.y = packbf(h[2], h[3]);
            hv.z = packbf(h[4], h[5]); hv.w = packbf(h[6], h[7]);
            *(uint4*)&h_e[(row0 + rr) * 64 + c8] = hv;
        }
    }
    #pragma unroll
    for (int d = 8; d < 64; d <<= 1) {
        #pragma unroll
        for (int j = 0; j < 8; j++) {
            s[j] += __shfl_xor(s[j], d);
            q[j] += __shfl_xor(q[j], d);
        }
    }
    if ((l >> 3) == 0) {
        #pragma unroll
        for (int j = 0; j < 8; j++) {
            sredS[wv][(l & 7) * 8 + j] = s[j];
            sredQ[wv][(l & 7) * 8 + j] = q[j];
        }
    }
    __syncthreads();
    if (tid < 128) {
        int which = tid >> 6, f = tid & 63;
        float v = which ? (sredQ[0][f] + sredQ[1][f] + sredQ[2][f] + sredQ[3][f])
                        : (sredS[0][f] + sredS[1][f] + sredS[2][f] + sredS[3][f]);
        atomicAdd(&estats[(blockIdx.x & 7) * 128 + which * 64 + f], v);
    }
}

// ---------- node finish: aggregation + node stats; FINAL also emits out_w in-loop ----------
template <bool FINAL>
__global__ __launch_bounds__(256)
void node_finish_kernel(const __hip_bfloat16* __restrict__ w_csr, const int* __restrict__ srcc,
                        const __hip_bfloat16* __restrict__ x2, const __hip_bfloat16* __restrict__ x1,
                        const int* __restrict__ off, float* __restrict__ h_v,
                        float* __restrict__ nstats,
                        const __hip_bfloat16* __restrict__ h_e, const int* __restrict__ eidx,
                        float* __restrict__ out_w, const float* __restrict__ fin, int Nn) {
    __shared__ float red[8 * 66];
    __shared__ float km[64], ka[64];
    int tid = threadIdx.x;
    if (FINAL) {
        if (tid < 64) { km[tid] = fin[128 + tid]; ka[tid] = fin[192 + tid]; }
        __syncthreads();
    }
    int hw = tid >> 5, k = tid & 31;
    int n = blockIdx.x * 8 + hw;
    float h0 = 0.f, h1 = 0.f;
    if (n < Nn) {
        int o0 = off[n], o1 = off[n + 1];
        float a0 = 0.f, a1 = 0.f;
        int j = o0;
        for (; j + 3 < o1; j += 4) {
            int s0 = srcc[j], s1 = srcc[j + 1], s2 = srcc[j + 2], s3 = srcc[j + 3];
            unsigned wu0 = *(const unsigned*)&w_csr[(long long)j * 64 + 2 * k];
            unsigned wu1 = *(const unsigned*)&w_csr[(long long)(j + 1) * 64 + 2 * k];
            unsigned wu2 = *(const unsigned*)&w_csr[(long long)(j + 2) * 64 + 2 * k];
            unsigned wu3 = *(const unsigned*)&w_csr[(long long)(j + 3) * 64 + 2 * k];
            unsigned xu0 = *(const unsigned*)&x2[(long long)s0 * 64 + 2 * k];
            unsigned xu1 = *(const unsigned*)&x2[(long long)s1 * 64 + 2 * k];
            unsigned xu2 = *(const unsigned*)&x2[(long long)s2 * 64 + 2 * k];
            unsigned xu3 = *(const unsigned*)&x2[(long long)s3 * 64 + 2 * k];
            a0 += bflo(xu0) * fsig(bflo(wu0)) + bflo(xu1) * fsig(bflo(wu1))
                + bflo(xu2) * fsig(bflo(wu2)) + bflo(xu3) * fsig(bflo(wu3));
            a1 += bfhi(xu0) * fsig(bfhi(wu0)) + bfhi(xu1) * fsig(bfhi(wu1))
                + bfhi(xu2) * fsig(bfhi(wu2)) + bfhi(xu3) * fsig(bfhi(wu3));
            if (FINAL) {
                unsigned hu0 = *(const unsigned*)&h_e[(long long)j * 64 + 2 * k];
                unsigned hu1 = *(const unsigned*)&h_e[(long long)(j + 1) * 64 + 2 * k];
                unsigned hu2 = *(const unsigned*)&h_e[(long long)(j + 2) * 64 + 2 * k];
                unsigned hu3 = *(const unsigned*)&h_e[(long long)(j + 3) * 64 + 2 * k];
                int e0 = eidx[j], e1 = eidx[j + 1], e2 = eidx[j + 2], e3 = eidx[j + 3];
                *(float2*)&out_w[(long long)e0 * 64 + 2 * k] = make_float2(
                    bflo(wu0) + silu(bflo(hu0) * km[2*k]   + ka[2*k]),
                    bfhi(wu0) + silu(bfhi(hu0) * km[2*k+1] + ka[2*k+1]));
                *(float2*)&out_w[(long long)e1 * 64 + 2 * k] = make_float2(
                    bflo(wu1) + silu(bflo(hu1) * km[2*k]   + ka[2*k]),
                    bfhi(wu1) + silu(bfhi(hu1) * km[2*k+1] + ka[2*k+1]));
                *(float2*)&out_w[(long long)e2 * 64 + 2 * k] = make_float2(
                    bflo(wu2) + silu(bflo(hu2) * km[2*k]   + ka[2*k]),
                    bfhi(wu2) + silu(bfhi(hu2) * km[2*k+1] + ka[2*k+1]));
                *(float2*)&out_w[(long long)e3 * 64 + 2 * k] = make_float2(
                    bflo(wu3) + silu(bflo(hu3) * km[2*k]   + ka[2*k]),
                    bfhi(wu3) + silu(bfhi(hu3) * km[2*k+1] + ka[2*k+1]));
            }
        }
        for (; j < o1; j++) {
            int s0 = srcc[j];
            unsigned wu0 = *(const unsigned*)&w_csr[(long long)j * 64 + 2 * k];
            unsigned xu0 = *(const unsigned*)&x2[(long long)s0 * 64 + 2 * k];
            a0 += bflo(xu0) * fsig(bflo(wu0));
            a1 += bfhi(xu0) * fsig(bfhi(wu0));
            if (FINAL) {
                unsigned hu0 = *(const unsigned*)&h_e[(long long)j * 64 + 2 * k];
                int e0 = eidx[j];
                *(float2*)&out_w[(long long)e0 * 64 + 2 * k] = make_float2(
                    bflo(wu0) + silu(bflo(hu0) * km[2*k]   + ka[2*k]),
                    bfhi(wu0) + silu(bfhi(hu0) * km[2*k+1] + ka[2*k+1]));
            }
        }
        float ic = 1.f / fmaxf((float)(o1 - o0), 1.f);
        unsigned xu = *(const unsigned*)&x1[(long long)n * 64 + 2 * k];
        h0 = bflo(xu) + a0 * ic;
        h1 = bfhi(xu) + a1 * ic;
        *(float2*)&h_v[(long long)n * 64 + 2 * k] = make_float2(h0, h1);
    }
    red[hw * 66 + 2 * k] = h0;
    red[hw * 66 + 2 * k + 1] = h1;
    __syncthreads();
    float* nst = nstats + (blockIdx.x & 7) * 128;
    if (tid < 64) {
        float s = 0.f;
        #pragma unroll
        for (int r = 0; r < 8; r++) s += red[r * 66 + tid];
        atomicAdd(&nst[tid], s);
    }
    __syncthreads();
    red[hw * 66 + 2 * k] = h0 * h0;
    red[hw * 66 + 2 * k + 1] = h1 * h1;
    __syncthreads();
    if (tid < 64) {
        float s = 0.f;
        #pragma unroll
        for (int r = 0; r < 8; r++) s += red[r * 66 + tid];
        atomicAdd(&nst[64 + tid], s);
    }
}

// ---------- finalize edge part: estats -> fin[128..256] ----------
__global__ void finalize_edge_kernel(const float* __restrict__ estats,
                                     const float* __restrict__ es, const float* __restrict__ eb,
                                     float* __restrict__ fin, float invE) {
    int c = threadIdx.x;
    float s = 0.f, q = 0.f;
    #pragma unroll
    for (int r = 0; r < 8; r++) { s += estats[r * 128 + c]; q += estats[r * 128 + 64 + c]; }
    float mean = s * invE;
    float var = q * invE - mean * mean;
    float kmul = rsqrtf(var + 1e-5f) * es[c];
    fin[128 + c] = kmul;
    fin[192 + c] = eb[c] - mean * kmul;
}

// ---------- finalize node part: nstats -> fin[0..128] ----------
__global__ void finalize_node_kernel(const float* __restrict__ nstats,
                                     const float* __restrict__ vs, const float* __restrict__ vb,
                                     float* __restrict__ fin, float invN) {
    int c = threadIdx.x;
    float s = 0.f, q = 0.f;
    #pragma unroll
    for (int r = 0; r < 8; r++) { s += nstats[r * 128 + c]; q += nstats[r * 128 + 64 + c]; }
    float mean = s * invN;
    float var = q * invN - mean * mean;
    float kmul = rsqrtf(var + 1e-5f) * vs[c];
    fin[c] = kmul;
    fin[64 + c] = vb[c] - mean * kmul;
}

// ---------- node BN apply (standalone, last layer only) ----------
__global__ __launch_bounds__(256)
void node_apply_kernel(const float4* __restrict__ hv4, const float4* __restrict__ xold4,
                       float4* __restrict__ out4, const float* __restrict__ fin, int total) {
    __shared__ float km[64], ka[64];
    if (threadIdx.x < 64) { km[threadIdx.x] = fin[threadIdx.x]; ka[threadIdx.x] = fin[64 + threadIdx.x]; }
    __syncthreads();
    int idx = blockIdx.x * 256 + threadIdx.x;
    if (idx >= total) return;
    int c0 = (idx & 15) * 4;
    float4 h = hv4[idx], xo = xold4[idx];
    float4 m = *(float4*)&km[c0], a = *(float4*)&ka[c0];
    float g0 = h.x * m.x + a.x, g1 = h.y * m.y + a.y, g2 = h.z * m.z + a.z, g3 = h.w * m.w + a.w;
    out4[idx] = make_float4(xo.x + silu(g0), xo.y + silu(g1),
                            xo.z + silu(g2), xo.w + silu(g3));
}

// ---------- launch ----------
extern "C" void kernel_launch(void* const* d_in, const int* in_sizes, int n_in,
                              void* d_out, int out_size, void* d_ws, size_t ws_size,
                              hipStream_t stream) {
    const float* x_in  = (const float*)d_in[0];
    const float* ea_in = (const float*)d_in[1];
    const int*   ei    = (const int*)d_in[2];
    const float* v_w   = (const float*)d_in[3];
    const float* v_b   = (const float*)d_in[4];
    const float* e_w   = (const float*)d_in[5];
    const float* e_b   = (const float*)d_in[6];
    const float* vbn_s = (const float*)d_in[7];
    const float* vbn_b = (const float*)d_in[8];
    const float* ebn_s = (const float*)d_in[9];
    const float* ebn_b = (const float*)d_in[10];

    const int Nn = in_sizes[0] / 64;
    const int E  = in_sizes[1] / 64;
    const int L  = in_sizes[3] / (4 * 64 * 64);

    const int* dst = ei;
    const int* src = ei + E;

    // workspace layout
    float* h_v    = (float*)d_ws;                       // [Nn][64] fp32
    float* nstats = h_v + (long long)Nn * 64;           // [L][8][128]
    float* estats = nstats + (long long)L * 1024;       // [L][8][128]
    float* fin    = estats + (long long)L * 1024;       // [4][64]
    __hip_bfloat16* xp0   = (__hip_bfloat16*)(fin + 256);      // [4][Nn][64]
    __hip_bfloat16* xp1   = xp0 + (long long)4 * Nn * 64;      // [4][Nn][64]
    __hip_bfloat16* h_e   = xp1 + (long long)4 * Nn * 64;      // [E][64] CSR (last layer only)
    __hip_bfloat16* w_csr = h_e + (long long)E * 64;           // [E][64] CSR
    short* vwp = (short*)(w_csr + (long long)E * 64);   // [L][4][4][2][64][8]
    short* ewp = vwp + (long long)L * 16384;            // [L][4][2][64][8]
    int* cnt  = (int*)(ewp + (long long)L * 4096);      // [Nn]
    int* off  = cnt + Nn;                               // [Nn+1]
    int* eidx = off + Nn + 1;                           // [E]
    int* dstc = eidx + E;                               // [E]
    int* srcc = dstc + E;                               // [E]
    int* bsum = srcc + E;                               // [64]

    size_t needed = ((size_t)Nn * 64 + (size_t)L * 2048 + 256) * 4 +
                    ((size_t)8 * Nn * 64 + (size_t)2 * E * 64 + (size_t)L * 20480) * 2 +
                    ((size_t)2 * Nn + 1 + (size_t)3 * E + 64) * 4;
    if (ws_size < needed) return;

    float* out_x = (float*)d_out;
    float* out_w = out_x + (long long)Nn * 64;

    // CSR build + zero stats + pack weights (once per call)
    const int nb = (Nn + 1023) / 1024;
    zero_int_kernel<<<64, 256, 0, stream>>>(cnt, Nn);
    zero_int_kernel<<<8, 256, 0, stream>>>((int*)nstats, L * 2048);
    count_kernel<<<(E + 255) / 256, 256, 0, stream>>>(dst, cnt, E);
    scan_block_kernel<<<nb, 1024, 0, stream>>>(cnt, off, bsum, Nn);
    scan_tops_kernel<<<1, 64, 0, stream>>>(bsum, nb);
    scan_add_kernel<<<nb, 1024, 0, stream>>>(off, bsum, Nn);
    fill_csr_kernel<<<(E + 255) / 256, 256, 0, stream>>>(dst, src, off, cnt, eidx, dstc, srcc, E);
    pack_kernel<<<(L * 2560 + 255) / 256, 256, 0, stream>>>(v_w, e_w, vwp, ewp, L);

    for (int l = 0; l < L; l++) {
        bool first = (l == 0);
        bool last = (l == L - 1);
        float* nst = nstats + (long long)l * 1024;
        float* est = estats + (long long)l * 1024;
        __hip_bfloat16* xp_cur  = (l & 1) ? xp1 : xp0;
        __hip_bfloat16* xp_prev = (l & 1) ? xp0 : xp1;
        const __hip_bfloat16* x1 = xp_cur;
        const __hip_bfloat16* x2 = xp_cur + (long long)Nn * 64;
        const __hip_bfloat16* x3 = xp_cur + (long long)2 * Nn * 64;
        const __hip_bfloat16* x4 = xp_cur + (long long)3 * Nn * 64;
        const __hip_bfloat16* x3p = xp_prev + (long long)2 * Nn * 64;
        const __hip_bfloat16* x4p = xp_prev + (long long)3 * Nn * 64;

        // node projections -> xp_cur; l>=1 fuses previous layer's residual apply
        // xold for apply(l-1): x(l-2) which is x_in for l==1, else out_x.
        const float* xold = (l <= 1) ? x_in : out_x;
        if (first)
            node_gemm_mfma<false><<<(Nn + 63) / 64, 256, 0, stream>>>(
                x_in, h_v, out_x, fin, vwp + (long long)l * 16384, v_b + l * 256, xp_cur, Nn);
        else
            node_gemm_mfma<true><<<(Nn + 63) / 64, 256, 0, stream>>>(
                xold, h_v, out_x, fin, vwp + (long long)l * 16384, v_b + l * 256, xp_cur, Nn);

        // edge GEMM: stage w + (recompute h_prev + fused update) + stats (+ h_e if last)
        const short* ewp_c = ewp + (long long)l * 4096;
        const short* ewp_pv = (l > 0) ? ewp + (long long)(l - 1) * 4096 : ewp_c;
        const float* eb_c = e_b + l * 64;
        const float* eb_pv = (l > 0) ? e_b + (l - 1) * 64 : eb_c;
        if (first && !last)
            edge_gemm_mfma<true, false><<<E / 64, 256, 0, stream>>>(
                ea_in, eidx, w_csr, h_e, fin, ewp_pv, eb_pv, ewp_c, eb_c,
                x3p, x4p, x3, x4, dstc, srcc, est);
        else if (first && last)
            edge_gemm_mfma<true, true><<<E / 64, 256, 0, stream>>>(
                ea_in, eidx, w_csr, h_e, fin, ewp_pv, eb_pv, ewp_c, eb_c,
                x3p, x4p, x3, x4, dstc, srcc, est);
        else if (!first && !last)
            edge_gemm_mfma<false, false><<<E / 64, 256, 0, stream>>>(
                ea_in, eidx, w_csr, h_e, fin, ewp_pv, eb_pv, ewp_c, eb_c,
                x3p, x4p, x3, x4, dstc, srcc, est);
        else
            edge_gemm_mfma<false, true><<<E / 64, 256, 0, stream>>>(
                ea_in, eidx, w_csr, h_e, fin, ewp_pv, eb_pv, ewp_c, eb_c,
                x3p, x4p, x3, x4, dstc, srcc, est);

        // fold edge BN affine -> fin[128..256]
        finalize_edge_kernel<<<1, 64, 0, stream>>>(
            est, ebn_s + l * 64, ebn_b + l * 64, fin, 1.f / (float)E);

        // aggregation + node stats (+ out_w emission on last layer)
        if (last)
            node_finish_kernel<true><<<(Nn + 7) / 8, 256, 0, stream>>>(
                w_csr, srcc, x2, x1, off, h_v, nst, h_e, eidx, out_w, fin, Nn);
        else
            node_finish_kernel<false><<<(Nn + 7) / 8, 256, 0, stream>>>(
                w_csr, srcc, x2, x1, off, h_v, nst, h_e, eidx, out_w, fin, Nn);

        // fold node BN affine -> fin[0..128]
        finalize_node_kernel<<<1, 64, 0, stream>>>(
            nst, vbn_s + l * 64, vbn_b + l * 64, fin, 1.f / (float)Nn);

        // standalone apply only for the last layer (fused into next node_gemm otherwise)
        if (last) {
            const float* xo_last = (L == 1) ? x_in : out_x;
            node_apply_kernel<<<(Nn * 16 + 255) / 256, 256, 0, stream>>>(
                (const float4*)h_v, (const float4*)xo_last, (float4*)out_x, fin, Nn * 16);
        }
    }
}

// Round 14
// 644.591 us; speedup vs baseline: 7.6578x; 1.0032x over previous
//
#include <hip/hip_runtime.h>
#include <hip/hip_bf16.h>
#include <math.h>

typedef __attribute__((ext_vector_type(8))) short bf16x8;
typedef __attribute__((ext_vector_type(4))) float f32x4;

// ---------- bf16 helpers ----------
__device__ __forceinline__ float bflo(unsigned u) { return __uint_as_float(u << 16); }
__device__ __forceinline__ float bfhi(unsigned u) { return __uint_as_float(u & 0xffff0000u); }
__device__ __forceinline__ unsigned packbf(float a, float b) {
    unsigned ua = __float_as_uint(a), ub = __float_as_uint(b);
    ua += 0x7fffu + ((ua >> 16) & 1u);
    ub += 0x7fffu + ((ub >> 16) & 1u);
    return (ua >> 16) | (ub & 0xffff0000u);
}
// fast sigmoid/silu: v_rcp_f32 (~1 ulp) instead of IEEE divide
__device__ __forceinline__ float fsig(float w) {
    return __builtin_amdgcn_rcpf(1.f + __expf(-w));
}
__device__ __forceinline__ float silu(float g) { return g * fsig(g); }

// ---------- setup ----------
__global__ void zero_int_kernel(int* __restrict__ p, int n) {
    int i = blockIdx.x * blockDim.x + threadIdx.x;
    int s = gridDim.x * blockDim.x;
    for (; i < n; i += s) p[i] = 0;
}

__global__ void count_kernel(const int* __restrict__ dst, int* __restrict__ cnt, int E) {
    int e = blockIdx.x * blockDim.x + threadIdx.x;
    if (e < E) atomicAdd(&cnt[dst[e]], 1);
}

// 3-phase scan
__global__ __launch_bounds__(1024)
void scan_block_kernel(const int* __restrict__ cnt, int* __restrict__ off,
                       int* __restrict__ bsum, int n) {
    __shared__ int wsum[16];
    int tid = threadIdx.x, lane = tid & 63, wid = tid >> 6;
    int i = blockIdx.x * 1024 + tid;
    int v = (i < n) ? cnt[i] : 0;
    int sc = v;
    #pragma unroll
    for (int s = 1; s < 64; s <<= 1) {
        int t = __shfl_up(sc, (unsigned)s, 64);
        if (lane >= s) sc += t;
    }
    if (lane == 63) wsum[wid] = sc;
    __syncthreads();
    int woff = 0;
    for (int k = 0; k < wid; k++) woff += wsum[k];
    if (i < n) off[i + 1] = woff + sc;
    if (tid == 0) {
        int t = 0;
        #pragma unroll
        for (int k = 0; k < 16; k++) t += wsum[k];
        bsum[blockIdx.x] = t;
    }
}

__global__ void scan_tops_kernel(int* __restrict__ bsum, int nb) {
    int lane = threadIdx.x;
    int v = (lane < nb) ? bsum[lane] : 0;
    int sc = v;
    #pragma unroll
    for (int s = 1; s < 64; s <<= 1) {
        int t = __shfl_up(sc, (unsigned)s, 64);
        if (lane >= s) sc += t;
    }
    if (lane < nb) bsum[lane] = sc - v;
}

__global__ __launch_bounds__(1024)
void scan_add_kernel(int* __restrict__ off, const int* __restrict__ bsum, int n) {
    int i = blockIdx.x * 1024 + threadIdx.x;
    int b = bsum[blockIdx.x];
    if (i < n) off[i + 1] += b;
    if (i == 0) off[0] = 0;
}

__global__ void fill_csr_kernel(const int* __restrict__ dst, const int* __restrict__ src,
                                const int* __restrict__ off, int* __restrict__ cnt,
                                int* __restrict__ eidx, int* __restrict__ dstc,
                                int* __restrict__ srcc, int E) {
    int e = blockIdx.x * blockDim.x + threadIdx.x;
    if (e < E) {
        int d = dst[e];
        int pos = atomicSub(&cnt[d], 1) - 1;
        int slot = off[d] + pos;
        eidx[slot] = e;
        dstc[slot] = d;
        srcc[slot] = src[e];
    }
}

// ---------- pack weights into MFMA A-operand fragments (W^T, bf16) ----------
__global__ void pack_kernel(const float* __restrict__ v_w, const float* __restrict__ e_w,
                            short* __restrict__ vwp, short* __restrict__ ewp, int L) {
    int t = blockIdx.x * blockDim.x + threadIdx.x;
    if (t >= L * 5 * 4 * 2 * 64) return;
    int lane = t & 63;
    int ks = (t >> 6) & 1;
    int ft = (t >> 7) & 3;
    int mat = t >> 9;
    int layer = mat / 5, mi = mat % 5;
    const float* W = (mi < 4) ? (v_w + (long long)(layer * 4 + mi) * 4096)
                              : (e_w + (long long)layer * 4096);
    int m = ft * 16 + (lane & 15);
    int k0 = ks * 32 + (lane >> 4) * 8;
    short* dstp = (mi < 4)
        ? vwp + ((((long long)(layer * 4 + mi) * 4 + ft) * 2 + ks) * 64 + lane) * 8
        : ewp + ((((long long)layer * 4 + ft) * 2 + ks) * 64 + lane) * 8;
    #pragma unroll
    for (int j = 0; j < 8; j++) {
        unsigned u = __float_as_uint(W[(k0 + j) * 64 + m]);
        u += 0x7fffu + ((u >> 16) & 1u);
        dstp[j] = (short)(u >> 16);
    }
}

// ---------- node GEMM (MFMA) + optional fused residual-apply of previous layer ----------
template <bool APPLY>
__global__ __launch_bounds__(256)
void node_gemm_mfma(const float* __restrict__ Xold, const float* __restrict__ h_v,
                    float* __restrict__ out_x, const float* __restrict__ fin,
                    const short* __restrict__ vwp, const float* __restrict__ vb,
                    __hip_bfloat16* __restrict__ xp, int Nn) {
    __shared__ short Xs[64 * 64];
    __shared__ short Hs[64 * 64];
    int tid = threadIdx.x;
    long long row0 = (long long)blockIdx.x * 64;

    {
        int r = tid >> 2, cq = tid & 3;
        long long row = row0 + r;
        float xv[16];
        #pragma unroll
        for (int j = 0; j < 16; j++) xv[j] = 0.f;
        if (row < Nn) {
            const float* sp = Xold + row * 64 + cq * 16;
            #pragma unroll
            for (int j = 0; j < 4; j++) {
                float4 v = *(const float4*)(sp + j * 4);
                xv[j*4] = v.x; xv[j*4+1] = v.y; xv[j*4+2] = v.z; xv[j*4+3] = v.w;
            }
            if (APPLY) {
                const float* hp = h_v + row * 64 + cq * 16;
                const float* kmp = fin + cq * 16;
                const float* kap = fin + 64 + cq * 16;
                #pragma unroll
                for (int j = 0; j < 16; j++) {
                    float g = hp[j] * kmp[j] + kap[j];
                    xv[j] = xv[j] + silu(g);
                }
                float* op = out_x + row * 64 + cq * 16;
                #pragma unroll
                for (int j = 0; j < 4; j++)
                    *(float4*)(op + j * 4) = make_float4(xv[j*4], xv[j*4+1], xv[j*4+2], xv[j*4+3]);
            }
        }
        uint4 w0, w1;
        w0.x = packbf(xv[0], xv[1]);   w0.y = packbf(xv[2], xv[3]);
        w0.z = packbf(xv[4], xv[5]);   w0.w = packbf(xv[6], xv[7]);
        w1.x = packbf(xv[8], xv[9]);   w1.y = packbf(xv[10], xv[11]);
        w1.z = packbf(xv[12], xv[13]); w1.w = packbf(xv[14], xv[15]);
        int base = r * 128 + cq * 32, swz = (r & 7) << 4;
        *(uint4*)((char*)Xs + (base ^ swz)) = w0;
        *(uint4*)((char*)Xs + ((base + 16) ^ swz)) = w1;
    }
    __syncthreads();

    int l = tid & 63;
    int rl = (tid >> 6) * 16 + (l & 15);
    bf16x8 bfr[2];
    #pragma unroll
    for (int ks = 0; ks < 2; ks++) {
        int off = (rl * 128 + ks * 64 + (l >> 4) * 16) ^ ((rl & 7) << 4);
        bfr[ks] = *(bf16x8*)((char*)Xs + off);
    }
    int q4 = (l >> 4) * 4;
    int r = tid >> 2, cc = (tid & 3) * 16;
    long long node = row0 + r;
    int swz = (r & 7) << 4;
    for (int g = 0; g < 4; g++) {
        #pragma unroll
        for (int ft = 0; ft < 4; ft++) {
            f32x4 acc = f32x4{0.f, 0.f, 0.f, 0.f};
            #pragma unroll
            for (int ks = 0; ks < 2; ks++) {
                bf16x8 a = *(const bf16x8*)(vwp + (((long long)(g * 4 + ft) * 2 + ks) * 64 + l) * 8);
                acc = __builtin_amdgcn_mfma_f32_16x16x32_bf16(a, bfr[ks], acc, 0, 0, 0);
            }
            int f0 = ft * 16 + q4;
            float4 bv = *(const float4*)&vb[g * 64 + f0];
            uint2 o;
            o.x = packbf(acc[0] + bv.x, acc[1] + bv.y);
            o.y = packbf(acc[2] + bv.z, acc[3] + bv.w);
            int hoff = (rl * 128 + f0 * 2) ^ ((rl & 7) << 4);
            *(uint2*)((char*)Hs + hoff) = o;
        }
        __syncthreads();
        if (node < Nn) {
            uint4 a = *(uint4*)((char*)Hs + ((r * 128 + cc * 2) ^ swz));
            uint4 b = *(uint4*)((char*)Hs + ((r * 128 + cc * 2 + 16) ^ swz));
            __hip_bfloat16* op = xp + ((long long)g * Nn + node) * 64 + cc;
            *(uint4*)op = a;
            *(uint4*)(op + 8) = b;
        }
        __syncthreads();
    }
}

// ---------- edge GEMM (MFMA), CSR state, h_e RECOMPUTE scheme ----------
template <bool FIRST, bool LAST>
__global__ __launch_bounds__(256)
void edge_gemm_mfma(const float* __restrict__ ea, const int* __restrict__ eidx,
                    __hip_bfloat16* __restrict__ w_csr, __hip_bfloat16* __restrict__ h_e,
                    const float* __restrict__ fin,
                    const short* __restrict__ ewp_p, const float* __restrict__ eb_p,
                    const short* __restrict__ ewp, const float* __restrict__ eb,
                    const __hip_bfloat16* __restrict__ x3p, const __hip_bfloat16* __restrict__ x4p,
                    const __hip_bfloat16* __restrict__ x3, const __hip_bfloat16* __restrict__ x4,
                    const int* __restrict__ dstc, const int* __restrict__ srcc,
                    float* __restrict__ estats) {
    __shared__ short Ws[64 * 64];
    __shared__ short Hs[64 * 68];
    __shared__ float sredS[4][64], sredQ[4][64];
    __shared__ int dstl[64], srcl[64];
    int tid = threadIdx.x;
    long long row0 = (long long)blockIdx.x * 64;

    // ---- stage w tile -> Ws ----
    {
        int r = tid >> 2, cq = tid & 3;
        long long grow = (row0 + r) * 64 + cq * 16;
        int base = r * 128 + cq * 32, swz = (r & 7) << 4;
        uint4 w0u, w1u;
        if (FIRST) {
            long long e0 = eidx[row0 + r];
            const float* sp = ea + e0 * 64 + cq * 16;
            float4 v0 = *(const float4*)(sp),     v1 = *(const float4*)(sp + 4);
            float4 v2 = *(const float4*)(sp + 8), v3 = *(const float4*)(sp + 12);
            w0u.x = packbf(v0.x, v0.y); w0u.y = packbf(v0.z, v0.w);
            w0u.z = packbf(v1.x, v1.y); w0u.w = packbf(v1.z, v1.w);
            w1u.x = packbf(v2.x, v2.y); w1u.y = packbf(v2.z, v2.w);
            w1u.z = packbf(v3.x, v3.y); w1u.w = packbf(v3.z, v3.w);
            *(uint4*)&w_csr[grow] = w0u;
            *(uint4*)&w_csr[grow + 8] = w1u;
        } else {
            w0u = *(const uint4*)&w_csr[grow];
            w1u = *(const uint4*)&w_csr[grow + 8];
        }
        *(uint4*)((char*)Ws + (base ^ swz)) = w0u;
        *(uint4*)((char*)Ws + ((base + 16) ^ swz)) = w1u;
        if (tid < 64) {
            dstl[tid] = dstc[row0 + tid];
            srcl[tid] = srcc[row0 + tid];
        }
    }
    __syncthreads();

    int l = tid & 63, wv = tid >> 6;
    int rl = wv * 16 + (l & 15);
    int q4 = (l >> 4) * 4;
    int rr0 = tid >> 3, rr1 = rr0 + 32;
    int c8 = (tid & 7) * 8;
    int de0 = dstl[rr0], se0 = srcl[rr0];
    int de1 = dstl[rr1], se1 = srcl[rr1];

    if (!FIRST) {
        uint4 p3a = *(const uint4*)&x3p[(long long)de0 * 64 + c8];
        uint4 p4a = *(const uint4*)&x4p[(long long)se0 * 64 + c8];
        uint4 p3b = *(const uint4*)&x3p[(long long)de1 * 64 + c8];
        uint4 p4b = *(const uint4*)&x4p[(long long)se1 * 64 + c8];

        bf16x8 bfr[2];
        #pragma unroll
        for (int ks = 0; ks < 2; ks++) {
            int off = (rl * 128 + ks * 64 + (l >> 4) * 16) ^ ((rl & 7) << 4);
            bfr[ks] = *(bf16x8*)((char*)Ws + off);
        }
        #pragma unroll
        for (int ft = 0; ft < 4; ft++) {
            f32x4 acc = f32x4{0.f, 0.f, 0.f, 0.f};
            #pragma unroll
            for (int ks = 0; ks < 2; ks++) {
                bf16x8 a = *(const bf16x8*)(ewp_p + (((long long)ft * 2 + ks) * 64 + l) * 8);
                acc = __builtin_amdgcn_mfma_f32_16x16x32_bf16(a, bfr[ks], acc, 0, 0, 0);
            }
            int f0 = ft * 16 + q4;
            float4 bv = *(const float4*)&eb_p[f0];
            uint2 o;
            o.x = packbf(acc[0] + bv.x, acc[1] + bv.y);
            o.y = packbf(acc[2] + bv.z, acc[3] + bv.w);
            *(uint2*)&Hs[rl * 68 + f0] = o;
        }
        __syncthreads();

        float4 km0 = *(const float4*)&fin[128 + c8], km1 = *(const float4*)&fin[128 + c8 + 4];
        float4 ka0 = *(const float4*)&fin[192 + c8], ka1 = *(const float4*)&fin[192 + c8 + 4];
        float kmv[8] = {km0.x, km0.y, km0.z, km0.w, km1.x, km1.y, km1.z, km1.w};
        float kav[8] = {ka0.x, ka0.y, ka0.z, ka0.w, ka1.x, ka1.y, ka1.z, ka1.w};
        #pragma unroll
        for (int p = 0; p < 2; p++) {
            int rr = p ? rr1 : rr0;
            uint4 p3 = p ? p3b : p3a;
            uint4 p4 = p ? p4b : p4a;
            unsigned u3[4] = {p3.x, p3.y, p3.z, p3.w};
            unsigned u4[4] = {p4.x, p4.y, p4.z, p4.w};
            uint4 hu = *(uint4*)&Hs[rr * 68 + c8];
            unsigned uh[4] = {hu.x, hu.y, hu.z, hu.w};
            int woff = (rr * 128 + c8 * 2) ^ ((rr & 7) << 4);
            uint4 wu = *(uint4*)((char*)Ws + woff);
            unsigned uw[4] = {wu.x, wu.y, wu.z, wu.w};
            float wn[8];
            #pragma unroll
            for (int j = 0; j < 4; j++) {
                float h0 = bflo(uh[j]) + bflo(u3[j]) + bflo(u4[j]);
                float h1 = bfhi(uh[j]) + bfhi(u3[j]) + bfhi(u4[j]);
                wn[2*j]   = bflo(uw[j]) + silu(h0 * kmv[2*j]   + kav[2*j]);
                wn[2*j+1] = bfhi(uw[j]) + silu(h1 * kmv[2*j+1] + kav[2*j+1]);
            }
            uint4 wo;
            wo.x = packbf(wn[0], wn[1]); wo.y = packbf(wn[2], wn[3]);
            wo.z = packbf(wn[4], wn[5]); wo.w = packbf(wn[6], wn[7]);
            *(uint4*)((char*)Ws + woff) = wo;
            *(uint4*)&w_csr[(row0 + rr) * 64 + c8] = wo;
        }
        __syncthreads();
    }

    // ---- current layer: gathers + fragment loads + MFMA ----
    uint4 g3a = *(const uint4*)&x3[(long long)de0 * 64 + c8];
    uint4 g4a = *(const uint4*)&x4[(long long)se0 * 64 + c8];
    uint4 g3b = *(const uint4*)&x3[(long long)de1 * 64 + c8];
    uint4 g4b = *(const uint4*)&x4[(long long)se1 * 64 + c8];
    bf16x8 bfr[2];
    #pragma unroll
    for (int ks = 0; ks < 2; ks++) {
        int off = (rl * 128 + ks * 64 + (l >> 4) * 16) ^ ((rl & 7) << 4);
        bfr[ks] = *(bf16x8*)((char*)Ws + off);
    }
    #pragma unroll
    for (int ft = 0; ft < 4; ft++) {
        f32x4 acc = f32x4{0.f, 0.f, 0.f, 0.f};
        #pragma unroll
        for (int ks = 0; ks < 2; ks++) {
            bf16x8 a = *(const bf16x8*)(ewp + (((long long)ft * 2 + ks) * 64 + l) * 8);
            acc = __builtin_amdgcn_mfma_f32_16x16x32_bf16(a, bfr[ks], acc, 0, 0, 0);
        }
        int f0 = ft * 16 + q4;
        float4 bv = *(const float4*)&eb[f0];
        uint2 o;
        o.x = packbf(acc[0] + bv.x, acc[1] + bv.y);
        o.y = packbf(acc[2] + bv.z, acc[3] + bv.w);
        *(uint2*)&Hs[rl * 68 + f0] = o;
    }
    __syncthreads();

    // ---- row-sliced epilogue: stats (+ h_e write if LAST) ----
    float s[8], q[8];
    #pragma unroll
    for (int j = 0; j < 8; j++) { s[j] = 0.f; q[j] = 0.f; }
    #pragma unroll
    for (int p = 0; p < 2; p++) {
        int rr = p ? rr1 : rr0;
        uint4 g3 = p ? g3b : g3a;
        uint4 g4 = p ? g4b : g4a;
        unsigned u3[4] = {g3.x, g3.y, g3.z, g3.w};
        unsigned u4[4] = {g4.x, g4.y, g4.z, g4.w};
        uint4 hu = *(uint4*)&Hs[rr * 68 + c8];
        unsigned uh[4] = {hu.x, hu.y, hu.z, hu.w};
        float h[8];
        #pragma unroll
        for (int j = 0; j < 4; j++) {
            float h0 = bflo(uh[j]) + bflo(u3[j]) + bflo(u4[j]);
            float h1 = bfhi(uh[j]) + bfhi(u3[j]) + bfhi(u4[j]);
            h[2*j] = h0; h[2*j+1] = h1;
            s[2*j] += h0; s[2*j+1] += h1;
            q[2*j] += h0 * h0; q[2*j+1] += h1 * h1;
        }
        if (LAST) {
            uint4 hv;
            hv.x = packbf(h[0], h[1]); hv.y = packbf(h[2], h[3]);
            hv.z = packbf(h[4], h[5]); hv.w = packbf(h[6], h[7]);
            *(uint4*)&h_e[(row0 + rr) * 64 + c8] = hv;
        }
    }
    #pragma unroll
    for (int d = 8; d < 64; d <<= 1) {
        #pragma unroll
        for (int j = 0; j < 8; j++) {
            s[j] += __shfl_xor(s[j], d);
            q[j] += __shfl_xor(q[j], d);
        }
    }
    if ((l >> 3) == 0) {
        #pragma unroll
        for (int j = 0; j < 8; j++) {
            sredS[wv][(l & 7) * 8 + j] = s[j];
            sredQ[wv][(l & 7) * 8 + j] = q[j];
        }
    }
    __syncthreads();
    if (tid < 128) {
        int which = tid >> 6, f = tid & 63;
        float v = which ? (sredQ[0][f] + sredQ[1][f] + sredQ[2][f] + sredQ[3][f])
                        : (sredS[0][f] + sredS[1][f] + sredS[2][f] + sredS[3][f]);
        atomicAdd(&estats[(blockIdx.x & 7) * 128 + which * 64 + f], v);
    }
}

// ---------- node finish: aggregation + node stats; FINAL also emits out_w in-loop ----------
// half-wave (32 lanes) per node; 16 lanes per edge row (uint2/lane), two edges
// concurrently (sub = lane>>4), 2-pair unroll -> 4 edges in flight.
template <bool FINAL>
__global__ __launch_bounds__(256)
void node_finish_kernel(const __hip_bfloat16* __restrict__ w_csr, const int* __restrict__ srcc,
                        const __hip_bfloat16* __restrict__ x2, const __hip_bfloat16* __restrict__ x1,
                        const int* __restrict__ off, float* __restrict__ h_v,
                        float* __restrict__ nstats,
                        const __hip_bfloat16* __restrict__ h_e, const int* __restrict__ eidx,
                        float* __restrict__ out_w, const float* __restrict__ fin, int Nn) {
    __shared__ float red[8 * 68];
    __shared__ float km[64], ka[64];
    int tid = threadIdx.x;
    if (FINAL) {
        if (tid < 64) { km[tid] = fin[128 + tid]; ka[tid] = fin[192 + tid]; }
        __syncthreads();
    }
    int hw = tid >> 5;
    int lane = tid & 31;
    int sub = lane >> 4;          // which edge of the pair
    int f4 = (lane & 15) * 4;     // 4 features per lane
    int n = blockIdx.x * 8 + hw;
    float a0 = 0.f, a1 = 0.f, a2 = 0.f, a3 = 0.f;
    float h0 = 0.f, h1 = 0.f, h2 = 0.f, h3 = 0.f;
    if (n < Nn) {
        int o0 = off[n], o1 = off[n + 1];
        int j = o0;
        for (; j + 3 < o1; j += 4) {        // 2 pairs: 4 edges in flight
            long long je0 = j + sub, je1 = j + 2 + sub;
            int s0 = srcc[je0], s1 = srcc[je1];
            uint2 wq0 = *(const uint2*)&w_csr[je0 * 64 + f4];
            uint2 wq1 = *(const uint2*)&w_csr[je1 * 64 + f4];
            uint2 xq0 = *(const uint2*)&x2[(long long)s0 * 64 + f4];
            uint2 xq1 = *(const uint2*)&x2[(long long)s1 * 64 + f4];
            a0 += bflo(xq0.x) * fsig(bflo(wq0.x)) + bflo(xq1.x) * fsig(bflo(wq1.x));
            a1 += bfhi(xq0.x) * fsig(bfhi(wq0.x)) + bfhi(xq1.x) * fsig(bfhi(wq1.x));
            a2 += bflo(xq0.y) * fsig(bflo(wq0.y)) + bflo(xq1.y) * fsig(bflo(wq1.y));
            a3 += bfhi(xq0.y) * fsig(bfhi(wq0.y)) + bfhi(xq1.y) * fsig(bfhi(wq1.y));
            if (FINAL) {
                uint2 hq0 = *(const uint2*)&h_e[je0 * 64 + f4];
                uint2 hq1 = *(const uint2*)&h_e[je1 * 64 + f4];
                long long e0 = eidx[je0], e1 = eidx[je1];
                *(float4*)&out_w[e0 * 64 + f4] = make_float4(
                    bflo(wq0.x) + silu(bflo(hq0.x) * km[f4]     + ka[f4]),
                    bfhi(wq0.x) + silu(bfhi(hq0.x) * km[f4 + 1] + ka[f4 + 1]),
                    bflo(wq0.y) + silu(bflo(hq0.y) * km[f4 + 2] + ka[f4 + 2]),
                    bfhi(wq0.y) + silu(bfhi(hq0.y) * km[f4 + 3] + ka[f4 + 3]));
                *(float4*)&out_w[e1 * 64 + f4] = make_float4(
                    bflo(wq1.x) + silu(bflo(hq1.x) * km[f4]     + ka[f4]),
                    bfhi(wq1.x) + silu(bfhi(hq1.x) * km[f4 + 1] + ka[f4 + 1]),
                    bflo(wq1.y) + silu(bflo(hq1.y) * km[f4 + 2] + ka[f4 + 2]),
                    bfhi(wq1.y) + silu(bfhi(hq1.y) * km[f4 + 3] + ka[f4 + 3]));
            }
        }
        for (; j + 1 < o1; j += 2) {        // one pair
            long long je0 = j + sub;
            int s0 = srcc[je0];
            uint2 wq0 = *(const uint2*)&w_csr[je0 * 64 + f4];
            uint2 xq0 = *(const uint2*)&x2[(long long)s0 * 64 + f4];
            a0 += bflo(xq0.x) * fsig(bflo(wq0.x));
            a1 += bfhi(xq0.x) * fsig(bfhi(wq0.x));
            a2 += bflo(xq0.y) * fsig(bflo(wq0.y));
            a3 += bfhi(xq0.y) * fsig(bfhi(wq0.y));
            if (FINAL) {
                uint2 hq0 = *(const uint2*)&h_e[je0 * 64 + f4];
                long long e0 = eidx[je0];
                *(float4*)&out_w[e0 * 64 + f4] = make_float4(
                    bflo(wq0.x) + silu(bflo(hq0.x) * km[f4]     + ka[f4]),
                    bfhi(wq0.x) + silu(bfhi(hq0.x) * km[f4 + 1] + ka[f4 + 1]),
                    bflo(wq0.y) + silu(bflo(hq0.y) * km[f4 + 2] + ka[f4 + 2]),
                    bfhi(wq0.y) + silu(bfhi(hq0.y) * km[f4 + 3] + ka[f4 + 3]));
            }
        }
        if (j < o1 && sub == 0) {           // odd tail, handled by sub 0
            long long je0 = j;
            int s0 = srcc[je0];
            uint2 wq0 = *(const uint2*)&w_csr[je0 * 64 + f4];
            uint2 xq0 = *(const uint2*)&x2[(long long)s0 * 64 + f4];
            a0 += bflo(xq0.x) * fsig(bflo(wq0.x));
            a1 += bfhi(xq0.x) * fsig(bfhi(wq0.x));
            a2 += bflo(xq0.y) * fsig(bflo(wq0.y));
            a3 += bfhi(xq0.y) * fsig(bfhi(wq0.y));
            if (FINAL) {
                uint2 hq0 = *(const uint2*)&h_e[je0 * 64 + f4];
                long long e0 = eidx[je0];
                *(float4*)&out_w[e0 * 64 + f4] = make_float4(
                    bflo(wq0.x) + silu(bflo(hq0.x) * km[f4]     + ka[f4]),
                    bfhi(wq0.x) + silu(bfhi(hq0.x) * km[f4 + 1] + ka[f4 + 1]),
                    bflo(wq0.y) + silu(bflo(hq0.y) * km[f4 + 2] + ka[f4 + 2]),
                    bfhi(wq0.y) + silu(bfhi(hq0.y) * km[f4 + 3] + ka[f4 + 3]));
            }
        }
        // combine sub halves (lane l <-> l^16 within same half-wave)
        a0 += __shfl_xor(a0, 16);
        a1 += __shfl_xor(a1, 16);
        a2 += __shfl_xor(a2, 16);
        a3 += __shfl_xor(a3, 16);
        float ic = 1.f / fmaxf((float)(o1 - o0), 1.f);
        uint2 xq = *(const uint2*)&x1[(long long)n * 64 + f4];
        h0 = bflo(xq.x) + a0 * ic;
        h1 = bfhi(xq.x) + a1 * ic;
        h2 = bflo(xq.y) + a2 * ic;
        h3 = bfhi(xq.y) + a3 * ic;
        if (sub == 0)
            *(float4*)&h_v[(long long)n * 64 + f4] = make_float4(h0, h1, h2, h3);
    }
    if (sub == 0)
        *(float4*)&red[hw * 68 + f4] = make_float4(h0, h1, h2, h3);
    __syncthreads();
    float* nst = nstats + (blockIdx.x & 7) * 128;
    if (tid < 64) {
        float s = 0.f;
        #pragma unroll
        for (int r = 0; r < 8; r++) s += red[r * 68 + tid];
        atomicAdd(&nst[tid], s);
    }
    __syncthreads();
    if (sub == 0)
        *(float4*)&red[hw * 68 + f4] = make_float4(h0 * h0, h1 * h1, h2 * h2, h3 * h3);
    __syncthreads();
    if (tid < 64) {
        float s = 0.f;
        #pragma unroll
        for (int r = 0; r < 8; r++) s += red[r * 68 + tid];
        atomicAdd(&nst[64 + tid], s);
    }
}

// ---------- finalize edge part: estats -> fin[128..256] ----------
__global__ void finalize_edge_kernel(const float* __restrict__ estats,
                                     const float* __restrict__ es, const float* __restrict__ eb,
                                     float* __restrict__ fin, float invE) {
    int c = threadIdx.x;
    float s = 0.f, q = 0.f;
    #pragma unroll
    for (int r = 0; r < 8; r++) { s += estats[r * 128 + c]; q += estats[r * 128 + 64 + c]; }
    float mean = s * invE;
    float var = q * invE - mean * mean;
    float kmul = rsqrtf(var + 1e-5f) * es[c];
    fin[128 + c] = kmul;
    fin[192 + c] = eb[c] - mean * kmul;
}

// ---------- finalize node part: nstats -> fin[0..128] ----------
__global__ void finalize_node_kernel(const float* __restrict__ nstats,
                                     const float* __restrict__ vs, const float* __restrict__ vb,
                                     float* __restrict__ fin, float invN) {
    int c = threadIdx.x;
    float s = 0.f, q = 0.f;
    #pragma unroll
    for (int r = 0; r < 8; r++) { s += nstats[r * 128 + c]; q += nstats[r * 128 + 64 + c]; }
    float mean = s * invN;
    float var = q * invN - mean * mean;
    float kmul = rsqrtf(var + 1e-5f) * vs[c];
    fin[c] = kmul;
    fin[64 + c] = vb[c] - mean * kmul;
}

// ---------- node BN apply (standalone, last layer only) ----------
__global__ __launch_bounds__(256)
void node_apply_kernel(const float4* __restrict__ hv4, const float4* __restrict__ xold4,
                       float4* __restrict__ out4, const float* __restrict__ fin, int total) {
    __shared__ float km[64], ka[64];
    if (threadIdx.x < 64) { km[threadIdx.x] = fin[threadIdx.x]; ka[threadIdx.x] = fin[64 + threadIdx.x]; }
    __syncthreads();
    int idx = blockIdx.x * 256 + threadIdx.x;
    if (idx >= total) return;
    int c0 = (idx & 15) * 4;
    float4 h = hv4[idx], xo = xold4[idx];
    float4 m = *(float4*)&km[c0], a = *(float4*)&ka[c0];
    float g0 = h.x * m.x + a.x, g1 = h.y * m.y + a.y, g2 = h.z * m.z + a.z, g3 = h.w * m.w + a.w;
    out4[idx] = make_float4(xo.x + silu(g0), xo.y + silu(g1),
                            xo.z + silu(g2), xo.w + silu(g3));
}

// ---------- launch ----------
extern "C" void kernel_launch(void* const* d_in, const int* in_sizes, int n_in,
                              void* d_out, int out_size, void* d_ws, size_t ws_size,
                              hipStream_t stream) {
    const float* x_in  = (const float*)d_in[0];
    const float* ea_in = (const float*)d_in[1];
    const int*   ei    = (const int*)d_in[2];
    const float* v_w   = (const float*)d_in[3];
    const float* v_b   = (const float*)d_in[4];
    const float* e_w   = (const float*)d_in[5];
    const float* e_b   = (const float*)d_in[6];
    const float* vbn_s = (const float*)d_in[7];
    const float* vbn_b = (const float*)d_in[8];
    const float* ebn_s = (const float*)d_in[9];
    const float* ebn_b = (const float*)d_in[10];

    const int Nn = in_sizes[0] / 64;
    const int E  = in_sizes[1] / 64;
    const int L  = in_sizes[3] / (4 * 64 * 64);

    const int* dst = ei;
    const int* src = ei + E;

    // workspace layout
    float* h_v    = (float*)d_ws;                       // [Nn][64] fp32
    float* nstats = h_v + (long long)Nn * 64;           // [L][8][128]
    float* estats = nstats + (long long)L * 1024;       // [L][8][128]
    float* fin    = estats + (long long)L * 1024;       // [4][64]
    __hip_bfloat16* xp0   = (__hip_bfloat16*)(fin + 256);      // [4][Nn][64]
    __hip_bfloat16* xp1   = xp0 + (long long)4 * Nn * 64;      // [4][Nn][64]
    __hip_bfloat16* h_e   = xp1 + (long long)4 * Nn * 64;      // [E][64] CSR (last layer only)
    __hip_bfloat16* w_csr = h_e + (long long)E * 64;           // [E][64] CSR
    short* vwp = (short*)(w_csr + (long long)E * 64);   // [L][4][4][2][64][8]
    short* ewp = vwp + (long long)L * 16384;            // [L][4][2][64][8]
    int* cnt  = (int*)(ewp + (long long)L * 4096);      // [Nn]
    int* off  = cnt + Nn;                               // [Nn+1]
    int* eidx = off + Nn + 1;                           // [E]
    int* dstc = eidx + E;                               // [E]
    int* srcc = dstc + E;                               // [E]
    int* bsum = srcc + E;                               // [64]

    size_t needed = ((size_t)Nn * 64 + (size_t)L * 2048 + 256) * 4 +
                    ((size_t)8 * Nn * 64 + (size_t)2 * E * 64 + (size_t)L * 20480) * 2 +
                    ((size_t)2 * Nn + 1 + (size_t)3 * E + 64) * 4;
    if (ws_size < needed) return;

    float* out_x = (float*)d_out;
    float* out_w = out_x + (long long)Nn * 64;

    // CSR build + zero stats + pack weights (once per call)
    const int nb = (Nn + 1023) / 1024;
    zero_int_kernel<<<64, 256, 0, stream>>>(cnt, Nn);
    zero_int_kernel<<<8, 256, 0, stream>>>((int*)nstats, L * 2048);
    count_kernel<<<(E + 255) / 256, 256, 0, stream>>>(dst, cnt, E);
    scan_block_kernel<<<nb, 1024, 0, stream>>>(cnt, off, bsum, Nn);
    scan_tops_kernel<<<1, 64, 0, stream>>>(bsum, nb);
    scan_add_kernel<<<nb, 1024, 0, stream>>>(off, bsum, Nn);
    fill_csr_kernel<<<(E + 255) / 256, 256, 0, stream>>>(dst, src, off, cnt, eidx, dstc, srcc, E);
    pack_kernel<<<(L * 2560 + 255) / 256, 256, 0, stream>>>(v_w, e_w, vwp, ewp, L);

    for (int l = 0; l < L; l++) {
        bool first = (l == 0);
        bool last = (l == L - 1);
        float* nst = nstats + (long long)l * 1024;
        float* est = estats + (long long)l * 1024;
        __hip_bfloat16* xp_cur  = (l & 1) ? xp1 : xp0;
        __hip_bfloat16* xp_prev = (l & 1) ? xp0 : xp1;
        const __hip_bfloat16* x1 = xp_cur;
        const __hip_bfloat16* x2 = xp_cur + (long long)Nn * 64;
        const __hip_bfloat16* x3 = xp_cur + (long long)2 * Nn * 64;
        const __hip_bfloat16* x4 = xp_cur + (long long)3 * Nn * 64;
        const __hip_bfloat16* x3p = xp_prev + (long long)2 * Nn * 64;
        const __hip_bfloat16* x4p = xp_prev + (long long)3 * Nn * 64;

        // node projections -> xp_cur; l>=1 fuses previous layer's residual apply
        const float* xold = (l <= 1) ? x_in : out_x;
        if (first)
            node_gemm_mfma<false><<<(Nn + 63) / 64, 256, 0, stream>>>(
                x_in, h_v, out_x, fin, vwp + (long long)l * 16384, v_b + l * 256, xp_cur, Nn);
        else
            node_gemm_mfma<true><<<(Nn + 63) / 64, 256, 0, stream>>>(
                xold, h_v, out_x, fin, vwp + (long long)l * 16384, v_b + l * 256, xp_cur, Nn);

        // edge GEMM: stage w + (recompute h_prev + fused update) + stats (+ h_e if last)
        const short* ewp_c = ewp + (long long)l * 4096;
        const short* ewp_pv = (l > 0) ? ewp + (long long)(l - 1) * 4096 : ewp_c;
        const float* eb_c = e_b + l * 64;
        const float* eb_pv = (l > 0) ? e_b + (l - 1) * 64 : eb_c;
        if (first && !last)
            edge_gemm_mfma<true, false><<<E / 64, 256, 0, stream>>>(
                ea_in, eidx, w_csr, h_e, fin, ewp_pv, eb_pv, ewp_c, eb_c,
                x3p, x4p, x3, x4, dstc, srcc, est);
        else if (first && last)
            edge_gemm_mfma<true, true><<<E / 64, 256, 0, stream>>>(
                ea_in, eidx, w_csr, h_e, fin, ewp_pv, eb_pv, ewp_c, eb_c,
                x3p, x4p, x3, x4, dstc, srcc, est);
        else if (!first && !last)
            edge_gemm_mfma<false, false><<<E / 64, 256, 0, stream>>>(
                ea_in, eidx, w_csr, h_e, fin, ewp_pv, eb_pv, ewp_c, eb_c,
                x3p, x4p, x3, x4, dstc, srcc, est);
        else
            edge_gemm_mfma<false, true><<<E / 64, 256, 0, stream>>>(
                ea_in, eidx, w_csr, h_e, fin, ewp_pv, eb_pv, ewp_c, eb_c,
                x3p, x4p, x3, x4, dstc, srcc, est);

        // fold edge BN affine -> fin[128..256]
        finalize_edge_kernel<<<1, 64, 0, stream>>>(
            est, ebn_s + l * 64, ebn_b + l * 64, fin, 1.f / (float)E);

        // aggregation + node stats (+ out_w emission on last layer)
        if (last)
            node_finish_kernel<true><<<(Nn + 7) / 8, 256, 0, stream>>>(
                w_csr, srcc, x2, x1, off, h_v, nst, h_e, eidx, out_w, fin, Nn);
        else
            node_finish_kernel<false><<<(Nn + 7) / 8, 256, 0, stream>>>(
                w_csr, srcc, x2, x1, off, h_v, nst, h_e, eidx, out_w, fin, Nn);

        // fold node BN affine -> fin[0..128]
        finalize_node_kernel<<<1, 64, 0, stream>>>(
            nst, vbn_s + l * 64, vbn_b + l * 64, fin, 1.f / (float)Nn);

        // standalone apply only for the last layer
        if (last) {
            const float* xo_last = (L == 1) ? x_in : out_x;
            node_apply_kernel<<<(Nn * 16 + 255) / 256, 256, 0, stream>>>(
                (const float4*)h_v, (const float4*)xo_last, (float4*)out_x, fin, Nn * 16);
        }
    }
}